// Round 15
// baseline (934.142 us; speedup 1.0000x reference)
//
#include <hip/hip_runtime.h>

// Problem constants
#define B_   512
#define T_   128
#define D_   384
#define H_   6
#define DH_  64
#define DFF_ 1536
#define NROW (B_*T_)   // 65536 rows

typedef __attribute__((ext_vector_type(8))) short bf16x8;   // MFMA A/B frag (4 VGPRs)
typedef __attribute__((ext_vector_type(4))) float f32x4;    // MFMA C/D frag
typedef __attribute__((ext_vector_type(4))) unsigned short u16x4;

__device__ __forceinline__ unsigned short f2bf(float f) {
  union { float f; unsigned u; } v; v.f = f;
  unsigned r = v.u + 0x7fffu + ((v.u >> 16) & 1u);   // RNE
  return (unsigned short)(r >> 16);
}

// non-temporal stores: 'nt' flag -> no L2 allocation (protects weight-panel residency)
__device__ __forceinline__ void nts_u4(unsigned short* p, ushort4 v) {
  __builtin_nontemporal_store(*(u16x4*)&v, (u16x4*)p);
}
__device__ __forceinline__ void nts_f4(float* p, float4 v) {
  __builtin_nontemporal_store(*(f32x4*)&v, (f32x4*)p);
}

// lgkm-only barrier (keeps reg-destined global loads in flight)
#define BAR_LGKM() asm volatile("s_waitcnt lgkmcnt(0)\n\ts_barrier" ::: "memory")

// ---------------- weight transpose + fp32->bf16 convert ----------------
__global__ void wt_kernel(const float* __restrict__ W, unsigned short* __restrict__ WT,
                          int K, int Nn) {
  int id = blockIdx.x * 256 + threadIdx.x;
  if (id >= K * Nn) return;
  int n = id % Nn, kk = id / Nn;               // coalesced read along n
  WT[(size_t)n * K + kk] = f2bf(W[(size_t)kk * Nn + n]);
}

// ---------------- fragment-order weight packing (K=384 weights, any NC) -------------
// frag=(c*8+w8)*12+k ; lane 16B = WT[c*128+w8*16+l15][k*32+lq*8]
__global__ void pack_w1(const unsigned short* __restrict__ W1T,  // [NC*128][384]
                        unsigned short* __restrict__ W1P) {
  int tid = blockIdx.x * 256 + threadIdx.x;      // NC*128*384/8 16B-chunks
  int lane = tid & 63, frag = tid >> 6;
  int k = frag % 12, t2 = frag / 12;
  int mi = t2 & 1, t3 = t2 >> 1;
  int w = t3 & 3, c = t3 >> 2;
  int l15 = lane & 15, lq = lane >> 4;
  int r = c * 128 + w * 32 + mi * 16 + l15;
  int col = k * 32 + lq * 8;
  *(int4*)(W1P + (size_t)tid * 8) = *(const int4*)(W1T + (size_t)r * 384 + col);
}
// W2 (K=1536): frag=(((w4*6+mi6)*12+c)*4+kk)
__global__ void pack_w2(const unsigned short* __restrict__ W2T,  // [384][1536]
                        unsigned short* __restrict__ W2P) {
  int tid = blockIdx.x * 256 + threadIdx.x;      // 73728 16B-chunks (288 blocks)
  int lane = tid & 63, frag = tid >> 6;
  int kk = frag & 3, t2 = frag >> 2;
  int c = t2 % 12, t3 = t2 / 12;
  int mi = t3 % 6, w = t3 / 6;
  int l15 = lane & 15, lq = lane >> 4;
  int r = w * 96 + mi * 16 + l15;
  int col = c * 128 + kk * 32 + lq * 8;
  *(int4*)(W2P + (size_t)tid * 8) = *(const int4*)(W2T + (size_t)r * 1536 + col);
}

// ---------------- layernorm: fp32 in -> bf16 out (one wave per row) ----------------
__global__ __launch_bounds__(256) void ln_kernel(const float* __restrict__ x,
                                                 const float* __restrict__ g,
                                                 const float* __restrict__ be,
                                                 unsigned short* __restrict__ out) {
  int row = (blockIdx.x * 256 + threadIdx.x) >> 6;
  int l = threadIdx.x & 63;
  const float* xr = x + (size_t)row * D_;
  float v[6]; float s = 0.f, ss = 0.f;
  #pragma unroll
  for (int i = 0; i < 6; ++i) { v[i] = xr[l + i*64]; s += v[i]; ss += v[i]*v[i]; }
  #pragma unroll
  for (int m = 1; m < 64; m <<= 1) { s += __shfl_xor(s, m); ss += __shfl_xor(ss, m); }
  float mu  = s * (1.f / D_);
  float var = ss * (1.f / D_) - mu * mu;
  float rs  = rsqrtf(var + 1e-5f);
  unsigned short* orow = out + (size_t)row * D_;
  #pragma unroll
  for (int i = 0; i < 6; ++i) {
    int c = l + i*64;
    orow[c] = f2bf((v[i] - mu) * rs * g[c] + be[c]);
  }
}

// ======== shared 8-wave row-GEMM building blocks (frag-order LDS + packed W) ========
#define LDA3(dst, pA, k0)                                                    \
  { _Pragma("unroll") for (int kq = 0; kq < 3; ++kq)                         \
      dst[kq] = *(const bf16x8*)((pA) + ((k0) + kq) * 512); }

#define CMP3(buf, k0, acc)                                                   \
  { _Pragma("unroll") for (int kq = 0; kq < 3; ++kq) {                       \
      bf16x8 bfr[4];                                                         \
      _Pragma("unroll") for (int ni = 0; ni < 4; ++ni)                       \
        bfr[ni] = *(const bf16x8*)(smem + (ni*12 + (k0)+kq)*1024 + l*16);    \
      _Pragma("unroll") for (int ni = 0; ni < 4; ++ni)                       \
        acc[ni] = __builtin_amdgcn_mfma_f32_16x16x32_bf16(                   \
            buf[kq], bfr[ni], acc[ni], 0, 0, 0);                             \
    } }

// ---------------- QKV GEMM (8-wave, 2-strip persistent, NT stores) ------------------
// R11-proven math; grid 512 blocks x 2 row-strips. Weight panel (0.88 MB) stays
// L2-resident: outputs bypass allocation (nt), logical weight demand halved.
__global__ __launch_bounds__(512, 4) void qkv_gemm(
    const unsigned short* __restrict__ h, const unsigned short* __restrict__ wP,
    unsigned short* __restrict__ qkv)
{
  __shared__ __align__(16) char smem[49152];
  int tid = threadIdx.x, w = tid >> 6, l = tid & 63;
  int l15 = l & 15, lq = l >> 4;

  const unsigned short* wb = wP + w * 6144 + l * 8;   // + c*49152 + k*512
  bf16x8 aA[3], aB[3];
  LDA3(aA, wb, 0)

  for (int s = 0; s < 2; ++s) {
    size_t R0 = ((size_t)blockIdx.x * 2 + s) * 64;
    if (s) __syncthreads();          // strip-0 LDS reads done before re-staging
    {
      int row = tid >> 3, q8 = tid & 7;
      int gi = row >> 4, l15w = row & 15;
      const unsigned short* src = h + (R0 + row) * 384;
      #pragma unroll
      for (int i = 0; i < 6; ++i) {
        int c16 = q8 + i * 8;                      // 16B-chunk index, col = c16*8
        int k = c16 >> 2, lqw = c16 & 3;
        *(int4*)(smem + (gi*12 + k)*1024 + (lqw*16 + l15w)*16) =
            *(const int4*)(src + c16 * 8);
      }
    }
    __syncthreads();

    for (int c = 0; c < 9; ++c) {
      const unsigned short* pA  = wb + (size_t)c * 49152;
      const unsigned short* pAn = wb + (size_t)(c < 8 ? c + 1 : 0) * 49152;  // wrap->strip s+1
      f32x4 acc[4];
      #pragma unroll
      for (int j = 0; j < 4; ++j) acc[j] = (f32x4){0.f, 0.f, 0.f, 0.f};

      LDA3(aB, pA, 3)   CMP3(aA, 0, acc)
      LDA3(aA, pA, 6)   CMP3(aB, 3, acc)
      LDA3(aB, pA, 9)   CMP3(aA, 6, acc)
      LDA3(aA, pAn, 0)  CMP3(aB, 9, acc)

      // store: buf = c/3 (q|k|v); M = lq*4+j -> col c2b..+3; N = ni*16+l15 -> row
      int buf = c / 3;
      int c2b = (c - buf * 3) * 128 + w * 16 + lq * 4;
      unsigned short* obase = qkv + (size_t)buf * NROW * 384;
      #pragma unroll
      for (int ni = 0; ni < 4; ++ni) {
        size_t row = R0 + ni * 16 + l15;
        ushort4 pk;
        pk.x = f2bf(acc[ni][0]);
        pk.y = f2bf(acc[ni][1]);
        pk.z = f2bf(acc[ni][2]);
        pk.w = f2bf(acc[ni][3]);
        nts_u4(obase + row * 384 + c2b, pk);
      }
    }
  }
}

// ---------------- fused Wo (8-wave, 2-strip persistent, NT stores) ------------------
__global__ __launch_bounds__(512, 4) void wo_fused(
    const unsigned short* __restrict__ o, const unsigned short* __restrict__ wP,
    const float* __restrict__ bo, const float* __restrict__ xres,
    float* __restrict__ out)
{
  __shared__ __align__(16) char smem[49152];
  int tid = threadIdx.x, w = tid >> 6, l = tid & 63;
  int l15 = l & 15, lq = l >> 4;

  const unsigned short* wb = wP + w * 6144 + l * 8;
  bf16x8 aA[3], aB[3];
  LDA3(aA, wb, 0)

  for (int s = 0; s < 2; ++s) {
    size_t R0 = ((size_t)blockIdx.x * 2 + s) * 64;
    if (s) __syncthreads();
    {
      int row = tid >> 3, q8 = tid & 7;
      int gi = row >> 4, l15w = row & 15;
      const unsigned short* src = o + (R0 + row) * 384;
      #pragma unroll
      for (int i = 0; i < 6; ++i) {
        int c16 = q8 + i * 8;
        int k = c16 >> 2, lqw = c16 & 3;
        *(int4*)(smem + (gi*12 + k)*1024 + (lqw*16 + l15w)*16) =
            *(const int4*)(src + c16 * 8);
      }
    }
    __syncthreads();

    for (int c = 0; c < 3; ++c) {
      const unsigned short* pA  = wb + (size_t)c * 49152;
      const unsigned short* pAn = wb + (size_t)(c < 2 ? c + 1 : 0) * 49152;
      f32x4 acc[4];
      #pragma unroll
      for (int j = 0; j < 4; ++j) acc[j] = (f32x4){0.f, 0.f, 0.f, 0.f};

      LDA3(aB, pA, 3)   CMP3(aA, 0, acc)
      LDA3(aA, pA, 6)   CMP3(aB, 3, acc)
      LDA3(aB, pA, 9)   CMP3(aA, 6, acc)
      LDA3(aA, pAn, 0)  CMP3(aB, 9, acc)

      int colb = c * 128 + w * 16 + lq * 4;
      float4 bias = *(const float4*)(bo + colb);
      #pragma unroll
      for (int ni = 0; ni < 4; ++ni) {
        size_t row = R0 + ni * 16 + l15;
        float4 r = *(const float4*)(xres + row * 384 + colb);
        float4 ov;
        ov.x = acc[ni][0] + bias.x + r.x;
        ov.y = acc[ni][1] + bias.y + r.y;
        ov.z = acc[ni][2] + bias.z + r.z;
        ov.w = acc[ni][3] + bias.w + r.w;
        nts_f4(out + row * 384 + colb, ov);
      }
    }
  }
}

// ---------------- fused FFN (8-wave + T5 setprio + lgkm barriers; R12/R13-proven) ---
__global__ __launch_bounds__(512, 4) void ffn_fused(
    const unsigned short* __restrict__ h2,   // [NROW][384] bf16
    const unsigned short* __restrict__ w1P,  // packed (pack_w1)
    const unsigned short* __restrict__ w2P,  // packed (pack_w2)
    const float* __restrict__ b1,            // [1536]
    const float* __restrict__ b2,            // [384]
    float* __restrict__ out)                 // [NROW][384] fp32, in-place residual add
{
  __shared__ __align__(16) char smem[65536];
  int tid = threadIdx.x, w = tid >> 6, l = tid & 63;
  int l15 = l & 15, lq = l >> 4;
  size_t R0 = (size_t)blockIdx.x * 64;

  // ---- stage h2 strip -> frag-order LDS (512 thr x 48 elems) ----
  {
    int row = tid >> 3, gi = row >> 4, l15w = row & 15;
    int cbase = (tid & 7) * 48;
    const unsigned short* src = h2 + (R0 + row) * 384 + cbase;
    #pragma unroll
    for (int i = 0; i < 6; ++i) {
      int col = cbase + i * 8;
      int k = col >> 5, lqw = (col >> 3) & 3;
      *(int4*)(smem + (gi*12 + k)*1024 + (lqw*16 + l15w)*16) = *(const int4*)(src + i*8);
    }
  }
  __syncthreads();

  f32x4 oacc[3][4];
  #pragma unroll
  for (int i = 0; i < 3; ++i)
    #pragma unroll
    for (int j = 0; j < 4; ++j) oacc[i][j] = (f32x4){0.f, 0.f, 0.f, 0.f};

  const unsigned short* w1b = w1P + w * 6144  + l * 8;  // + c*49152 + k*512
  const unsigned short* w2b = w2P + w * 73728 + l * 8;  // + mi*24576 + c*2048 + kk*512

  #define LDV(dst, pV, kk)                                                   \
    { _Pragma("unroll") for (int mi = 0; mi < 3; ++mi)                       \
        dst[mi] = *(const bf16x8*)((pV) + mi * 24576 + (kk) * 512); }

  #define CMPV(buf, kk)                                                      \
    { bf16x8 bv[4];                                                          \
      _Pragma("unroll") for (int ni = 0; ni < 4; ++ni)                       \
        bv[ni] = *(const bf16x8*)(smem + 49152 + (ni*4 + (kk))*1024 + l*16); \
      _Pragma("unroll") for (int mi = 0; mi < 3; ++mi)                       \
        _Pragma("unroll") for (int ni = 0; ni < 4; ++ni)                     \
          oacc[mi][ni] = __builtin_amdgcn_mfma_f32_16x16x32_bf16(            \
              buf[mi], bv[ni], oacc[mi][ni], 0, 0, 0);                       \
    }

  bf16x8 afA[3], afB[3];
  bf16x8 avA[3], avB[3];

  LDA3(afA, w1b, 0)   // prologue: first P-group of chunk 0

  for (int c = 0; c < 12; ++c) {
    const unsigned short* pA = w1b + (size_t)c * 49152;
    const unsigned short* pV = w2b + c * 2048;

    f32x4 pacc[4];
    #pragma unroll
    for (int j = 0; j < 4; ++j) pacc[j] = (f32x4){0.f, 0.f, 0.f, 0.f};

    // P-phase: 4 groups of 3 k-steps, ping-pong prefetch; T5 around MFMA clusters
    LDA3(afB, pA, 3)
    __builtin_amdgcn_s_setprio(1); CMP3(afA, 0, pacc) __builtin_amdgcn_s_setprio(0);
    LDA3(afA, pA, 6)
    __builtin_amdgcn_s_setprio(1); CMP3(afB, 3, pacc) __builtin_amdgcn_s_setprio(0);
    LDA3(afB, pA, 9)
    __builtin_amdgcn_s_setprio(1); CMP3(afA, 6, pacc) __builtin_amdgcn_s_setprio(0);
    LDV(avA, pV, 0)
    __builtin_amdgcn_s_setprio(1); CMP3(afB, 9, pacc) __builtin_amdgcn_s_setprio(0);

    // P epilogue: bias1 + relu + bf16 pack -> Psf
    {
      int fcb = c * 128 + w * 16 + lq * 4;
      float4 bb = *(const float4*)(b1 + fcb);
      unsigned pw = (unsigned)(49152 + (w >> 1) * 1024 +
                    (((w & 1) * 2 + (lq >> 1)) * 16 + l15) * 16 + (lq & 1) * 8);
      #pragma unroll
      for (int ni = 0; ni < 4; ++ni) {
        float p0 = pacc[ni][0] + bb.x;
        float p1 = pacc[ni][1] + bb.y;
        float p2 = pacc[ni][2] + bb.z;
        float p3 = pacc[ni][3] + bb.w;
        ushort4 pk;
        pk.x = f2bf(p0 > 0.f ? p0 : 0.f);
        pk.y = f2bf(p1 > 0.f ? p1 : 0.f);
        pk.z = f2bf(p2 > 0.f ? p2 : 0.f);
        pk.w = f2bf(p3 > 0.f ? p3 : 0.f);
        *(ushort4*)(smem + pw + ni * 4096) = pk;
      }
    }
    BAR_LGKM();   // P ds_writes drained (lgkm); avA global prefetch stays in flight

    const unsigned short* pAn = w1b + (size_t)(c < 11 ? c + 1 : 11) * 49152;
    LDV(avB, pV, 1)
    __builtin_amdgcn_s_setprio(1); CMPV(avA, 0) __builtin_amdgcn_s_setprio(0);
    LDV(avA, pV, 2)
    __builtin_amdgcn_s_setprio(1); CMPV(avB, 1) __builtin_amdgcn_s_setprio(0);
    LDV(avB, pV, 3)
    __builtin_amdgcn_s_setprio(1); CMPV(avA, 2) __builtin_amdgcn_s_setprio(0);
    LDA3(afA, pAn, 0)
    __builtin_amdgcn_s_setprio(1); CMPV(avB, 3) __builtin_amdgcn_s_setprio(0);
    BAR_LGKM();   // PV ds_reads retired (lgkm); afA prefetch for next chunk in flight
  }
  #undef LDV
  #undef CMPV

  // epilogue: out[row][ocol..+3] = oacc + b2 + res  (dwordx4)
  #pragma unroll
  for (int mi = 0; mi < 3; ++mi) {
    int ocb = w * 48 + mi * 16 + lq * 4;
    float4 b2v = *(const float4*)(b2 + ocb);
    #pragma unroll
    for (int ni = 0; ni < 4; ++ni) {
      size_t row = R0 + ni * 16 + l15;
      float* op = out + row * D_ + ocb;
      float4 r = *(const float4*)op;
      float4 o;
      o.x = oacc[mi][ni][0] + b2v.x + r.x;
      o.y = oacc[mi][ni][1] + b2v.y + r.y;
      o.z = oacc[mi][ni][2] + b2v.z + r.z;
      o.w = oacc[mi][ni][3] + b2v.w + r.w;
      *(float4*)op = o;
    }
  }
}

// ---------------- causal attention (+T5 setprio), one block per (b,h) ----------------
__global__ __launch_bounds__(256) void attn_kernel(const unsigned short* __restrict__ q,
                                                   const unsigned short* __restrict__ k,
                                                   const unsigned short* __restrict__ v,
                                                   unsigned short* __restrict__ o) {
  __shared__ __align__(16) char smem[52224];
  unsigned short (*Ks)[72]       = (unsigned short(*)[72])smem;
  unsigned short (*Ps)[32][136]  = (unsigned short(*)[32][136])smem;
  unsigned short (*Vt)[136]      = (unsigned short(*)[136])(smem + 34816);

  int bh = blockIdx.x;
  int b = bh / H_, h = bh % H_;
  int tid = threadIdx.x, w = tid >> 6, l = tid & 63;

  const unsigned short* kb = k + ((size_t)b * T_) * D_ + h * DH_;
  const unsigned short* vb = v + ((size_t)b * T_) * D_ + h * DH_;
  #pragma unroll
  for (int it = 0; it < 4; ++it) {
    int id = it * 256 + tid;
    int s = id >> 3, c8 = (id & 7) * 8;
    int4 kv = *(const int4*)(kb + (size_t)s * D_ + c8);
    *(int4*)(&Ks[s][c8]) = kv;
    int4 vv = *(const int4*)(vb + (size_t)s * D_ + c8);
    const unsigned short* pe = (const unsigned short*)&vv;
    #pragma unroll
    for (int j2 = 0; j2 < 8; ++j2) Vt[c8 + j2][s] = pe[j2];
  }
  __syncthreads();

  const unsigned short* qbp = q + ((size_t)b * T_) * D_ + h * DH_;
  int rowbase = w * 32;
  bf16x8 aq[2][2];
  #pragma unroll
  for (int mi = 0; mi < 2; ++mi)
    #pragma unroll
    for (int ks = 0; ks < 2; ++ks)
      aq[mi][ks] = *(const bf16x8*)(qbp + (size_t)(rowbase + mi*16 + (l & 15)) * D_
                                        + ks*32 + ((l >> 4) << 3));

  f32x4 accs[2][8];
  #pragma unroll
  for (int i = 0; i < 2; ++i)
    #pragma unroll
    for (int j = 0; j < 8; ++j) accs[i][j] = (f32x4){0.f, 0.f, 0.f, 0.f};
  #pragma unroll
  for (int ks = 0; ks < 2; ++ks) {
    bf16x8 bk[8];
    #pragma unroll
    for (int ni = 0; ni < 8; ++ni)
      bk[ni] = *(const bf16x8*)(&Ks[ni*16 + (l & 15)][ks*32 + ((l >> 4) << 3)]);
    __builtin_amdgcn_s_setprio(1);
    #pragma unroll
    for (int mi = 0; mi < 2; ++mi)
      #pragma unroll
      for (int ni = 0; ni < 8; ++ni)
        accs[mi][ni] = __builtin_amdgcn_mfma_f32_16x16x32_bf16(aq[mi][ks], bk[ni], accs[mi][ni], 0, 0, 0);
    __builtin_amdgcn_s_setprio(0);
  }
  __syncthreads();

  #pragma unroll
  for (int mi = 0; mi < 2; ++mi) {
    #pragma unroll
    for (int j = 0; j < 4; ++j) {
      int t = rowbase + mi*16 + ((l >> 4) << 2) + j;
      float mx = -1e30f;
      #pragma unroll
      for (int ni = 0; ni < 8; ++ni) {
        int scol = ni*16 + (l & 15);
        float sv = accs[mi][ni][j] * 0.125f;
        sv = (scol <= t) ? sv : -1e30f;
        accs[mi][ni][j] = sv;
        mx = fmaxf(mx, sv);
      }
      mx = fmaxf(mx, __shfl_xor(mx, 1));
      mx = fmaxf(mx, __shfl_xor(mx, 2));
      mx = fmaxf(mx, __shfl_xor(mx, 4));
      mx = fmaxf(mx, __shfl_xor(mx, 8));
      float sum = 0.f;
      #pragma unroll
      for (int ni = 0; ni < 8; ++ni) {
        float e = __expf(accs[mi][ni][j] - mx);
        accs[mi][ni][j] = e;
        sum += e;
      }
      sum += __shfl_xor(sum, 1);
      sum += __shfl_xor(sum, 2);
      sum += __shfl_xor(sum, 4);
      sum += __shfl_xor(sum, 8);
      float inv = 1.f / sum;
      #pragma unroll
      for (int ni = 0; ni < 8; ++ni)
        Ps[w][mi*16 + ((l >> 4) << 2) + j][ni*16 + (l & 15)] = f2bf(accs[mi][ni][j] * inv);
    }
  }
  __syncthreads();

  f32x4 acco[2][4];
  #pragma unroll
  for (int i = 0; i < 2; ++i)
    #pragma unroll
    for (int j = 0; j < 4; ++j) acco[i][j] = (f32x4){0.f, 0.f, 0.f, 0.f};
  #pragma unroll
  for (int ks = 0; ks < 4; ++ks) {
    bf16x8 ap[2], bv[4];
    #pragma unroll
    for (int mi = 0; mi < 2; ++mi)
      ap[mi] = *(const bf16x8*)(&Ps[w][mi*16 + (l & 15)][ks*32 + ((l >> 4) << 3)]);
    #pragma unroll
    for (int ni = 0; ni < 4; ++ni)
      bv[ni] = *(const bf16x8*)(&Vt[ni*16 + (l & 15)][ks*32 + ((l >> 4) << 3)]);
    __builtin_amdgcn_s_setprio(1);
    #pragma unroll
    for (int mi = 0; mi < 2; ++mi)
      #pragma unroll
      for (int ni = 0; ni < 4; ++ni)
        acco[mi][ni] = __builtin_amdgcn_mfma_f32_16x16x32_bf16(ap[mi], bv[ni], acco[mi][ni], 0, 0, 0);
    __builtin_amdgcn_s_setprio(0);
  }

  unsigned short* ob = o + ((size_t)b * T_) * D_ + h * DH_;
  #pragma unroll
  for (int mi = 0; mi < 2; ++mi)
    #pragma unroll
    for (int ni = 0; ni < 4; ++ni)
      #pragma unroll
      for (int j = 0; j < 4; ++j) {
        int t = rowbase + mi*16 + ((l >> 4) << 2) + j;
        int d = ni*16 + (l & 15);
        ob[(size_t)t * D_ + d] = f2bf(acco[mi][ni][j]);
      }
}

extern "C" void kernel_launch(void* const* d_in, const int* in_sizes, int n_in,
                              void* d_out, int out_size, void* d_ws, size_t ws_size,
                              hipStream_t stream) {
  const float* x   = (const float*)d_in[0];
  const float* Wq  = (const float*)d_in[1];
  const float* Wk  = (const float*)d_in[2];
  const float* Wv  = (const float*)d_in[3];
  const float* Wo  = (const float*)d_in[4];
  const float* bo  = (const float*)d_in[5];
  const float* W1  = (const float*)d_in[6];
  const float* b1  = (const float*)d_in[7];
  const float* W2  = (const float*)d_in[8];
  const float* b2  = (const float*)d_in[9];
  const float* g1  = (const float*)d_in[10];
  const float* be1 = (const float*)d_in[11];
  const float* g2  = (const float*)d_in[12];
  const float* be2 = (const float*)d_in[13];

  // workspace layout (bytes); total ~209 MiB
  char* ws = (char*)d_ws;
  unsigned short* hb    = (unsigned short*)(ws);               // h (LN1), later h2 (LN2)
  unsigned short* qb    = (unsigned short*)(ws +  50331648);   // q|k|v contiguous; o in-place
  unsigned short* kbuf  = (unsigned short*)(ws + 100663296);
  unsigned short* vbuf  = (unsigned short*)(ws + 150994944);
  unsigned short* wqT   = (unsigned short*)(ws + 201326592);   // [1152][384] (wq|wk|wv contiguous)
  unsigned short* woT   = wqT + 442368;                        // [384][384]
  unsigned short* w1T   = woT + 147456;                        // [1536][384]
  unsigned short* w2T   = w1T + 589824;                        // [384][1536]
  unsigned short* w1P   = w2T + 589824;                        // packed (pack_w1, NC=12)
  unsigned short* w2P   = w1P + 589824;                        // packed (pack_w2)
  unsigned short* wqkvP = w2P + 589824;                        // packed (pack_w1, NC=9)
  unsigned short* woP   = wqkvP + 442368;                      // packed (pack_w1, NC=3)
  float* x2 = (float*)d_out;
  (void)kbuf; (void)vbuf;

  // 1) weight convert+transpose (tiny) + fragment-order packs
  wt_kernel<<<dim3(576),  256, 0, stream>>>(Wq, wqT,          384, 384);
  wt_kernel<<<dim3(576),  256, 0, stream>>>(Wk, wqT + 147456, 384, 384);
  wt_kernel<<<dim3(576),  256, 0, stream>>>(Wv, wqT + 294912, 384, 384);
  wt_kernel<<<dim3(576),  256, 0, stream>>>(Wo, woT,          384, 384);
  wt_kernel<<<dim3(2304), 256, 0, stream>>>(W1, w1T, 384, 1536);
  wt_kernel<<<dim3(2304), 256, 0, stream>>>(W2, w2T, 1536, 384);
  pack_w1<<<dim3(216), 256, 0, stream>>>(wqT, wqkvP);   // NC=9
  pack_w1<<<dim3(72),  256, 0, stream>>>(woT, woP);     // NC=3
  pack_w1<<<dim3(288), 256, 0, stream>>>(w1T, w1P);     // NC=12
  pack_w2<<<dim3(288), 256, 0, stream>>>(w2T, w2P);

  // 2) LN1: x -> h (bf16)
  ln_kernel<<<dim3(NROW / 4), 256, 0, stream>>>(x, g1, be1, hb);

  // 3) QKV GEMM (8-wave, 2-strip, NT stores): q|k|v = h @ [Wq|Wk|Wv]
  qkv_gemm<<<dim3(NROW / 128), 512, 0, stream>>>(hb, wqkvP, qb);

  // 4) attention: o overwrites q in place (per-block disjoint strips)
  attn_kernel<<<dim3(B_ * H_), 256, 0, stream>>>(qb, kbuf, vbuf, qb);

  // 5) x2 = x + o @ Wo + bo  (8-wave, 2-strip, NT stores, into d_out)
  wo_fused<<<dim3(NROW / 128), 512, 0, stream>>>(qb, woP, bo, x, x2);

  // 6) LN2: x2 -> h2 (bf16, into hb)
  ln_kernel<<<dim3(NROW / 4), 256, 0, stream>>>((const float*)x2, g2, be2, hb);

  // 7) fused FFN (8-wave + setprio + lgkm-barriers): out = x2 + relu(h2@W1+b1)@W2 + b2
  ffn_fused<<<dim3(NROW / 64), 512, 0, stream>>>(hb, w1P, w2P, b1, b2, x2);
}

// Round 16
// 447.081 us; speedup vs baseline: 2.0894x; 2.0894x over previous
//
#include <hip/hip_runtime.h>

// Problem constants
#define B_   512
#define T_   128
#define D_   384
#define H_   6
#define DH_  64
#define DFF_ 1536
#define NROW (B_*T_)   // 65536 rows

typedef __attribute__((ext_vector_type(8))) short bf16x8;   // MFMA A/B frag (4 VGPRs)
typedef __attribute__((ext_vector_type(4))) float f32x4;    // MFMA C/D frag

__device__ __forceinline__ unsigned short f2bf(float f) {
  union { float f; unsigned u; } v; v.f = f;
  unsigned r = v.u + 0x7fffu + ((v.u >> 16) & 1u);   // RNE
  return (unsigned short)(r >> 16);
}

// async global->LDS, 16 B per lane, wave-uniform LDS base (m97 pattern)
#define GLDS16(gp, lp)                                                     \
  __builtin_amdgcn_global_load_lds(                                        \
      (const __attribute__((address_space(1))) void*)(gp),                 \
      (__attribute__((address_space(3))) void*)(lp), 16, 0, 0)

// lgkm-only barrier (keeps reg-destined global loads in flight)
#define BAR_LGKM() asm volatile("s_waitcnt lgkmcnt(0)\n\ts_barrier" ::: "memory")

// ---------------- weight transpose + fp32->bf16 convert ----------------
__global__ void wt_kernel(const float* __restrict__ W, unsigned short* __restrict__ WT,
                          int K, int Nn) {
  int id = blockIdx.x * 256 + threadIdx.x;
  if (id >= K * Nn) return;
  int n = id % Nn, kk = id / Nn;               // coalesced read along n
  WT[(size_t)n * K + kk] = f2bf(W[(size_t)kk * Nn + n]);
}

// ---------------- fragment-order weight packing (from bf16 WT, K=384) ----------------
__global__ void pack_w1(const unsigned short* __restrict__ W1T,  // [1536][384]
                        unsigned short* __restrict__ W1P) {
  int tid = blockIdx.x * 256 + threadIdx.x;      // 73728 16B-chunks (288 blocks)
  int lane = tid & 63, frag = tid >> 6;
  int k = frag % 12, t2 = frag / 12;
  int mi = t2 & 1, t3 = t2 >> 1;
  int w = t3 & 3, c = t3 >> 2;
  int l15 = lane & 15, lq = lane >> 4;
  int r = c * 128 + w * 32 + mi * 16 + l15;
  int col = k * 32 + lq * 8;
  *(int4*)(W1P + (size_t)tid * 8) = *(const int4*)(W1T + (size_t)r * 384 + col);
}
// W2 (K=1536): frag=(((w4*6+mi6)*12+c)*4+kk)
__global__ void pack_w2(const unsigned short* __restrict__ W2T,  // [384][1536]
                        unsigned short* __restrict__ W2P) {
  int tid = blockIdx.x * 256 + threadIdx.x;      // 73728 16B-chunks (288 blocks)
  int lane = tid & 63, frag = tid >> 6;
  int kk = frag & 3, t2 = frag >> 2;
  int c = t2 % 12, t3 = t2 / 12;
  int mi = t3 % 6, w = t3 / 6;
  int l15 = lane & 15, lq = lane >> 4;
  int r = w * 96 + mi * 16 + l15;
  int col = c * 128 + kk * 32 + lq * 8;
  *(int4*)(W2P + (size_t)tid * 8) = *(const int4*)(W2T + (size_t)r * 1536 + col);
}

// ---------------- layernorm: fp32 in -> bf16 out (one wave per row) ----------------
__global__ __launch_bounds__(256) void ln_kernel(const float* __restrict__ x,
                                                 const float* __restrict__ g,
                                                 const float* __restrict__ be,
                                                 unsigned short* __restrict__ out) {
  int row = (blockIdx.x * 256 + threadIdx.x) >> 6;
  int l = threadIdx.x & 63;
  const float* xr = x + (size_t)row * D_;
  float v[6]; float s = 0.f, ss = 0.f;
  #pragma unroll
  for (int i = 0; i < 6; ++i) { v[i] = xr[l + i*64]; s += v[i]; ss += v[i]*v[i]; }
  #pragma unroll
  for (int m = 1; m < 64; m <<= 1) { s += __shfl_xor(s, m); ss += __shfl_xor(ss, m); }
  float mu  = s * (1.f / D_);
  float var = ss * (1.f / D_) - mu * mu;
  float rs  = rsqrtf(var + 1e-5f);
  unsigned short* orow = out + (size_t)row * D_;
  #pragma unroll
  for (int i = 0; i < 6; ++i) {
    int c = l + i*64;
    orow[c] = f2bf((v[i] - mu) * rs * g[c] + be[c]);
  }
}

// ---------------- NT GEMM (QKV / Wo): 2-phase dbuf, gload_lds (R9-proven) ----------
// + T1 bijective XCD swizzle (m157): each XCD gets contiguous 64-row x all-col
//   logical tile range (col-fastest) -> A-strips stay L2-hot across the column sweep.
// EPI 1: += bias[col] + res[row,col], store fp32
// EPI 3: store bf16 split across 3 contiguous [NROW,384] buffers (fused QKV)
template<int EPI>
__global__ __launch_bounds__(256) void gemm_bt(const unsigned short* __restrict__ A,
                                               const unsigned short* __restrict__ BT,
                                               void* __restrict__ Cc,
                                               const float* __restrict__ bias,
                                               const float* __restrict__ res,
                                               int Nn, int K) {
  __shared__ unsigned short As[2][128][32];   // linear inner layout: required by global_load_lds
  __shared__ unsigned short Bs[2][128][32];
  int tid = threadIdx.x, w = tid >> 6, l = tid & 63;
  int wr = w >> 1, wc = w & 1;

  // T1: hw dispatch index lin (x-fastest) -> XCD-contiguous logical tile swz
  int ncol = gridDim.y;
  int nwg  = gridDim.x * ncol;                 // launches ensure nwg % 8 == 0
  int lin  = blockIdx.y * gridDim.x + blockIdx.x;
  int cpx  = nwg >> 3;
  int swz  = (lin & 7) * cpx + (lin >> 3);     // bijective (nwg%8==0)
  size_t R0 = (size_t)(swz / ncol) * 128;      // col-fastest logical order
  int C0 = (swz % ncol) * 128;

  int seg0 = (w * 2 + 0) * 16;
  int seg1 = (w * 2 + 1) * 16;
  int srow0 = seg0 + (l >> 2);
  int srow1 = seg1 + (l >> 2);
  int scol  = (l & 3) * 8;

  const unsigned short* ga0 = A  + (R0 + srow0) * K + scol;
  const unsigned short* ga1 = A  + (R0 + srow1) * K + scol;
  const unsigned short* gb0 = BT + (size_t)(C0 + srow0) * K + scol;
  const unsigned short* gb1 = BT + (size_t)(C0 + srow1) * K + scol;

  f32x4 acc[4][4];
  #pragma unroll
  for (int i = 0; i < 4; ++i)
    #pragma unroll
    for (int j = 0; j < 4; ++j) acc[i][j] = (f32x4){0.f, 0.f, 0.f, 0.f};

  GLDS16(ga0, &As[0][seg0][0]);
  GLDS16(ga1, &As[0][seg1][0]);
  GLDS16(gb0, &Bs[0][seg0][0]);
  GLDS16(gb1, &Bs[0][seg1][0]);
  ga0 += 32; ga1 += 32; gb0 += 32; gb1 += 32;

  int nk = K >> 5;
  for (int t = 0; t < nk; ++t) {
    int cur = t & 1;
    __syncthreads();
    if (t + 1 < nk) {
      GLDS16(ga0, &As[cur ^ 1][seg0][0]);
      GLDS16(ga1, &As[cur ^ 1][seg1][0]);
      GLDS16(gb0, &Bs[cur ^ 1][seg0][0]);
      GLDS16(gb1, &Bs[cur ^ 1][seg1][0]);
      ga0 += 32; ga1 += 32; gb0 += 32; gb1 += 32;
    }
    bf16x8 af[4], bf[4];
    #pragma unroll
    for (int mi = 0; mi < 4; ++mi)
      af[mi] = *(const bf16x8*)(&As[cur][wr*64 + mi*16 + (l & 15)][(l >> 4) * 8]);
    #pragma unroll
    for (int ni = 0; ni < 4; ++ni)
      bf[ni] = *(const bf16x8*)(&Bs[cur][wc*64 + ni*16 + (l & 15)][(l >> 4) * 8]);
    #pragma unroll
    for (int mi = 0; mi < 4; ++mi)
      #pragma unroll
      for (int ni = 0; ni < 4; ++ni)
        acc[mi][ni] = __builtin_amdgcn_mfma_f32_16x16x32_bf16(af[mi], bf[ni], acc[mi][ni], 0, 0, 0);
  }

  #pragma unroll
  for (int mi = 0; mi < 4; ++mi) {
    #pragma unroll
    for (int ni = 0; ni < 4; ++ni) {
      int col = C0 + wc*64 + ni*16 + (l & 15);
      #pragma unroll
      for (int j = 0; j < 4; ++j) {
        size_t row = R0 + wr*64 + mi*16 + ((l >> 4) << 2) + j;
        float vv = acc[mi][ni][j];
        if (EPI == 1) {
          ((float*)Cc)[row * Nn + col] = vv + bias[col] + res[row * Nn + col];
        } else {
          int buf = col / 384, c2 = col - buf * 384;
          ((unsigned short*)Cc)[(size_t)buf * NROW * 384 + row * 384 + c2] = f2bf(vv);
        }
      }
    }
  }
}

// ======== 8-wave ffn building blocks (frag-order LDS + packed W) ========
#define LDA3(dst, pA, k0)                                                    \
  { _Pragma("unroll") for (int kq = 0; kq < 3; ++kq)                         \
      dst[kq] = *(const bf16x8*)((pA) + ((k0) + kq) * 512); }

#define CMP3(buf, k0, acc)                                                   \
  { _Pragma("unroll") for (int kq = 0; kq < 3; ++kq) {                       \
      bf16x8 bfr[4];                                                         \
      _Pragma("unroll") for (int ni = 0; ni < 4; ++ni)                       \
        bfr[ni] = *(const bf16x8*)(smem + (ni*12 + (k0)+kq)*1024 + l*16);    \
      _Pragma("unroll") for (int ni = 0; ni < 4; ++ni)                       \
        acc[ni] = __builtin_amdgcn_mfma_f32_16x16x32_bf16(                   \
            buf[kq], bfr[ni], acc[ni], 0, 0, 0);                             \
    } }

// ---------------- fused FFN (8-wave + T5 setprio + lgkm barriers; R13-proven) -------
__global__ __launch_bounds__(512, 4) void ffn_fused(
    const unsigned short* __restrict__ h2,   // [NROW][384] bf16
    const unsigned short* __restrict__ w1P,  // packed (pack_w1)
    const unsigned short* __restrict__ w2P,  // packed (pack_w2)
    const float* __restrict__ b1,            // [1536]
    const float* __restrict__ b2,            // [384]
    float* __restrict__ out)                 // [NROW][384] fp32, in-place residual add
{
  __shared__ __align__(16) char smem[65536];
  int tid = threadIdx.x, w = tid >> 6, l = tid & 63;
  int l15 = l & 15, lq = l >> 4;
  size_t R0 = (size_t)blockIdx.x * 64;

  // ---- stage h2 strip -> frag-order LDS (512 thr x 48 elems) ----
  {
    int row = tid >> 3, gi = row >> 4, l15w = row & 15;
    int cbase = (tid & 7) * 48;
    const unsigned short* src = h2 + (R0 + row) * 384 + cbase;
    #pragma unroll
    for (int i = 0; i < 6; ++i) {
      int col = cbase + i * 8;
      int k = col >> 5, lqw = (col >> 3) & 3;
      *(int4*)(smem + (gi*12 + k)*1024 + (lqw*16 + l15w)*16) = *(const int4*)(src + i*8);
    }
  }
  __syncthreads();

  f32x4 oacc[3][4];
  #pragma unroll
  for (int i = 0; i < 3; ++i)
    #pragma unroll
    for (int j = 0; j < 4; ++j) oacc[i][j] = (f32x4){0.f, 0.f, 0.f, 0.f};

  const unsigned short* w1b = w1P + w * 6144  + l * 8;  // + c*49152 + k*512
  const unsigned short* w2b = w2P + w * 73728 + l * 8;  // + mi*24576 + c*2048 + kk*512

  #define LDV(dst, pV, kk)                                                   \
    { _Pragma("unroll") for (int mi = 0; mi < 3; ++mi)                       \
        dst[mi] = *(const bf16x8*)((pV) + mi * 24576 + (kk) * 512); }

  #define CMPV(buf, kk)                                                      \
    { bf16x8 bv[4];                                                          \
      _Pragma("unroll") for (int ni = 0; ni < 4; ++ni)                       \
        bv[ni] = *(const bf16x8*)(smem + 49152 + (ni*4 + (kk))*1024 + l*16); \
      _Pragma("unroll") for (int mi = 0; mi < 3; ++mi)                       \
        _Pragma("unroll") for (int ni = 0; ni < 4; ++ni)                     \
          oacc[mi][ni] = __builtin_amdgcn_mfma_f32_16x16x32_bf16(            \
              buf[mi], bv[ni], oacc[mi][ni], 0, 0, 0);                       \
    }

  bf16x8 afA[3], afB[3];
  bf16x8 avA[3], avB[3];

  LDA3(afA, w1b, 0)   // prologue: first P-group of chunk 0

  for (int c = 0; c < 12; ++c) {
    const unsigned short* pA = w1b + (size_t)c * 49152;
    const unsigned short* pV = w2b + c * 2048;

    f32x4 pacc[4];
    #pragma unroll
    for (int j = 0; j < 4; ++j) pacc[j] = (f32x4){0.f, 0.f, 0.f, 0.f};

    // P-phase: 4 groups of 3 k-steps, ping-pong prefetch; T5 around MFMA clusters
    LDA3(afB, pA, 3)
    __builtin_amdgcn_s_setprio(1); CMP3(afA, 0, pacc) __builtin_amdgcn_s_setprio(0);
    LDA3(afA, pA, 6)
    __builtin_amdgcn_s_setprio(1); CMP3(afB, 3, pacc) __builtin_amdgcn_s_setprio(0);
    LDA3(afB, pA, 9)
    __builtin_amdgcn_s_setprio(1); CMP3(afA, 6, pacc) __builtin_amdgcn_s_setprio(0);
    LDV(avA, pV, 0)
    __builtin_amdgcn_s_setprio(1); CMP3(afB, 9, pacc) __builtin_amdgcn_s_setprio(0);

    // P epilogue: bias1 + relu + bf16 pack -> Psf
    {
      int fcb = c * 128 + w * 16 + lq * 4;
      float4 bb = *(const float4*)(b1 + fcb);
      unsigned pw = (unsigned)(49152 + (w >> 1) * 1024 +
                    (((w & 1) * 2 + (lq >> 1)) * 16 + l15) * 16 + (lq & 1) * 8);
      #pragma unroll
      for (int ni = 0; ni < 4; ++ni) {
        float p0 = pacc[ni][0] + bb.x;
        float p1 = pacc[ni][1] + bb.y;
        float p2 = pacc[ni][2] + bb.z;
        float p3 = pacc[ni][3] + bb.w;
        ushort4 pk;
        pk.x = f2bf(p0 > 0.f ? p0 : 0.f);
        pk.y = f2bf(p1 > 0.f ? p1 : 0.f);
        pk.z = f2bf(p2 > 0.f ? p2 : 0.f);
        pk.w = f2bf(p3 > 0.f ? p3 : 0.f);
        *(ushort4*)(smem + pw + ni * 4096) = pk;
      }
    }
    BAR_LGKM();   // P ds_writes drained (lgkm); avA global prefetch stays in flight

    const unsigned short* pAn = w1b + (size_t)(c < 11 ? c + 1 : 11) * 49152;
    LDV(avB, pV, 1)
    __builtin_amdgcn_s_setprio(1); CMPV(avA, 0) __builtin_amdgcn_s_setprio(0);
    LDV(avA, pV, 2)
    __builtin_amdgcn_s_setprio(1); CMPV(avB, 1) __builtin_amdgcn_s_setprio(0);
    LDV(avB, pV, 3)
    __builtin_amdgcn_s_setprio(1); CMPV(avA, 2) __builtin_amdgcn_s_setprio(0);
    LDA3(afA, pAn, 0)
    __builtin_amdgcn_s_setprio(1); CMPV(avB, 3) __builtin_amdgcn_s_setprio(0);
    BAR_LGKM();   // PV ds_reads retired (lgkm); afA prefetch for next chunk in flight
  }
  #undef LDV
  #undef CMPV

  // epilogue: out[row][ocol..+3] = oacc + b2 + res  (dwordx4)
  #pragma unroll
  for (int mi = 0; mi < 3; ++mi) {
    int ocb = w * 48 + mi * 16 + lq * 4;
    float4 b2v = *(const float4*)(b2 + ocb);
    #pragma unroll
    for (int ni = 0; ni < 4; ++ni) {
      size_t row = R0 + ni * 16 + l15;
      float* op = out + row * D_ + ocb;
      float4 r = *(const float4*)op;
      float4 o;
      o.x = oacc[mi][ni][0] + b2v.x + r.x;
      o.y = oacc[mi][ni][1] + b2v.y + r.y;
      o.z = oacc[mi][ni][2] + b2v.z + r.z;
      o.w = oacc[mi][ni][3] + b2v.w + r.w;
      *(float4*)op = o;
    }
  }
}

// ---------------- causal attention (+T5 setprio), one block per (b,h) ----------------
__global__ __launch_bounds__(256) void attn_kernel(const unsigned short* __restrict__ q,
                                                   const unsigned short* __restrict__ k,
                                                   const unsigned short* __restrict__ v,
                                                   unsigned short* __restrict__ o) {
  __shared__ __align__(16) char smem[52224];
  unsigned short (*Ks)[72]       = (unsigned short(*)[72])smem;
  unsigned short (*Ps)[32][136]  = (unsigned short(*)[32][136])smem;
  unsigned short (*Vt)[136]      = (unsigned short(*)[136])(smem + 34816);

  int bh = blockIdx.x;
  int b = bh / H_, h = bh % H_;
  int tid = threadIdx.x, w = tid >> 6, l = tid & 63;

  const unsigned short* kb = k + ((size_t)b * T_) * D_ + h * DH_;
  const unsigned short* vb = v + ((size_t)b * T_) * D_ + h * DH_;
  #pragma unroll
  for (int it = 0; it < 4; ++it) {
    int id = it * 256 + tid;
    int s = id >> 3, c8 = (id & 7) * 8;
    int4 kv = *(const int4*)(kb + (size_t)s * D_ + c8);
    *(int4*)(&Ks[s][c8]) = kv;
    int4 vv = *(const int4*)(vb + (size_t)s * D_ + c8);
    const unsigned short* pe = (const unsigned short*)&vv;
    #pragma unroll
    for (int j2 = 0; j2 < 8; ++j2) Vt[c8 + j2][s] = pe[j2];
  }
  __syncthreads();

  const unsigned short* qbp = q + ((size_t)b * T_) * D_ + h * DH_;
  int rowbase = w * 32;
  bf16x8 aq[2][2];
  #pragma unroll
  for (int mi = 0; mi < 2; ++mi)
    #pragma unroll
    for (int ks = 0; ks < 2; ++ks)
      aq[mi][ks] = *(const bf16x8*)(qbp + (size_t)(rowbase + mi*16 + (l & 15)) * D_
                                        + ks*32 + ((l >> 4) << 3));

  f32x4 accs[2][8];
  #pragma unroll
  for (int i = 0; i < 2; ++i)
    #pragma unroll
    for (int j = 0; j < 8; ++j) accs[i][j] = (f32x4){0.f, 0.f, 0.f, 0.f};
  #pragma unroll
  for (int ks = 0; ks < 2; ++ks) {
    bf16x8 bk[8];
    #pragma unroll
    for (int ni = 0; ni < 8; ++ni)
      bk[ni] = *(const bf16x8*)(&Ks[ni*16 + (l & 15)][ks*32 + ((l >> 4) << 3)]);
    __builtin_amdgcn_s_setprio(1);
    #pragma unroll
    for (int mi = 0; mi < 2; ++mi)
      #pragma unroll
      for (int ni = 0; ni < 8; ++ni)
        accs[mi][ni] = __builtin_amdgcn_mfma_f32_16x16x32_bf16(aq[mi][ks], bk[ni], accs[mi][ni], 0, 0, 0);
    __builtin_amdgcn_s_setprio(0);
  }
  __syncthreads();

  #pragma unroll
  for (int mi = 0; mi < 2; ++mi) {
    #pragma unroll
    for (int j = 0; j < 4; ++j) {
      int t = rowbase + mi*16 + ((l >> 4) << 2) + j;
      float mx = -1e30f;
      #pragma unroll
      for (int ni = 0; ni < 8; ++ni) {
        int scol = ni*16 + (l & 15);
        float sv = accs[mi][ni][j] * 0.125f;
        sv = (scol <= t) ? sv : -1e30f;
        accs[mi][ni][j] = sv;
        mx = fmaxf(mx, sv);
      }
      mx = fmaxf(mx, __shfl_xor(mx, 1));
      mx = fmaxf(mx, __shfl_xor(mx, 2));
      mx = fmaxf(mx, __shfl_xor(mx, 4));
      mx = fmaxf(mx, __shfl_xor(mx, 8));
      float sum = 0.f;
      #pragma unroll
      for (int ni = 0; ni < 8; ++ni) {
        float e = __expf(accs[mi][ni][j] - mx);
        accs[mi][ni][j] = e;
        sum += e;
      }
      sum += __shfl_xor(sum, 1);
      sum += __shfl_xor(sum, 2);
      sum += __shfl_xor(sum, 4);
      sum += __shfl_xor(sum, 8);
      float inv = 1.f / sum;
      #pragma unroll
      for (int ni = 0; ni < 8; ++ni)
        Ps[w][mi*16 + ((l >> 4) << 2) + j][ni*16 + (l & 15)] = f2bf(accs[mi][ni][j] * inv);
    }
  }
  __syncthreads();

  f32x4 acco[2][4];
  #pragma unroll
  for (int i = 0; i < 2; ++i)
    #pragma unroll
    for (int j = 0; j < 4; ++j) acco[i][j] = (f32x4){0.f, 0.f, 0.f, 0.f};
  #pragma unroll
  for (int ks = 0; ks < 4; ++ks) {
    bf16x8 ap[2], bv[4];
    #pragma unroll
    for (int mi = 0; mi < 2; ++mi)
      ap[mi] = *(const bf16x8*)(&Ps[w][mi*16 + (l & 15)][ks*32 + ((l >> 4) << 3)]);
    #pragma unroll
    for (int ni = 0; ni < 4; ++ni)
      bv[ni] = *(const bf16x8*)(&Vt[ni*16 + (l & 15)][ks*32 + ((l >> 4) << 3)]);
    __builtin_amdgcn_s_setprio(1);
    #pragma unroll
    for (int mi = 0; mi < 2; ++mi)
      #pragma unroll
      for (int ni = 0; ni < 4; ++ni)
        acco[mi][ni] = __builtin_amdgcn_mfma_f32_16x16x32_bf16(ap[mi], bv[ni], acco[mi][ni], 0, 0, 0);
    __builtin_amdgcn_s_setprio(0);
  }

  unsigned short* ob = o + ((size_t)b * T_) * D_ + h * DH_;
  #pragma unroll
  for (int mi = 0; mi < 2; ++mi)
    #pragma unroll
    for (int ni = 0; ni < 4; ++ni)
      #pragma unroll
      for (int j = 0; j < 4; ++j) {
        int t = rowbase + mi*16 + ((l >> 4) << 2) + j;
        int d = ni*16 + (l & 15);
        ob[(size_t)t * D_ + d] = f2bf(acco[mi][ni][j]);
      }
}

extern "C" void kernel_launch(void* const* d_in, const int* in_sizes, int n_in,
                              void* d_out, int out_size, void* d_ws, size_t ws_size,
                              hipStream_t stream) {
  const float* x   = (const float*)d_in[0];
  const float* Wq  = (const float*)d_in[1];
  const float* Wk  = (const float*)d_in[2];
  const float* Wv  = (const float*)d_in[3];
  const float* Wo  = (const float*)d_in[4];
  const float* bo  = (const float*)d_in[5];
  const float* W1  = (const float*)d_in[6];
  const float* b1  = (const float*)d_in[7];
  const float* W2  = (const float*)d_in[8];
  const float* b2  = (const float*)d_in[9];
  const float* g1  = (const float*)d_in[10];
  const float* be1 = (const float*)d_in[11];
  const float* g2  = (const float*)d_in[12];
  const float* be2 = (const float*)d_in[13];

  // workspace layout (bytes); total ~207 MiB  (R13 layout)
  char* ws = (char*)d_ws;
  unsigned short* hb   = (unsigned short*)(ws);               // h (LN1), later h2 (LN2)
  unsigned short* qb   = (unsigned short*)(ws +  50331648);   // q|k|v contiguous; o in-place
  unsigned short* kbuf = (unsigned short*)(ws + 100663296);
  unsigned short* vbuf = (unsigned short*)(ws + 150994944);
  unsigned short* wqT  = (unsigned short*)(ws + 201326592);   // [1152][384] (wq|wk|wv)
  unsigned short* wkT  = wqT + 147456;
  unsigned short* wvT  = wkT + 147456;
  unsigned short* woT  = wvT + 147456;                        // [384][384]
  unsigned short* w1T  = woT + 147456;                        // [1536][384]
  unsigned short* w2T  = w1T + 589824;                        // [384][1536]
  unsigned short* w1P  = w2T + 589824;                        // packed frag-order
  unsigned short* w2P  = w1P + 589824;
  float* x2 = (float*)d_out;
  (void)kbuf; (void)vbuf;

  // 1) weight convert+transpose (tiny) + fragment-order packs (FFN weights)
  wt_kernel<<<dim3(576),  256, 0, stream>>>(Wq, wqT, 384, 384);
  wt_kernel<<<dim3(576),  256, 0, stream>>>(Wk, wkT, 384, 384);
  wt_kernel<<<dim3(576),  256, 0, stream>>>(Wv, wvT, 384, 384);
  wt_kernel<<<dim3(576),  256, 0, stream>>>(Wo, woT, 384, 384);
  wt_kernel<<<dim3(2304), 256, 0, stream>>>(W1, w1T, 384, 1536);
  wt_kernel<<<dim3(2304), 256, 0, stream>>>(W2, w2T, 1536, 384);
  pack_w1<<<dim3(288), 256, 0, stream>>>(w1T, w1P);
  pack_w2<<<dim3(288), 256, 0, stream>>>(w2T, w2P);

  // 2) LN1: x -> h (bf16)
  ln_kernel<<<dim3(NROW / 4), 256, 0, stream>>>(x, g1, be1, hb);

  // 3) fused q|k|v = h @ [Wq|Wk|Wv]  (N=1152; T1 XCD swizzle; nwg=4608 %8==0)
  gemm_bt<3><<<dim3(NROW / 128, 9), 256, 0, stream>>>(hb, wqT, qb, nullptr, nullptr, 1152, 384);

  // 4) attention: o overwrites q in place (per-block disjoint strips)
  attn_kernel<<<dim3(B_ * H_), 256, 0, stream>>>(qb, kbuf, vbuf, qb);

  // 5) x2 = x + o @ Wo + bo   (fp32, into d_out; T1 swizzle; nwg=1536 %8==0)
  gemm_bt<1><<<dim3(NROW / 128, 3), 256, 0, stream>>>(qb, woT, x2, bo, x, 384, 384);

  // 6) LN2: x2 -> h2 (bf16, into hb)
  ln_kernel<<<dim3(NROW / 4), 256, 0, stream>>>((const float*)x2, g2, be2, hb);

  // 7) fused FFN (8-wave + setprio + lgkm-barriers): out = x2 + relu(h2@W1+b1)@W2 + b2
  ffn_fused<<<dim3(NROW / 64), 512, 0, stream>>>(hb, w1P, w2P, b1, b2, x2);
}

// Round 17
// 442.240 us; speedup vs baseline: 2.1123x; 1.0109x over previous
//
#include <hip/hip_runtime.h>

// Problem constants
#define B_   512
#define T_   128
#define D_   384
#define H_   6
#define DH_  64
#define DFF_ 1536
#define NROW (B_*T_)   // 65536 rows

typedef __attribute__((ext_vector_type(8))) short bf16x8;   // MFMA A/B frag (4 VGPRs)
typedef __attribute__((ext_vector_type(4))) float f32x4;    // MFMA C/D frag

__device__ __forceinline__ unsigned short f2bf(float f) {
  union { float f; unsigned u; } v; v.f = f;
  unsigned r = v.u + 0x7fffu + ((v.u >> 16) & 1u);   // RNE
  return (unsigned short)(r >> 16);
}

// async global->LDS, 16 B per lane, wave-uniform LDS base (m97 pattern)
#define GLDS16(gp, lp)                                                     \
  __builtin_amdgcn_global_load_lds(                                        \
      (const __attribute__((address_space(1))) void*)(gp),                 \
      (__attribute__((address_space(3))) void*)(lp), 16, 0, 0)

// lgkm-only barrier (keeps reg-destined global loads in flight)
#define BAR_LGKM() asm volatile("s_waitcnt lgkmcnt(0)\n\ts_barrier" ::: "memory")

// ---------------- weight transpose + fp32->bf16 convert ----------------
__global__ void wt_kernel(const float* __restrict__ W, unsigned short* __restrict__ WT,
                          int K, int Nn) {
  int id = blockIdx.x * 256 + threadIdx.x;
  if (id >= K * Nn) return;
  int n = id % Nn, kk = id / Nn;               // coalesced read along n
  WT[(size_t)n * K + kk] = f2bf(W[(size_t)kk * Nn + n]);
}

// ---------------- fragment-order weight packing (K=384 weights, any NC) -------------
// frag=(c*8+w8)*12+k ; lane 16B = WT[c*128+w8*16+l15][k*32+lq*8]
__global__ void pack_w1(const unsigned short* __restrict__ W1T,  // [NC*128][384]
                        unsigned short* __restrict__ W1P) {
  int tid = blockIdx.x * 256 + threadIdx.x;      // NC*128*384/8 16B-chunks
  int lane = tid & 63, frag = tid >> 6;
  int k = frag % 12, t2 = frag / 12;
  int mi = t2 & 1, t3 = t2 >> 1;
  int w = t3 & 3, c = t3 >> 2;
  int l15 = lane & 15, lq = lane >> 4;
  int r = c * 128 + w * 32 + mi * 16 + l15;
  int col = k * 32 + lq * 8;
  *(int4*)(W1P + (size_t)tid * 8) = *(const int4*)(W1T + (size_t)r * 384 + col);
}
// W2 (K=1536): frag=(((w4*6+mi6)*12+c)*4+kk)
__global__ void pack_w2(const unsigned short* __restrict__ W2T,  // [384][1536]
                        unsigned short* __restrict__ W2P) {
  int tid = blockIdx.x * 256 + threadIdx.x;      // 73728 16B-chunks (288 blocks)
  int lane = tid & 63, frag = tid >> 6;
  int kk = frag & 3, t2 = frag >> 2;
  int c = t2 % 12, t3 = t2 / 12;
  int mi = t3 % 6, w = t3 / 6;
  int l15 = lane & 15, lq = lane >> 4;
  int r = w * 96 + mi * 16 + l15;
  int col = c * 128 + kk * 32 + lq * 8;
  *(int4*)(W2P + (size_t)tid * 8) = *(const int4*)(W2T + (size_t)r * 1536 + col);
}

// ---------------- layernorm: fp32 in -> bf16 out (one wave per row) ----------------
__global__ __launch_bounds__(256) void ln_kernel(const float* __restrict__ x,
                                                 const float* __restrict__ g,
                                                 const float* __restrict__ be,
                                                 unsigned short* __restrict__ out) {
  int row = (blockIdx.x * 256 + threadIdx.x) >> 6;
  int l = threadIdx.x & 63;
  const float* xr = x + (size_t)row * D_;
  float v[6]; float s = 0.f, ss = 0.f;
  #pragma unroll
  for (int i = 0; i < 6; ++i) { v[i] = xr[l + i*64]; s += v[i]; ss += v[i]*v[i]; }
  #pragma unroll
  for (int m = 1; m < 64; m <<= 1) { s += __shfl_xor(s, m); ss += __shfl_xor(ss, m); }
  float mu  = s * (1.f / D_);
  float var = ss * (1.f / D_) - mu * mu;
  float rs  = rsqrtf(var + 1e-5f);
  unsigned short* orow = out + (size_t)row * D_;
  #pragma unroll
  for (int i = 0; i < 6; ++i) {
    int c = l + i*64;
    orow[c] = f2bf((v[i] - mu) * rs * g[c] + be[c]);
  }
}

// ---------------- QKV GEMM v3 (32-row block, k-outer, deferred epilogue) ------------
// Mechanism fixes vs R11/R15 failures:
//  * zero global writes during the weight stream -> wqkvP (0.88 MB) stays L2-resident
//  * k-outer loop: h B-frags read once per k (24 LDS reads/wave total)
//  * epilogue LDS-transpose -> 16 B/lane full-sector stores (no write amplification)
// Accumulation per (c,ni) is k-ascending: numerics identical to R11 (passed).
__global__ __launch_bounds__(512, 4) void qkv_gemm(
    const unsigned short* __restrict__ h, const unsigned short* __restrict__ wP,
    unsigned short* __restrict__ qkv)
{
  __shared__ __align__(16) char smem[25600];   // staging 24576 | transpose 32x784
  int tid = threadIdx.x, w = tid >> 6, l = tid & 63;
  int l15 = l & 15, lq = l >> 4;
  size_t R0 = (size_t)blockIdx.x * 32;

  // ---- stage h strip (32 rows) -> frag-order LDS: 512 thr x 3 int4 ----
  {
    int row = tid >> 4, gi = row >> 4, l15w = row & 15;
    const unsigned short* src = h + (R0 + row) * 384 + (tid & 15) * 24;
    #pragma unroll
    for (int i = 0; i < 3; ++i) {
      int col = (tid & 15) * 24 + i * 8;
      int k = col >> 5, lqw = (col >> 3) & 3;
      *(int4*)(smem + (gi*12 + k)*1024 + (lqw*16 + l15w)*16) = *(const int4*)(src + i*8);
    }
  }
  __syncthreads();

  f32x4 acc[9][2];
  #pragma unroll
  for (int c = 0; c < 9; ++c)
    #pragma unroll
    for (int ni = 0; ni < 2; ++ni) acc[c][ni] = (f32x4){0.f, 0.f, 0.f, 0.f};

  const unsigned short* wb = wP + l * 8;       // + ((c*8+w)*12 + k)*512

  #define LDG(dst, cb, k)                                                    \
    { _Pragma("unroll") for (int ci = 0; ci < 3; ++ci)                       \
        dst[ci] = *(const bf16x8*)(wb + (((cb)+ci)*8 + w) * 6144 + (k) * 512); }

  #define CMPG(buf, cb)                                                      \
    { _Pragma("unroll") for (int ci = 0; ci < 3; ++ci)                       \
        _Pragma("unroll") for (int ni = 0; ni < 2; ++ni)                     \
          acc[(cb)+ci][ni] = __builtin_amdgcn_mfma_f32_16x16x32_bf16(        \
              buf[ci], bfr[ni], acc[(cb)+ci][ni], 0, 0, 0); }

  bf16x8 a0[3], a1[3], a2[3];
  LDG(a0, 0, 0)                                // preload k=0 group 0

  for (int k = 0; k < 12; ++k) {
    bf16x8 bfr[2];
    #pragma unroll
    for (int ni = 0; ni < 2; ++ni)
      bfr[ni] = *(const bf16x8*)(smem + (ni*12 + k)*1024 + l*16);
    int kn = (k < 11) ? k + 1 : 11;
    LDG(a1, 3, k)
    __builtin_amdgcn_s_setprio(1); CMPG(a0, 0) __builtin_amdgcn_s_setprio(0);
    LDG(a2, 6, k)
    __builtin_amdgcn_s_setprio(1); CMPG(a1, 3) __builtin_amdgcn_s_setprio(0);
    LDG(a0, 0, kn)
    __builtin_amdgcn_s_setprio(1); CMPG(a2, 6) __builtin_amdgcn_s_setprio(0);
  }
  #undef LDG
  #undef CMPG

  // ---- deferred epilogue: per buffer (q,k,v): acc -> LDS (784B rows) -> int4 stores
  __syncthreads();                              // staging region dead; reads drained
  #pragma unroll
  for (int buf = 0; buf < 3; ++buf) {
    #pragma unroll
    for (int ci = 0; ci < 3; ++ci) {
      int c = buf * 3 + ci;
      #pragma unroll
      for (int ni = 0; ni < 2; ++ni) {
        int row = ni * 16 + l15;
        ushort4 pk;
        pk.x = f2bf(acc[c][ni][0]);
        pk.y = f2bf(acc[c][ni][1]);
        pk.z = f2bf(acc[c][ni][2]);
        pk.w = f2bf(acc[c][ni][3]);
        *(ushort4*)(smem + row * 784 + ci * 256 + w * 32 + lq * 8) = pk;
      }
    }
    __syncthreads();
    {
      int row = tid >> 4;
      unsigned short* obase = qkv + (size_t)buf * NROW * 384 + (R0 + row) * 384;
      #pragma unroll
      for (int i = 0; i < 3; ++i) {
        int ob = (tid & 15) * 16 + i * 256;     // byte offset in 768-B row
        *(int4*)(obase + (ob >> 1)) = *(const int4*)(smem + row * 784 + ob);
      }
    }
    __syncthreads();
  }
}

// ---------------- NT GEMM (Wo): 2-phase dbuf, gload_lds + T1 swizzle (R16-proven) ---
// EPI 1: += bias[col] + res[row,col], store fp32
template<int EPI>
__global__ __launch_bounds__(256) void gemm_bt(const unsigned short* __restrict__ A,
                                               const unsigned short* __restrict__ BT,
                                               void* __restrict__ Cc,
                                               const float* __restrict__ bias,
                                               const float* __restrict__ res,
                                               int Nn, int K) {
  __shared__ unsigned short As[2][128][32];
  __shared__ unsigned short Bs[2][128][32];
  int tid = threadIdx.x, w = tid >> 6, l = tid & 63;
  int wr = w >> 1, wc = w & 1;

  int ncol = gridDim.y;
  int nwg  = gridDim.x * ncol;
  int lin  = blockIdx.y * gridDim.x + blockIdx.x;
  int cpx  = nwg >> 3;
  int swz  = (lin & 7) * cpx + (lin >> 3);
  size_t R0 = (size_t)(swz / ncol) * 128;
  int C0 = (swz % ncol) * 128;

  int seg0 = (w * 2 + 0) * 16;
  int seg1 = (w * 2 + 1) * 16;
  int srow0 = seg0 + (l >> 2);
  int srow1 = seg1 + (l >> 2);
  int scol  = (l & 3) * 8;

  const unsigned short* ga0 = A  + (R0 + srow0) * K + scol;
  const unsigned short* ga1 = A  + (R0 + srow1) * K + scol;
  const unsigned short* gb0 = BT + (size_t)(C0 + srow0) * K + scol;
  const unsigned short* gb1 = BT + (size_t)(C0 + srow1) * K + scol;

  f32x4 acc[4][4];
  #pragma unroll
  for (int i = 0; i < 4; ++i)
    #pragma unroll
    for (int j = 0; j < 4; ++j) acc[i][j] = (f32x4){0.f, 0.f, 0.f, 0.f};

  GLDS16(ga0, &As[0][seg0][0]);
  GLDS16(ga1, &As[0][seg1][0]);
  GLDS16(gb0, &Bs[0][seg0][0]);
  GLDS16(gb1, &Bs[0][seg1][0]);
  ga0 += 32; ga1 += 32; gb0 += 32; gb1 += 32;

  int nk = K >> 5;
  for (int t = 0; t < nk; ++t) {
    int cur = t & 1;
    __syncthreads();
    if (t + 1 < nk) {
      GLDS16(ga0, &As[cur ^ 1][seg0][0]);
      GLDS16(ga1, &As[cur ^ 1][seg1][0]);
      GLDS16(gb0, &Bs[cur ^ 1][seg0][0]);
      GLDS16(gb1, &Bs[cur ^ 1][seg1][0]);
      ga0 += 32; ga1 += 32; gb0 += 32; gb1 += 32;
    }
    bf16x8 af[4], bf[4];
    #pragma unroll
    for (int mi = 0; mi < 4; ++mi)
      af[mi] = *(const bf16x8*)(&As[cur][wr*64 + mi*16 + (l & 15)][(l >> 4) * 8]);
    #pragma unroll
    for (int ni = 0; ni < 4; ++ni)
      bf[ni] = *(const bf16x8*)(&Bs[cur][wc*64 + ni*16 + (l & 15)][(l >> 4) * 8]);
    #pragma unroll
    for (int mi = 0; mi < 4; ++mi)
      #pragma unroll
      for (int ni = 0; ni < 4; ++ni)
        acc[mi][ni] = __builtin_amdgcn_mfma_f32_16x16x32_bf16(af[mi], bf[ni], acc[mi][ni], 0, 0, 0);
  }

  #pragma unroll
  for (int mi = 0; mi < 4; ++mi) {
    #pragma unroll
    for (int ni = 0; ni < 4; ++ni) {
      int col = C0 + wc*64 + ni*16 + (l & 15);
      #pragma unroll
      for (int j = 0; j < 4; ++j) {
        size_t row = R0 + wr*64 + mi*16 + ((l >> 4) << 2) + j;
        float vv = acc[mi][ni][j];
        ((float*)Cc)[row * Nn + col] = vv + bias[col] + res[row * Nn + col];
      }
    }
  }
}

// ======== 8-wave ffn building blocks (frag-order LDS + packed W) ========
#define LDA3(dst, pA, k0)                                                    \
  { _Pragma("unroll") for (int kq = 0; kq < 3; ++kq)                         \
      dst[kq] = *(const bf16x8*)((pA) + ((k0) + kq) * 512); }

#define CMP3(buf, k0, acc)                                                   \
  { _Pragma("unroll") for (int kq = 0; kq < 3; ++kq) {                       \
      bf16x8 bfr[4];                                                         \
      _Pragma("unroll") for (int ni = 0; ni < 4; ++ni)                       \
        bfr[ni] = *(const bf16x8*)(smem + (ni*12 + (k0)+kq)*1024 + l*16);    \
      _Pragma("unroll") for (int ni = 0; ni < 4; ++ni)                       \
        acc[ni] = __builtin_amdgcn_mfma_f32_16x16x32_bf16(                   \
            buf[kq], bfr[ni], acc[ni], 0, 0, 0);                             \
    } }

// ---------------- fused FFN (8-wave + T5 setprio + lgkm barriers; R13-proven) -------
__global__ __launch_bounds__(512, 4) void ffn_fused(
    const unsigned short* __restrict__ h2,   // [NROW][384] bf16
    const unsigned short* __restrict__ w1P,  // packed (pack_w1)
    const unsigned short* __restrict__ w2P,  // packed (pack_w2)
    const float* __restrict__ b1,            // [1536]
    const float* __restrict__ b2,            // [384]
    float* __restrict__ out)                 // [NROW][384] fp32, in-place residual add
{
  __shared__ __align__(16) char smem[65536];
  int tid = threadIdx.x, w = tid >> 6, l = tid & 63;
  int l15 = l & 15, lq = l >> 4;
  size_t R0 = (size_t)blockIdx.x * 64;

  // ---- stage h2 strip -> frag-order LDS (512 thr x 48 elems) ----
  {
    int row = tid >> 3, gi = row >> 4, l15w = row & 15;
    int cbase = (tid & 7) * 48;
    const unsigned short* src = h2 + (R0 + row) * 384 + cbase;
    #pragma unroll
    for (int i = 0; i < 6; ++i) {
      int col = cbase + i * 8;
      int k = col >> 5, lqw = (col >> 3) & 3;
      *(int4*)(smem + (gi*12 + k)*1024 + (lqw*16 + l15w)*16) = *(const int4*)(src + i*8);
    }
  }
  __syncthreads();

  f32x4 oacc[3][4];
  #pragma unroll
  for (int i = 0; i < 3; ++i)
    #pragma unroll
    for (int j = 0; j < 4; ++j) oacc[i][j] = (f32x4){0.f, 0.f, 0.f, 0.f};

  const unsigned short* w1b = w1P + w * 6144  + l * 8;  // + c*49152 + k*512
  const unsigned short* w2b = w2P + w * 73728 + l * 8;  // + mi*24576 + c*2048 + kk*512

  #define LDV(dst, pV, kk)                                                   \
    { _Pragma("unroll") for (int mi = 0; mi < 3; ++mi)                       \
        dst[mi] = *(const bf16x8*)((pV) + mi * 24576 + (kk) * 512); }

  #define CMPV(buf, kk)                                                      \
    { bf16x8 bv[4];                                                          \
      _Pragma("unroll") for (int ni = 0; ni < 4; ++ni)                       \
        bv[ni] = *(const bf16x8*)(smem + 49152 + (ni*4 + (kk))*1024 + l*16); \
      _Pragma("unroll") for (int mi = 0; mi < 3; ++mi)                       \
        _Pragma("unroll") for (int ni = 0; ni < 4; ++ni)                     \
          oacc[mi][ni] = __builtin_amdgcn_mfma_f32_16x16x32_bf16(            \
              buf[mi], bv[ni], oacc[mi][ni], 0, 0, 0);                       \
    }

  bf16x8 afA[3], afB[3];
  bf16x8 avA[3], avB[3];

  LDA3(afA, w1b, 0)   // prologue: first P-group of chunk 0

  for (int c = 0; c < 12; ++c) {
    const unsigned short* pA = w1b + (size_t)c * 49152;
    const unsigned short* pV = w2b + c * 2048;

    f32x4 pacc[4];
    #pragma unroll
    for (int j = 0; j < 4; ++j) pacc[j] = (f32x4){0.f, 0.f, 0.f, 0.f};

    // P-phase: 4 groups of 3 k-steps, ping-pong prefetch; T5 around MFMA clusters
    LDA3(afB, pA, 3)
    __builtin_amdgcn_s_setprio(1); CMP3(afA, 0, pacc) __builtin_amdgcn_s_setprio(0);
    LDA3(afA, pA, 6)
    __builtin_amdgcn_s_setprio(1); CMP3(afB, 3, pacc) __builtin_amdgcn_s_setprio(0);
    LDA3(afB, pA, 9)
    __builtin_amdgcn_s_setprio(1); CMP3(afA, 6, pacc) __builtin_amdgcn_s_setprio(0);
    LDV(avA, pV, 0)
    __builtin_amdgcn_s_setprio(1); CMP3(afB, 9, pacc) __builtin_amdgcn_s_setprio(0);

    // P epilogue: bias1 + relu + bf16 pack -> Psf
    {
      int fcb = c * 128 + w * 16 + lq * 4;
      float4 bb = *(const float4*)(b1 + fcb);
      unsigned pw = (unsigned)(49152 + (w >> 1) * 1024 +
                    (((w & 1) * 2 + (lq >> 1)) * 16 + l15) * 16 + (lq & 1) * 8);
      #pragma unroll
      for (int ni = 0; ni < 4; ++ni) {
        float p0 = pacc[ni][0] + bb.x;
        float p1 = pacc[ni][1] + bb.y;
        float p2 = pacc[ni][2] + bb.z;
        float p3 = pacc[ni][3] + bb.w;
        ushort4 pk;
        pk.x = f2bf(p0 > 0.f ? p0 : 0.f);
        pk.y = f2bf(p1 > 0.f ? p1 : 0.f);
        pk.z = f2bf(p2 > 0.f ? p2 : 0.f);
        pk.w = f2bf(p3 > 0.f ? p3 : 0.f);
        *(ushort4*)(smem + pw + ni * 4096) = pk;
      }
    }
    BAR_LGKM();   // P ds_writes drained (lgkm); avA global prefetch stays in flight

    const unsigned short* pAn = w1b + (size_t)(c < 11 ? c + 1 : 11) * 49152;
    LDV(avB, pV, 1)
    __builtin_amdgcn_s_setprio(1); CMPV(avA, 0) __builtin_amdgcn_s_setprio(0);
    LDV(avA, pV, 2)
    __builtin_amdgcn_s_setprio(1); CMPV(avB, 1) __builtin_amdgcn_s_setprio(0);
    LDV(avB, pV, 3)
    __builtin_amdgcn_s_setprio(1); CMPV(avA, 2) __builtin_amdgcn_s_setprio(0);
    LDA3(afA, pAn, 0)
    __builtin_amdgcn_s_setprio(1); CMPV(avB, 3) __builtin_amdgcn_s_setprio(0);
    BAR_LGKM();   // PV ds_reads retired (lgkm); afA prefetch for next chunk in flight
  }
  #undef LDV
  #undef CMPV

  // epilogue: out[row][ocol..+3] = oacc + b2 + res  (dwordx4)
  #pragma unroll
  for (int mi = 0; mi < 3; ++mi) {
    int ocb = w * 48 + mi * 16 + lq * 4;
    float4 b2v = *(const float4*)(b2 + ocb);
    #pragma unroll
    for (int ni = 0; ni < 4; ++ni) {
      size_t row = R0 + ni * 16 + l15;
      float* op = out + row * D_ + ocb;
      float4 r = *(const float4*)op;
      float4 o;
      o.x = oacc[mi][ni][0] + b2v.x + r.x;
      o.y = oacc[mi][ni][1] + b2v.y + r.y;
      o.z = oacc[mi][ni][2] + b2v.z + r.z;
      o.w = oacc[mi][ni][3] + b2v.w + r.w;
      *(float4*)op = o;
    }
  }
}

// ---------------- causal attention (+T5 setprio), one block per (b,h) ----------------
__global__ __launch_bounds__(256) void attn_kernel(const unsigned short* __restrict__ q,
                                                   const unsigned short* __restrict__ k,
                                                   const unsigned short* __restrict__ v,
                                                   unsigned short* __restrict__ o) {
  __shared__ __align__(16) char smem[52224];
  unsigned short (*Ks)[72]       = (unsigned short(*)[72])smem;
  unsigned short (*Ps)[32][136]  = (unsigned short(*)[32][136])smem;
  unsigned short (*Vt)[136]      = (unsigned short(*)[136])(smem + 34816);

  int bh = blockIdx.x;
  int b = bh / H_, h = bh % H_;
  int tid = threadIdx.x, w = tid >> 6, l = tid & 63;

  const unsigned short* kb = k + ((size_t)b * T_) * D_ + h * DH_;
  const unsigned short* vb = v + ((size_t)b * T_) * D_ + h * DH_;
  #pragma unroll
  for (int it = 0; it < 4; ++it) {
    int id = it * 256 + tid;
    int s = id >> 3, c8 = (id & 7) * 8;
    int4 kv = *(const int4*)(kb + (size_t)s * D_ + c8);
    *(int4*)(&Ks[s][c8]) = kv;
    int4 vv = *(const int4*)(vb + (size_t)s * D_ + c8);
    const unsigned short* pe = (const unsigned short*)&vv;
    #pragma unroll
    for (int j2 = 0; j2 < 8; ++j2) Vt[c8 + j2][s] = pe[j2];
  }
  __syncthreads();

  const unsigned short* qbp = q + ((size_t)b * T_) * D_ + h * DH_;
  int rowbase = w * 32;
  bf16x8 aq[2][2];
  #pragma unroll
  for (int mi = 0; mi < 2; ++mi)
    #pragma unroll
    for (int ks = 0; ks < 2; ++ks)
      aq[mi][ks] = *(const bf16x8*)(qbp + (size_t)(rowbase + mi*16 + (l & 15)) * D_
                                        + ks*32 + ((l >> 4) << 3));

  f32x4 accs[2][8];
  #pragma unroll
  for (int i = 0; i < 2; ++i)
    #pragma unroll
    for (int j = 0; j < 8; ++j) accs[i][j] = (f32x4){0.f, 0.f, 0.f, 0.f};
  #pragma unroll
  for (int ks = 0; ks < 2; ++ks) {
    bf16x8 bk[8];
    #pragma unroll
    for (int ni = 0; ni < 8; ++ni)
      bk[ni] = *(const bf16x8*)(&Ks[ni*16 + (l & 15)][ks*32 + ((l >> 4) << 3)]);
    __builtin_amdgcn_s_setprio(1);
    #pragma unroll
    for (int mi = 0; mi < 2; ++mi)
      #pragma unroll
      for (int ni = 0; ni < 8; ++ni)
        accs[mi][ni] = __builtin_amdgcn_mfma_f32_16x16x32_bf16(aq[mi][ks], bk[ni], accs[mi][ni], 0, 0, 0);
    __builtin_amdgcn_s_setprio(0);
  }
  __syncthreads();

  #pragma unroll
  for (int mi = 0; mi < 2; ++mi) {
    #pragma unroll
    for (int j = 0; j < 4; ++j) {
      int t = rowbase + mi*16 + ((l >> 4) << 2) + j;
      float mx = -1e30f;
      #pragma unroll
      for (int ni = 0; ni < 8; ++ni) {
        int scol = ni*16 + (l & 15);
        float sv = accs[mi][ni][j] * 0.125f;
        sv = (scol <= t) ? sv : -1e30f;
        accs[mi][ni][j] = sv;
        mx = fmaxf(mx, sv);
      }
      mx = fmaxf(mx, __shfl_xor(mx, 1));
      mx = fmaxf(mx, __shfl_xor(mx, 2));
      mx = fmaxf(mx, __shfl_xor(mx, 4));
      mx = fmaxf(mx, __shfl_xor(mx, 8));
      float sum = 0.f;
      #pragma unroll
      for (int ni = 0; ni < 8; ++ni) {
        float e = __expf(accs[mi][ni][j] - mx);
        accs[mi][ni][j] = e;
        sum += e;
      }
      sum += __shfl_xor(sum, 1);
      sum += __shfl_xor(sum, 2);
      sum += __shfl_xor(sum, 4);
      sum += __shfl_xor(sum, 8);
      float inv = 1.f / sum;
      #pragma unroll
      for (int ni = 0; ni < 8; ++ni)
        Ps[w][mi*16 + ((l >> 4) << 2) + j][ni*16 + (l & 15)] = f2bf(accs[mi][ni][j] * inv);
    }
  }
  __syncthreads();

  f32x4 acco[2][4];
  #pragma unroll
  for (int i = 0; i < 2; ++i)
    #pragma unroll
    for (int j = 0; j < 4; ++j) acco[i][j] = (f32x4){0.f, 0.f, 0.f, 0.f};
  #pragma unroll
  for (int ks = 0; ks < 4; ++ks) {
    bf16x8 ap[2], bv[4];
    #pragma unroll
    for (int mi = 0; mi < 2; ++mi)
      ap[mi] = *(const bf16x8*)(&Ps[w][mi*16 + (l & 15)][ks*32 + ((l >> 4) << 3)]);
    #pragma unroll
    for (int ni = 0; ni < 4; ++ni)
      bv[ni] = *(const bf16x8*)(&Vt[ni*16 + (l & 15)][ks*32 + ((l >> 4) << 3)]);
    __builtin_amdgcn_s_setprio(1);
    #pragma unroll
    for (int mi = 0; mi < 2; ++mi)
      #pragma unroll
      for (int ni = 0; ni < 4; ++ni)
        acco[mi][ni] = __builtin_amdgcn_mfma_f32_16x16x32_bf16(ap[mi], bv[ni], acco[mi][ni], 0, 0, 0);
    __builtin_amdgcn_s_setprio(0);
  }

  unsigned short* ob = o + ((size_t)b * T_) * D_ + h * DH_;
  #pragma unroll
  for (int mi = 0; mi < 2; ++mi)
    #pragma unroll
    for (int ni = 0; ni < 4; ++ni)
      #pragma unroll
      for (int j = 0; j < 4; ++j) {
        int t = rowbase + mi*16 + ((l >> 4) << 2) + j;
        int d = ni*16 + (l & 15);
        ob[(size_t)t * D_ + d] = f2bf(acco[mi][ni][j]);
      }
}

extern "C" void kernel_launch(void* const* d_in, const int* in_sizes, int n_in,
                              void* d_out, int out_size, void* d_ws, size_t ws_size,
                              hipStream_t stream) {
  const float* x   = (const float*)d_in[0];
  const float* Wq  = (const float*)d_in[1];
  const float* Wk  = (const float*)d_in[2];
  const float* Wv  = (const float*)d_in[3];
  const float* Wo  = (const float*)d_in[4];
  const float* bo  = (const float*)d_in[5];
  const float* W1  = (const float*)d_in[6];
  const float* b1  = (const float*)d_in[7];
  const float* W2  = (const float*)d_in[8];
  const float* b2  = (const float*)d_in[9];
  const float* g1  = (const float*)d_in[10];
  const float* be1 = (const float*)d_in[11];
  const float* g2  = (const float*)d_in[12];
  const float* be2 = (const float*)d_in[13];

  // workspace layout (bytes); total ~209 MiB
  char* ws = (char*)d_ws;
  unsigned short* hb    = (unsigned short*)(ws);               // h (LN1), later h2 (LN2)
  unsigned short* qb    = (unsigned short*)(ws +  50331648);   // q|k|v contiguous; o in-place
  unsigned short* kbuf  = (unsigned short*)(ws + 100663296);
  unsigned short* vbuf  = (unsigned short*)(ws + 150994944);
  unsigned short* wqT   = (unsigned short*)(ws + 201326592);   // [1152][384] (wq|wk|wv)
  unsigned short* woT   = wqT + 442368;                        // [384][384]
  unsigned short* w1T   = woT + 147456;                        // [1536][384]
  unsigned short* w2T   = w1T + 589824;                        // [384][1536]
  unsigned short* w1P   = w2T + 589824;                        // packed (pack_w1, NC=12)
  unsigned short* w2P   = w1P + 589824;                        // packed (pack_w2)
  unsigned short* wqkvP = w2P + 589824;                        // packed (pack_w1, NC=9)
  float* x2 = (float*)d_out;
  (void)kbuf; (void)vbuf;

  // 1) weight convert+transpose (tiny) + fragment-order packs
  wt_kernel<<<dim3(576),  256, 0, stream>>>(Wq, wqT,          384, 384);
  wt_kernel<<<dim3(576),  256, 0, stream>>>(Wk, wqT + 147456, 384, 384);
  wt_kernel<<<dim3(576),  256, 0, stream>>>(Wv, wqT + 294912, 384, 384);
  wt_kernel<<<dim3(576),  256, 0, stream>>>(Wo, woT,          384, 384);
  wt_kernel<<<dim3(2304), 256, 0, stream>>>(W1, w1T, 384, 1536);
  wt_kernel<<<dim3(2304), 256, 0, stream>>>(W2, w2T, 1536, 384);
  pack_w1<<<dim3(216), 256, 0, stream>>>(wqT, wqkvP);   // NC=9
  pack_w1<<<dim3(288), 256, 0, stream>>>(w1T, w1P);     // NC=12
  pack_w2<<<dim3(288), 256, 0, stream>>>(w2T, w2P);

  // 2) LN1: x -> h (bf16)
  ln_kernel<<<dim3(NROW / 4), 256, 0, stream>>>(x, g1, be1, hb);

  // 3) QKV GEMM v3 (32-row blocks, deferred epilogue): q|k|v = h @ [Wq|Wk|Wv]
  qkv_gemm<<<dim3(NROW / 32), 512, 0, stream>>>(hb, wqkvP, qb);

  // 4) attention: o overwrites q in place (per-block disjoint strips)
  attn_kernel<<<dim3(B_ * H_), 256, 0, stream>>>(qb, kbuf, vbuf, qb);

  // 5) x2 = x + o @ Wo + bo   (fp32, into d_out; T1 swizzle; nwg=1536 %8==0)
  gemm_bt<1><<<dim3(NROW / 128, 3), 256, 0, stream>>>(qb, woT, x2, bo, x, 384, 384);

  // 6) LN2: x2 -> h2 (bf16, into hb)
  ln_kernel<<<dim3(NROW / 4), 256, 0, stream>>>((const float*)x2, g2, be2, hb);

  // 7) fused FFN (8-wave + setprio + lgkm-barriers): out = x2 + relu(h2@W1+b1)@W2 + b2
  ffn_fused<<<dim3(NROW / 64), 512, 0, stream>>>(hb, w1P, w2P, b1, b2, x2);
}

// Round 18
// 438.797 us; speedup vs baseline: 2.1289x; 1.0078x over previous
//
#include <hip/hip_runtime.h>

// Problem constants
#define B_   512
#define T_   128
#define D_   384
#define H_   6
#define DH_  64
#define DFF_ 1536
#define NROW (B_*T_)   // 65536 rows

typedef __attribute__((ext_vector_type(8))) short bf16x8;   // MFMA A/B frag (4 VGPRs)
typedef __attribute__((ext_vector_type(4))) float f32x4;    // MFMA C/D frag

__device__ __forceinline__ unsigned short f2bf(float f) {
  union { float f; unsigned u; } v; v.f = f;
  unsigned r = v.u + 0x7fffu + ((v.u >> 16) & 1u);   // RNE
  return (unsigned short)(r >> 16);
}

// async global->LDS, 16 B per lane, wave-uniform LDS base (m97 pattern)
#define GLDS16(gp, lp)                                                     \
  __builtin_amdgcn_global_load_lds(                                        \
      (const __attribute__((address_space(1))) void*)(gp),                 \
      (__attribute__((address_space(3))) void*)(lp), 16, 0, 0)

// lgkm-only barrier (keeps reg-destined global loads in flight)
#define BAR_LGKM() asm volatile("s_waitcnt lgkmcnt(0)\n\ts_barrier" ::: "memory")

// ---------------- weight transpose + fp32->bf16 convert ----------------
__global__ void wt_kernel(const float* __restrict__ W, unsigned short* __restrict__ WT,
                          int K, int Nn) {
  int id = blockIdx.x * 256 + threadIdx.x;
  if (id >= K * Nn) return;
  int n = id % Nn, kk = id / Nn;               // coalesced read along n
  WT[(size_t)n * K + kk] = f2bf(W[(size_t)kk * Nn + n]);
}

// ---------------- fragment-order weight packing (K=384 weights, any NC) -------------
// frag=(c*8+w8)*12+k ; lane 16B = WT[c*128+w8*16+l15][k*32+lq*8]
__global__ void pack_w1(const unsigned short* __restrict__ W1T,  // [NC*128][384]
                        unsigned short* __restrict__ W1P) {
  int tid = blockIdx.x * 256 + threadIdx.x;      // NC*128*384/8 16B-chunks
  int lane = tid & 63, frag = tid >> 6;
  int k = frag % 12, t2 = frag / 12;
  int mi = t2 & 1, t3 = t2 >> 1;
  int w = t3 & 3, c = t3 >> 2;
  int l15 = lane & 15, lq = lane >> 4;
  int r = c * 128 + w * 32 + mi * 16 + l15;
  int col = k * 32 + lq * 8;
  *(int4*)(W1P + (size_t)tid * 8) = *(const int4*)(W1T + (size_t)r * 384 + col);
}
// W2 (K=1536): frag=(((w4*6+mi6)*12+c)*4+kk)
__global__ void pack_w2(const unsigned short* __restrict__ W2T,  // [384][1536]
                        unsigned short* __restrict__ W2P) {
  int tid = blockIdx.x * 256 + threadIdx.x;      // 73728 16B-chunks (288 blocks)
  int lane = tid & 63, frag = tid >> 6;
  int kk = frag & 3, t2 = frag >> 2;
  int c = t2 % 12, t3 = t2 / 12;
  int mi = t3 % 6, w = t3 / 6;
  int l15 = lane & 15, lq = lane >> 4;
  int r = w * 96 + mi * 16 + l15;
  int col = c * 128 + kk * 32 + lq * 8;
  *(int4*)(W2P + (size_t)tid * 8) = *(const int4*)(W2T + (size_t)r * 1536 + col);
}

// ---------------- layernorm: fp32 in -> bf16 out (one wave per row) ----------------
__global__ __launch_bounds__(256) void ln_kernel(const float* __restrict__ x,
                                                 const float* __restrict__ g,
                                                 const float* __restrict__ be,
                                                 unsigned short* __restrict__ out) {
  int row = (blockIdx.x * 256 + threadIdx.x) >> 6;
  int l = threadIdx.x & 63;
  const float* xr = x + (size_t)row * D_;
  float v[6]; float s = 0.f, ss = 0.f;
  #pragma unroll
  for (int i = 0; i < 6; ++i) { v[i] = xr[l + i*64]; s += v[i]; ss += v[i]*v[i]; }
  #pragma unroll
  for (int m = 1; m < 64; m <<= 1) { s += __shfl_xor(s, m); ss += __shfl_xor(ss, m); }
  float mu  = s * (1.f / D_);
  float var = ss * (1.f / D_) - mu * mu;
  float rs  = rsqrtf(var + 1e-5f);
  unsigned short* orow = out + (size_t)row * D_;
  #pragma unroll
  for (int i = 0; i < 6; ++i) {
    int c = l + i*64;
    orow[c] = f2bf((v[i] - mu) * rs * g[c] + be[c]);
  }
}

// ---------------- QKV GEMM v3 (32-row block, k-outer, deferred epilogue; R17-proven) -
__global__ __launch_bounds__(512, 4) void qkv_gemm(
    const unsigned short* __restrict__ h, const unsigned short* __restrict__ wP,
    unsigned short* __restrict__ qkv)
{
  __shared__ __align__(16) char smem[25600];   // staging 24576 | transpose 32x784
  int tid = threadIdx.x, w = tid >> 6, l = tid & 63;
  int l15 = l & 15, lq = l >> 4;
  size_t R0 = (size_t)blockIdx.x * 32;

  // ---- stage h strip (32 rows) -> frag-order LDS: 512 thr x 3 int4 ----
  {
    int row = tid >> 4, gi = row >> 4, l15w = row & 15;
    const unsigned short* src = h + (R0 + row) * 384 + (tid & 15) * 24;
    #pragma unroll
    for (int i = 0; i < 3; ++i) {
      int col = (tid & 15) * 24 + i * 8;
      int k = col >> 5, lqw = (col >> 3) & 3;
      *(int4*)(smem + (gi*12 + k)*1024 + (lqw*16 + l15w)*16) = *(const int4*)(src + i*8);
    }
  }
  __syncthreads();

  f32x4 acc[9][2];
  #pragma unroll
  for (int c = 0; c < 9; ++c)
    #pragma unroll
    for (int ni = 0; ni < 2; ++ni) acc[c][ni] = (f32x4){0.f, 0.f, 0.f, 0.f};

  const unsigned short* wb = wP + l * 8;       // + ((c*8+w)*12 + k)*512

  #define LDG(dst, cb, k)                                                    \
    { _Pragma("unroll") for (int ci = 0; ci < 3; ++ci)                       \
        dst[ci] = *(const bf16x8*)(wb + (((cb)+ci)*8 + w) * 6144 + (k) * 512); }

  #define CMPG(buf, cb)                                                      \
    { _Pragma("unroll") for (int ci = 0; ci < 3; ++ci)                       \
        _Pragma("unroll") for (int ni = 0; ni < 2; ++ni)                     \
          acc[(cb)+ci][ni] = __builtin_amdgcn_mfma_f32_16x16x32_bf16(        \
              buf[ci], bfr[ni], acc[(cb)+ci][ni], 0, 0, 0); }

  bf16x8 a0[3], a1[3], a2[3];
  LDG(a0, 0, 0)                                // preload k=0 group 0

  for (int k = 0; k < 12; ++k) {
    bf16x8 bfr[2];
    #pragma unroll
    for (int ni = 0; ni < 2; ++ni)
      bfr[ni] = *(const bf16x8*)(smem + (ni*12 + k)*1024 + l*16);
    int kn = (k < 11) ? k + 1 : 11;
    LDG(a1, 3, k)
    __builtin_amdgcn_s_setprio(1); CMPG(a0, 0) __builtin_amdgcn_s_setprio(0);
    LDG(a2, 6, k)
    __builtin_amdgcn_s_setprio(1); CMPG(a1, 3) __builtin_amdgcn_s_setprio(0);
    LDG(a0, 0, kn)
    __builtin_amdgcn_s_setprio(1); CMPG(a2, 6) __builtin_amdgcn_s_setprio(0);
  }
  #undef LDG
  #undef CMPG

  // ---- deferred epilogue: per buffer (q,k,v): acc -> LDS (784B rows) -> int4 stores
  __syncthreads();                              // staging region dead; reads drained
  #pragma unroll
  for (int buf = 0; buf < 3; ++buf) {
    #pragma unroll
    for (int ci = 0; ci < 3; ++ci) {
      int c = buf * 3 + ci;
      #pragma unroll
      for (int ni = 0; ni < 2; ++ni) {
        int row = ni * 16 + l15;
        ushort4 pk;
        pk.x = f2bf(acc[c][ni][0]);
        pk.y = f2bf(acc[c][ni][1]);
        pk.z = f2bf(acc[c][ni][2]);
        pk.w = f2bf(acc[c][ni][3]);
        *(ushort4*)(smem + row * 784 + ci * 256 + w * 32 + lq * 8) = pk;
      }
    }
    __syncthreads();
    {
      int row = tid >> 4;
      unsigned short* obase = qkv + (size_t)buf * NROW * 384 + (R0 + row) * 384;
      #pragma unroll
      for (int i = 0; i < 3; ++i) {
        int ob = (tid & 15) * 16 + i * 256;     // byte offset in 768-B row
        *(int4*)(obase + (ob >> 1)) = *(const int4*)(smem + row * 784 + ob);
      }
    }
    __syncthreads();
  }
}

// ---------------- NT GEMM (Wo): 2-phase dbuf, gload_lds + T1 swizzle (R16-proven) ---
template<int EPI>
__global__ __launch_bounds__(256) void gemm_bt(const unsigned short* __restrict__ A,
                                               const unsigned short* __restrict__ BT,
                                               void* __restrict__ Cc,
                                               const float* __restrict__ bias,
                                               const float* __restrict__ res,
                                               int Nn, int K) {
  __shared__ unsigned short As[2][128][32];
  __shared__ unsigned short Bs[2][128][32];
  int tid = threadIdx.x, w = tid >> 6, l = tid & 63;
  int wr = w >> 1, wc = w & 1;

  int ncol = gridDim.y;
  int nwg  = gridDim.x * ncol;
  int lin  = blockIdx.y * gridDim.x + blockIdx.x;
  int cpx  = nwg >> 3;
  int swz  = (lin & 7) * cpx + (lin >> 3);
  size_t R0 = (size_t)(swz / ncol) * 128;
  int C0 = (swz % ncol) * 128;

  int seg0 = (w * 2 + 0) * 16;
  int seg1 = (w * 2 + 1) * 16;
  int srow0 = seg0 + (l >> 2);
  int srow1 = seg1 + (l >> 2);
  int scol  = (l & 3) * 8;

  const unsigned short* ga0 = A  + (R0 + srow0) * K + scol;
  const unsigned short* ga1 = A  + (R0 + srow1) * K + scol;
  const unsigned short* gb0 = BT + (size_t)(C0 + srow0) * K + scol;
  const unsigned short* gb1 = BT + (size_t)(C0 + srow1) * K + scol;

  f32x4 acc[4][4];
  #pragma unroll
  for (int i = 0; i < 4; ++i)
    #pragma unroll
    for (int j = 0; j < 4; ++j) acc[i][j] = (f32x4){0.f, 0.f, 0.f, 0.f};

  GLDS16(ga0, &As[0][seg0][0]);
  GLDS16(ga1, &As[0][seg1][0]);
  GLDS16(gb0, &Bs[0][seg0][0]);
  GLDS16(gb1, &Bs[0][seg1][0]);
  ga0 += 32; ga1 += 32; gb0 += 32; gb1 += 32;

  int nk = K >> 5;
  for (int t = 0; t < nk; ++t) {
    int cur = t & 1;
    __syncthreads();
    if (t + 1 < nk) {
      GLDS16(ga0, &As[cur ^ 1][seg0][0]);
      GLDS16(ga1, &As[cur ^ 1][seg1][0]);
      GLDS16(gb0, &Bs[cur ^ 1][seg0][0]);
      GLDS16(gb1, &Bs[cur ^ 1][seg1][0]);
      ga0 += 32; ga1 += 32; gb0 += 32; gb1 += 32;
    }
    bf16x8 af[4], bf[4];
    #pragma unroll
    for (int mi = 0; mi < 4; ++mi)
      af[mi] = *(const bf16x8*)(&As[cur][wr*64 + mi*16 + (l & 15)][(l >> 4) * 8]);
    #pragma unroll
    for (int ni = 0; ni < 4; ++ni)
      bf[ni] = *(const bf16x8*)(&Bs[cur][wc*64 + ni*16 + (l & 15)][(l >> 4) * 8]);
    #pragma unroll
    for (int mi = 0; mi < 4; ++mi)
      #pragma unroll
      for (int ni = 0; ni < 4; ++ni)
        acc[mi][ni] = __builtin_amdgcn_mfma_f32_16x16x32_bf16(af[mi], bf[ni], acc[mi][ni], 0, 0, 0);
  }

  #pragma unroll
  for (int mi = 0; mi < 4; ++mi) {
    #pragma unroll
    for (int ni = 0; ni < 4; ++ni) {
      int col = C0 + wc*64 + ni*16 + (l & 15);
      #pragma unroll
      for (int j = 0; j < 4; ++j) {
        size_t row = R0 + wr*64 + mi*16 + ((l >> 4) << 2) + j;
        float vv = acc[mi][ni][j];
        ((float*)Cc)[row * Nn + col] = vv + bias[col] + res[row * Nn + col];
      }
    }
  }
}

// ======== 8-wave ffn building blocks (frag-order LDS + packed W) ========
#define LDA3(dst, pA, k0)                                                    \
  { _Pragma("unroll") for (int kq = 0; kq < 3; ++kq)                         \
      dst[kq] = *(const bf16x8*)((pA) + ((k0) + kq) * 512); }

#define CMP3(buf, k0, acc)                                                   \
  { _Pragma("unroll") for (int kq = 0; kq < 3; ++kq) {                       \
      bf16x8 bfr[4];                                                         \
      _Pragma("unroll") for (int ni = 0; ni < 4; ++ni)                       \
        bfr[ni] = *(const bf16x8*)(smem + (ni*12 + (k0)+kq)*1024 + l*16);    \
      _Pragma("unroll") for (int ni = 0; ni < 4; ++ni)                       \
        acc[ni] = __builtin_amdgcn_mfma_f32_16x16x32_bf16(                   \
            buf[kq], bfr[ni], acc[ni], 0, 0, 0);                             \
    } }

// ---------------- fused FFN (8-wave, setprio, DOUBLE-BUFFERED Psf, 1 barrier/chunk) -
// LDS (dynamic 81920 B): h2f @0 (48KB), Psf[0] @49152 (16KB), Psf[1] @65536 (16KB).
// Race proof for single barrier: P-write(c+2)->Psf[c&1] occurs after BAR(c+1);
// every wave reaches BAR(c+1) only after its PV(c) reads of Psf[c&1] retired.
__global__ __launch_bounds__(512, 4) void ffn_fused(
    const unsigned short* __restrict__ h2,   // [NROW][384] bf16
    const unsigned short* __restrict__ w1P,  // packed (pack_w1)
    const unsigned short* __restrict__ w2P,  // packed (pack_w2)
    const float* __restrict__ b1,            // [1536]
    const float* __restrict__ b2,            // [384]
    float* __restrict__ out)                 // [NROW][384] fp32, in-place residual add
{
  extern __shared__ __align__(16) char smem[];
  int tid = threadIdx.x, w = tid >> 6, l = tid & 63;
  int l15 = l & 15, lq = l >> 4;
  size_t R0 = (size_t)blockIdx.x * 64;

  // ---- stage h2 strip -> frag-order LDS (512 thr x 48 elems) ----
  {
    int row = tid >> 3, gi = row >> 4, l15w = row & 15;
    int cbase = (tid & 7) * 48;
    const unsigned short* src = h2 + (R0 + row) * 384 + cbase;
    #pragma unroll
    for (int i = 0; i < 6; ++i) {
      int col = cbase + i * 8;
      int k = col >> 5, lqw = (col >> 3) & 3;
      *(int4*)(smem + (gi*12 + k)*1024 + (lqw*16 + l15w)*16) = *(const int4*)(src + i*8);
    }
  }
  __syncthreads();

  f32x4 oacc[3][4];
  #pragma unroll
  for (int i = 0; i < 3; ++i)
    #pragma unroll
    for (int j = 0; j < 4; ++j) oacc[i][j] = (f32x4){0.f, 0.f, 0.f, 0.f};

  const unsigned short* w1b = w1P + w * 6144  + l * 8;  // + c*49152 + k*512
  const unsigned short* w2b = w2P + w * 73728 + l * 8;  // + mi*24576 + c*2048 + kk*512

  #define LDV(dst, pV, kk)                                                   \
    { _Pragma("unroll") for (int mi = 0; mi < 3; ++mi)                       \
        dst[mi] = *(const bf16x8*)((pV) + mi * 24576 + (kk) * 512); }

  #define CMPV(buf, kk, pb)                                                  \
    { bf16x8 bv[4];                                                          \
      _Pragma("unroll") for (int ni = 0; ni < 4; ++ni)                       \
        bv[ni] = *(const bf16x8*)(smem + (pb) + (ni*4 + (kk))*1024 + l*16);  \
      _Pragma("unroll") for (int mi = 0; mi < 3; ++mi)                       \
        _Pragma("unroll") for (int ni = 0; ni < 4; ++ni)                     \
          oacc[mi][ni] = __builtin_amdgcn_mfma_f32_16x16x32_bf16(            \
              buf[mi], bv[ni], oacc[mi][ni], 0, 0, 0);                       \
    }

  bf16x8 afA[3], afB[3];
  bf16x8 avA[3], avB[3];

  LDA3(afA, w1b, 0)   // prologue: first P-group of chunk 0

  for (int c = 0; c < 12; ++c) {
    const unsigned short* pA = w1b + (size_t)c * 49152;
    const unsigned short* pV = w2b + c * 2048;
    unsigned pb = 49152u + (unsigned)(c & 1) * 16384u;

    f32x4 pacc[4];
    #pragma unroll
    for (int j = 0; j < 4; ++j) pacc[j] = (f32x4){0.f, 0.f, 0.f, 0.f};

    // P-phase: 4 groups of 3 k-steps, ping-pong prefetch; T5 around MFMA clusters
    LDA3(afB, pA, 3)
    __builtin_amdgcn_s_setprio(1); CMP3(afA, 0, pacc) __builtin_amdgcn_s_setprio(0);
    LDA3(afA, pA, 6)
    __builtin_amdgcn_s_setprio(1); CMP3(afB, 3, pacc) __builtin_amdgcn_s_setprio(0);
    LDA3(afB, pA, 9)
    __builtin_amdgcn_s_setprio(1); CMP3(afA, 6, pacc) __builtin_amdgcn_s_setprio(0);
    LDV(avA, pV, 0)
    __builtin_amdgcn_s_setprio(1); CMP3(afB, 9, pacc) __builtin_amdgcn_s_setprio(0);

    // P epilogue: bias1 + relu + bf16 pack -> Psf[c&1]
    {
      int fcb = c * 128 + w * 16 + lq * 4;
      float4 bb = *(const float4*)(b1 + fcb);
      unsigned pw = pb + (unsigned)((w >> 1) * 1024 +
                    (((w & 1) * 2 + (lq >> 1)) * 16 + l15) * 16 + (lq & 1) * 8);
      #pragma unroll
      for (int ni = 0; ni < 4; ++ni) {
        float p0 = pacc[ni][0] + bb.x;
        float p1 = pacc[ni][1] + bb.y;
        float p2 = pacc[ni][2] + bb.z;
        float p3 = pacc[ni][3] + bb.w;
        ushort4 pk;
        pk.x = f2bf(p0 > 0.f ? p0 : 0.f);
        pk.y = f2bf(p1 > 0.f ? p1 : 0.f);
        pk.z = f2bf(p2 > 0.f ? p2 : 0.f);
        pk.w = f2bf(p3 > 0.f ? p3 : 0.f);
        *(ushort4*)(smem + pw + ni * 4096) = pk;
      }
    }
    BAR_LGKM();   // single barrier per chunk: Psf[c&1] visible; prefetches stay in flight

    // PV on Psf[c&1]; next chunk's first A-group prefetched at the tail.
    const unsigned short* pAn = w1b + (size_t)(c < 11 ? c + 1 : 11) * 49152;
    LDV(avB, pV, 1)
    __builtin_amdgcn_s_setprio(1); CMPV(avA, 0, pb) __builtin_amdgcn_s_setprio(0);
    LDV(avA, pV, 2)
    __builtin_amdgcn_s_setprio(1); CMPV(avB, 1, pb) __builtin_amdgcn_s_setprio(0);
    LDV(avB, pV, 3)
    __builtin_amdgcn_s_setprio(1); CMPV(avA, 2, pb) __builtin_amdgcn_s_setprio(0);
    LDA3(afA, pAn, 0)
    __builtin_amdgcn_s_setprio(1); CMPV(avB, 3, pb) __builtin_amdgcn_s_setprio(0);
    // no trailing barrier: next chunk writes Psf[(c+1)&1]
  }
  #undef LDV
  #undef CMPV

  // epilogue: out[row][ocol..+3] = oacc + b2 + res  (dwordx4)
  #pragma unroll
  for (int mi = 0; mi < 3; ++mi) {
    int ocb = w * 48 + mi * 16 + lq * 4;
    float4 b2v = *(const float4*)(b2 + ocb);
    #pragma unroll
    for (int ni = 0; ni < 4; ++ni) {
      size_t row = R0 + ni * 16 + l15;
      float* op = out + row * D_ + ocb;
      float4 r = *(const float4*)op;
      float4 o;
      o.x = oacc[mi][ni][0] + b2v.x + r.x;
      o.y = oacc[mi][ni][1] + b2v.y + r.y;
      o.z = oacc[mi][ni][2] + b2v.z + r.z;
      o.w = oacc[mi][ni][3] + b2v.w + r.w;
      *(float4*)op = o;
    }
  }
}

// ---------------- causal attention (+T5 setprio), one block per (b,h) ----------------
__global__ __launch_bounds__(256) void attn_kernel(const unsigned short* __restrict__ q,
                                                   const unsigned short* __restrict__ k,
                                                   const unsigned short* __restrict__ v,
                                                   unsigned short* __restrict__ o) {
  __shared__ __align__(16) char smem[52224];
  unsigned short (*Ks)[72]       = (unsigned short(*)[72])smem;
  unsigned short (*Ps)[32][136]  = (unsigned short(*)[32][136])smem;
  unsigned short (*Vt)[136]      = (unsigned short(*)[136])(smem + 34816);

  int bh = blockIdx.x;
  int b = bh / H_, h = bh % H_;
  int tid = threadIdx.x, w = tid >> 6, l = tid & 63;

  const unsigned short* kb = k + ((size_t)b * T_) * D_ + h * DH_;
  const unsigned short* vb = v + ((size_t)b * T_) * D_ + h * DH_;
  #pragma unroll
  for (int it = 0; it < 4; ++it) {
    int id = it * 256 + tid;
    int s = id >> 3, c8 = (id & 7) * 8;
    int4 kv = *(const int4*)(kb + (size_t)s * D_ + c8);
    *(int4*)(&Ks[s][c8]) = kv;
    int4 vv = *(const int4*)(vb + (size_t)s * D_ + c8);
    const unsigned short* pe = (const unsigned short*)&vv;
    #pragma unroll
    for (int j2 = 0; j2 < 8; ++j2) Vt[c8 + j2][s] = pe[j2];
  }
  __syncthreads();

  const unsigned short* qbp = q + ((size_t)b * T_) * D_ + h * DH_;
  int rowbase = w * 32;
  bf16x8 aq[2][2];
  #pragma unroll
  for (int mi = 0; mi < 2; ++mi)
    #pragma unroll
    for (int ks = 0; ks < 2; ++ks)
      aq[mi][ks] = *(const bf16x8*)(qbp + (size_t)(rowbase + mi*16 + (l & 15)) * D_
                                        + ks*32 + ((l >> 4) << 3));

  f32x4 accs[2][8];
  #pragma unroll
  for (int i = 0; i < 2; ++i)
    #pragma unroll
    for (int j = 0; j < 8; ++j) accs[i][j] = (f32x4){0.f, 0.f, 0.f, 0.f};
  #pragma unroll
  for (int ks = 0; ks < 2; ++ks) {
    bf16x8 bk[8];
    #pragma unroll
    for (int ni = 0; ni < 8; ++ni)
      bk[ni] = *(const bf16x8*)(&Ks[ni*16 + (l & 15)][ks*32 + ((l >> 4) << 3)]);
    __builtin_amdgcn_s_setprio(1);
    #pragma unroll
    for (int mi = 0; mi < 2; ++mi)
      #pragma unroll
      for (int ni = 0; ni < 8; ++ni)
        accs[mi][ni] = __builtin_amdgcn_mfma_f32_16x16x32_bf16(aq[mi][ks], bk[ni], accs[mi][ni], 0, 0, 0);
    __builtin_amdgcn_s_setprio(0);
  }
  __syncthreads();

  #pragma unroll
  for (int mi = 0; mi < 2; ++mi) {
    #pragma unroll
    for (int j = 0; j < 4; ++j) {
      int t = rowbase + mi*16 + ((l >> 4) << 2) + j;
      float mx = -1e30f;
      #pragma unroll
      for (int ni = 0; ni < 8; ++ni) {
        int scol = ni*16 + (l & 15);
        float sv = accs[mi][ni][j] * 0.125f;
        sv = (scol <= t) ? sv : -1e30f;
        accs[mi][ni][j] = sv;
        mx = fmaxf(mx, sv);
      }
      mx = fmaxf(mx, __shfl_xor(mx, 1));
      mx = fmaxf(mx, __shfl_xor(mx, 2));
      mx = fmaxf(mx, __shfl_xor(mx, 4));
      mx = fmaxf(mx, __shfl_xor(mx, 8));
      float sum = 0.f;
      #pragma unroll
      for (int ni = 0; ni < 8; ++ni) {
        float e = __expf(accs[mi][ni][j] - mx);
        accs[mi][ni][j] = e;
        sum += e;
      }
      sum += __shfl_xor(sum, 1);
      sum += __shfl_xor(sum, 2);
      sum += __shfl_xor(sum, 4);
      sum += __shfl_xor(sum, 8);
      float inv = 1.f / sum;
      #pragma unroll
      for (int ni = 0; ni < 8; ++ni)
        Ps[w][mi*16 + ((l >> 4) << 2) + j][ni*16 + (l & 15)] = f2bf(accs[mi][ni][j] * inv);
    }
  }
  __syncthreads();

  f32x4 acco[2][4];
  #pragma unroll
  for (int i = 0; i < 2; ++i)
    #pragma unroll
    for (int j = 0; j < 4; ++j) acco[i][j] = (f32x4){0.f, 0.f, 0.f, 0.f};
  #pragma unroll
  for (int ks = 0; ks < 4; ++ks) {
    bf16x8 ap[2], bv[4];
    #pragma unroll
    for (int mi = 0; mi < 2; ++mi)
      ap[mi] = *(const bf16x8*)(&Ps[w][mi*16 + (l & 15)][ks*32 + ((l >> 4) << 3)]);
    #pragma unroll
    for (int ni = 0; ni < 4; ++ni)
      bv[ni] = *(const bf16x8*)(&Vt[ni*16 + (l & 15)][ks*32 + ((l >> 4) << 3)]);
    __builtin_amdgcn_s_setprio(1);
    #pragma unroll
    for (int mi = 0; mi < 2; ++mi)
      #pragma unroll
      for (int ni = 0; ni < 4; ++ni)
        acco[mi][ni] = __builtin_amdgcn_mfma_f32_16x16x32_bf16(ap[mi], bv[ni], acco[mi][ni], 0, 0, 0);
    __builtin_amdgcn_s_setprio(0);
  }

  unsigned short* ob = o + ((size_t)b * T_) * D_ + h * DH_;
  #pragma unroll
  for (int mi = 0; mi < 2; ++mi)
    #pragma unroll
    for (int ni = 0; ni < 4; ++ni)
      #pragma unroll
      for (int j = 0; j < 4; ++j) {
        int t = rowbase + mi*16 + ((l >> 4) << 2) + j;
        int d = ni*16 + (l & 15);
        ob[(size_t)t * D_ + d] = f2bf(acco[mi][ni][j]);
      }
}

extern "C" void kernel_launch(void* const* d_in, const int* in_sizes, int n_in,
                              void* d_out, int out_size, void* d_ws, size_t ws_size,
                              hipStream_t stream) {
  const float* x   = (const float*)d_in[0];
  const float* Wq  = (const float*)d_in[1];
  const float* Wk  = (const float*)d_in[2];
  const float* Wv  = (const float*)d_in[3];
  const float* Wo  = (const float*)d_in[4];
  const float* bo  = (const float*)d_in[5];
  const float* W1  = (const float*)d_in[6];
  const float* b1  = (const float*)d_in[7];
  const float* W2  = (const float*)d_in[8];
  const float* b2  = (const float*)d_in[9];
  const float* g1  = (const float*)d_in[10];
  const float* be1 = (const float*)d_in[11];
  const float* g2  = (const float*)d_in[12];
  const float* be2 = (const float*)d_in[13];

  // workspace layout (bytes); total ~209 MiB
  char* ws = (char*)d_ws;
  unsigned short* hb    = (unsigned short*)(ws);               // h (LN1), later h2 (LN2)
  unsigned short* qb    = (unsigned short*)(ws +  50331648);   // q|k|v contiguous; o in-place
  unsigned short* kbuf  = (unsigned short*)(ws + 100663296);
  unsigned short* vbuf  = (unsigned short*)(ws + 150994944);
  unsigned short* wqT   = (unsigned short*)(ws + 201326592);   // [1152][384] (wq|wk|wv)
  unsigned short* woT   = wqT + 442368;                        // [384][384]
  unsigned short* w1T   = woT + 147456;                        // [1536][384]
  unsigned short* w2T   = w1T + 589824;                        // [384][1536]
  unsigned short* w1P   = w2T + 589824;                        // packed (pack_w1, NC=12)
  unsigned short* w2P   = w1P + 589824;                        // packed (pack_w2)
  unsigned short* wqkvP = w2P + 589824;                        // packed (pack_w1, NC=9)
  float* x2 = (float*)d_out;
  (void)kbuf; (void)vbuf;

  // allow 80KB dynamic LDS for ffn_fused (host-side attribute; idempotent)
  hipFuncSetAttribute(reinterpret_cast<const void*>(ffn_fused),
                      hipFuncAttributeMaxDynamicSharedMemorySize, 81920);

  // 1) weight convert+transpose (tiny) + fragment-order packs
  wt_kernel<<<dim3(576),  256, 0, stream>>>(Wq, wqT,          384, 384);
  wt_kernel<<<dim3(576),  256, 0, stream>>>(Wk, wqT + 147456, 384, 384);
  wt_kernel<<<dim3(576),  256, 0, stream>>>(Wv, wqT + 294912, 384, 384);
  wt_kernel<<<dim3(576),  256, 0, stream>>>(Wo, woT,          384, 384);
  wt_kernel<<<dim3(2304), 256, 0, stream>>>(W1, w1T, 384, 1536);
  wt_kernel<<<dim3(2304), 256, 0, stream>>>(W2, w2T, 1536, 384);
  pack_w1<<<dim3(216), 256, 0, stream>>>(wqT, wqkvP);   // NC=9
  pack_w1<<<dim3(288), 256, 0, stream>>>(w1T, w1P);     // NC=12
  pack_w2<<<dim3(288), 256, 0, stream>>>(w2T, w2P);

  // 2) LN1: x -> h (bf16)
  ln_kernel<<<dim3(NROW / 4), 256, 0, stream>>>(x, g1, be1, hb);

  // 3) QKV GEMM v3 (32-row blocks, deferred epilogue): q|k|v = h @ [Wq|Wk|Wv]
  qkv_gemm<<<dim3(NROW / 32), 512, 0, stream>>>(hb, wqkvP, qb);

  // 4) attention: o overwrites q in place (per-block disjoint strips)
  attn_kernel<<<dim3(B_ * H_), 256, 0, stream>>>(qb, kbuf, vbuf, qb);

  // 5) x2 = x + o @ Wo + bo   (fp32, into d_out; T1 swizzle; nwg=1536 %8==0)
  gemm_bt<1><<<dim3(NROW / 128, 3), 256, 0, stream>>>(qb, woT, x2, bo, x, 384, 384);

  // 6) LN2: x2 -> h2 (bf16, into hb)
  ln_kernel<<<dim3(NROW / 4), 256, 0, stream>>>((const float*)x2, g2, be2, hb);

  // 7) fused FFN (dbuf-Psf, 1 barrier/chunk, 80KB dyn LDS)
  ffn_fused<<<dim3(NROW / 64), 512, 81920, stream>>>(hb, w1P, w2P, b1, b2, x2);
}

// Round 19
// 422.288 us; speedup vs baseline: 2.2121x; 1.0391x over previous
//
#include <hip/hip_runtime.h>

// Problem constants
#define B_   512
#define T_   128
#define D_   384
#define H_   6
#define DH_  64
#define DFF_ 1536
#define NROW (B_*T_)   // 65536 rows

typedef __attribute__((ext_vector_type(8))) short bf16x8;   // MFMA A/B frag (4 VGPRs)
typedef __attribute__((ext_vector_type(4))) float f32x4;    // MFMA C/D frag

__device__ __forceinline__ unsigned short f2bf(float f) {
  union { float f; unsigned u; } v; v.f = f;
  unsigned r = v.u + 0x7fffu + ((v.u >> 16) & 1u);   // RNE
  return (unsigned short)(r >> 16);
}

// lgkm-only barrier (keeps reg-destined global loads in flight)
#define BAR_LGKM() asm volatile("s_waitcnt lgkmcnt(0)\n\ts_barrier" ::: "memory")

// ---------------- weight transpose + fp32->bf16 convert ----------------
__global__ void wt_kernel(const float* __restrict__ W, unsigned short* __restrict__ WT,
                          int K, int Nn) {
  int id = blockIdx.x * 256 + threadIdx.x;
  if (id >= K * Nn) return;
  int n = id % Nn, kk = id / Nn;               // coalesced read along n
  WT[(size_t)n * K + kk] = f2bf(W[(size_t)kk * Nn + n]);
}

// ---------------- fragment-order weight packing (K=384 weights, any NC) -------------
// frag=(c*8+w8)*12+k ; lane 16B = WT[c*128+w8*16+l15][k*32+lq*8]
__global__ void pack_w1(const unsigned short* __restrict__ W1T,  // [NC*128][384]
                        unsigned short* __restrict__ W1P) {
  int tid = blockIdx.x * 256 + threadIdx.x;      // NC*128*384/8 16B-chunks
  int lane = tid & 63, frag = tid >> 6;
  int k = frag % 12, t2 = frag / 12;
  int mi = t2 & 1, t3 = t2 >> 1;
  int w = t3 & 3, c = t3 >> 2;
  int l15 = lane & 15, lq = lane >> 4;
  int r = c * 128 + w * 32 + mi * 16 + l15;
  int col = k * 32 + lq * 8;
  *(int4*)(W1P + (size_t)tid * 8) = *(const int4*)(W1T + (size_t)r * 384 + col);
}
// W2 (K=1536): frag=(((w4*6+mi6)*12+c)*4+kk)
__global__ void pack_w2(const unsigned short* __restrict__ W2T,  // [384][1536]
                        unsigned short* __restrict__ W2P) {
  int tid = blockIdx.x * 256 + threadIdx.x;      // 73728 16B-chunks (288 blocks)
  int lane = tid & 63, frag = tid >> 6;
  int kk = frag & 3, t2 = frag >> 2;
  int c = t2 % 12, t3 = t2 / 12;
  int mi = t3 % 6, w = t3 / 6;
  int l15 = lane & 15, lq = lane >> 4;
  int r = w * 96 + mi * 16 + l15;
  int col = c * 128 + kk * 32 + lq * 8;
  *(int4*)(W2P + (size_t)tid * 8) = *(const int4*)(W2T + (size_t)r * 1536 + col);
}

// ---------------- layernorm (LN1): fp32 in -> bf16 out (one wave per row) -----------
__global__ __launch_bounds__(256) void ln_kernel(const float* __restrict__ x,
                                                 const float* __restrict__ g,
                                                 const float* __restrict__ be,
                                                 unsigned short* __restrict__ out) {
  int row = (blockIdx.x * 256 + threadIdx.x) >> 6;
  int l = threadIdx.x & 63;
  const float* xr = x + (size_t)row * D_;
  float v[6]; float s = 0.f, ss = 0.f;
  #pragma unroll
  for (int i = 0; i < 6; ++i) { v[i] = xr[l + i*64]; s += v[i]; ss += v[i]*v[i]; }
  #pragma unroll
  for (int m = 1; m < 64; m <<= 1) { s += __shfl_xor(s, m); ss += __shfl_xor(ss, m); }
  float mu  = s * (1.f / D_);
  float var = ss * (1.f / D_) - mu * mu;
  float rs  = rsqrtf(var + 1e-5f);
  unsigned short* orow = out + (size_t)row * D_;
  #pragma unroll
  for (int i = 0; i < 6; ++i) {
    int c = l + i*64;
    orow[c] = f2bf((v[i] - mu) * rs * g[c] + be[c]);
  }
}

// ---------------- QKV GEMM v3 (32-row block, k-outer, deferred epilogue; R17-proven) -
__global__ __launch_bounds__(512, 4) void qkv_gemm(
    const unsigned short* __restrict__ h, const unsigned short* __restrict__ wP,
    unsigned short* __restrict__ qkv)
{
  __shared__ __align__(16) char smem[25600];   // staging 24576 | transpose 32x784
  int tid = threadIdx.x, w = tid >> 6, l = tid & 63;
  int l15 = l & 15, lq = l >> 4;
  size_t R0 = (size_t)blockIdx.x * 32;

  // ---- stage h strip (32 rows) -> frag-order LDS: 512 thr x 3 int4 ----
  {
    int row = tid >> 4, gi = row >> 4, l15w = row & 15;
    const unsigned short* src = h + (R0 + row) * 384 + (tid & 15) * 24;
    #pragma unroll
    for (int i = 0; i < 3; ++i) {
      int col = (tid & 15) * 24 + i * 8;
      int k = col >> 5, lqw = (col >> 3) & 3;
      *(int4*)(smem + (gi*12 + k)*1024 + (lqw*16 + l15w)*16) = *(const int4*)(src + i*8);
    }
  }
  __syncthreads();

  f32x4 acc[9][2];
  #pragma unroll
  for (int c = 0; c < 9; ++c)
    #pragma unroll
    for (int ni = 0; ni < 2; ++ni) acc[c][ni] = (f32x4){0.f, 0.f, 0.f, 0.f};

  const unsigned short* wb = wP + l * 8;       // + ((c*8+w)*12 + k)*512

  #define LDG(dst, cb, k)                                                    \
    { _Pragma("unroll") for (int ci = 0; ci < 3; ++ci)                       \
        dst[ci] = *(const bf16x8*)(wb + (((cb)+ci)*8 + w) * 6144 + (k) * 512); }

  #define CMPG(buf, cb)                                                      \
    { _Pragma("unroll") for (int ci = 0; ci < 3; ++ci)                       \
        _Pragma("unroll") for (int ni = 0; ni < 2; ++ni)                     \
          acc[(cb)+ci][ni] = __builtin_amdgcn_mfma_f32_16x16x32_bf16(        \
              buf[ci], bfr[ni], acc[(cb)+ci][ni], 0, 0, 0); }

  bf16x8 a0[3], a1[3], a2[3];
  LDG(a0, 0, 0)                                // preload k=0 group 0

  for (int k = 0; k < 12; ++k) {
    bf16x8 bfr[2];
    #pragma unroll
    for (int ni = 0; ni < 2; ++ni)
      bfr[ni] = *(const bf16x8*)(smem + (ni*12 + k)*1024 + l*16);
    int kn = (k < 11) ? k + 1 : 11;
    LDG(a1, 3, k)
    __builtin_amdgcn_s_setprio(1); CMPG(a0, 0) __builtin_amdgcn_s_setprio(0);
    LDG(a2, 6, k)
    __builtin_amdgcn_s_setprio(1); CMPG(a1, 3) __builtin_amdgcn_s_setprio(0);
    LDG(a0, 0, kn)
    __builtin_amdgcn_s_setprio(1); CMPG(a2, 6) __builtin_amdgcn_s_setprio(0);
  }
  #undef LDG
  #undef CMPG

  // ---- deferred epilogue: per buffer (q,k,v): acc -> LDS (784B rows) -> int4 stores
  __syncthreads();                              // staging region dead; reads drained
  #pragma unroll
  for (int buf = 0; buf < 3; ++buf) {
    #pragma unroll
    for (int ci = 0; ci < 3; ++ci) {
      int c = buf * 3 + ci;
      #pragma unroll
      for (int ni = 0; ni < 2; ++ni) {
        int row = ni * 16 + l15;
        ushort4 pk;
        pk.x = f2bf(acc[c][ni][0]);
        pk.y = f2bf(acc[c][ni][1]);
        pk.z = f2bf(acc[c][ni][2]);
        pk.w = f2bf(acc[c][ni][3]);
        *(ushort4*)(smem + row * 784 + ci * 256 + w * 32 + lq * 8) = pk;
      }
    }
    __syncthreads();
    {
      int row = tid >> 4;
      unsigned short* obase = qkv + (size_t)buf * NROW * 384 + (R0 + row) * 384;
      #pragma unroll
      for (int i = 0; i < 3; ++i) {
        int ob = (tid & 15) * 16 + i * 256;     // byte offset in 768-B row
        *(int4*)(obase + (ob >> 1)) = *(const int4*)(smem + row * 784 + ob);
      }
    }
    __syncthreads();
  }
}

// ---------------- fused Wo + residual + LN2 (32-row block, qkv-v3 skeleton) ---------
// x2 = x + o@Wo + bo computed into LDS tile; LN2 runs on the tile; emits x2 (fp32)
// and h2 (bf16) with fully-coalesced stores. Replaces gemm_bt<1> + ln_kernel(LN2):
// kills the 100 MB x2 HBM round-trip between them.
__global__ __launch_bounds__(512, 4) void wo_ln(
    const unsigned short* __restrict__ o,    // [NROW][384] bf16 (attention out)
    const unsigned short* __restrict__ wP,   // woP packed (pack_w1, NC=3)
    const float* __restrict__ bo, const float* __restrict__ xres,
    const float* __restrict__ g, const float* __restrict__ be,
    float* __restrict__ x2out,               // d_out
    unsigned short* __restrict__ h2out)      // hb
{
  __shared__ __align__(16) char smem[50176]; // staging 24576 (reused) | x2 tile 32x392 f32
  int tid = threadIdx.x, w = tid >> 6, l = tid & 63;
  int l15 = l & 15, lq = l >> 4;
  size_t R0 = (size_t)blockIdx.x * 32;

  // ---- stage o strip (32 rows) -> frag-order LDS (qkv-v3 pattern) ----
  {
    int row = tid >> 4, gi = row >> 4, l15w = row & 15;
    const unsigned short* src = o + (R0 + row) * 384 + (tid & 15) * 24;
    #pragma unroll
    for (int i = 0; i < 3; ++i) {
      int col = (tid & 15) * 24 + i * 8;
      int k = col >> 5, lqw = (col >> 3) & 3;
      *(int4*)(smem + (gi*12 + k)*1024 + (lqw*16 + l15w)*16) = *(const int4*)(src + i*8);
    }
  }
  __syncthreads();

  f32x4 acc[3][2];
  #pragma unroll
  for (int c = 0; c < 3; ++c)
    #pragma unroll
    for (int ni = 0; ni < 2; ++ni) acc[c][ni] = (f32x4){0.f, 0.f, 0.f, 0.f};

  const unsigned short* wb = wP + l * 8;       // + ((ci*8+w)*12 + k)*512

  #define LDGW(dst, k)                                                       \
    { _Pragma("unroll") for (int ci = 0; ci < 3; ++ci)                       \
        dst[ci] = *(const bf16x8*)(wb + (ci*8 + w) * 6144 + (k) * 512); }

  #define CMPW(buf)                                                          \
    { _Pragma("unroll") for (int ci = 0; ci < 3; ++ci)                       \
        _Pragma("unroll") for (int ni = 0; ni < 2; ++ni)                     \
          acc[ci][ni] = __builtin_amdgcn_mfma_f32_16x16x32_bf16(             \
              buf[ci], bfr[ni], acc[ci][ni], 0, 0, 0); }

  bf16x8 aA[3], aB[3];
  LDGW(aA, 0)
  for (int k = 0; k < 12; k += 2) {
    bf16x8 bfr[2];
    #pragma unroll
    for (int ni = 0; ni < 2; ++ni)
      bfr[ni] = *(const bf16x8*)(smem + (ni*12 + k)*1024 + l*16);
    LDGW(aB, k + 1)
    __builtin_amdgcn_s_setprio(1); CMPW(aA) __builtin_amdgcn_s_setprio(0);
    #pragma unroll
    for (int ni = 0; ni < 2; ++ni)
      bfr[ni] = *(const bf16x8*)(smem + (ni*12 + k + 1)*1024 + l*16);
    int kn = (k + 2 < 12) ? k + 2 : 11;
    LDGW(aA, kn)
    __builtin_amdgcn_s_setprio(1); CMPW(aB) __builtin_amdgcn_s_setprio(0);
  }
  #undef LDGW
  #undef CMPW

  // ---- epilogue: x2 = acc + bo + x -> LDS tile [32][392] f32 ----
  __syncthreads();                              // staging reads retired
  #pragma unroll
  for (int ci = 0; ci < 3; ++ci) {
    int col = ci * 128 + w * 16 + lq * 4;
    float4 bb = *(const float4*)(bo + col);
    #pragma unroll
    for (int ni = 0; ni < 2; ++ni) {
      int row = ni * 16 + l15;
      float4 r = *(const float4*)(xres + (R0 + row) * 384 + col);
      float4 v;
      v.x = acc[ci][ni][0] + bb.x + r.x;
      v.y = acc[ci][ni][1] + bb.y + r.y;
      v.z = acc[ci][ni][2] + bb.z + r.z;
      v.w = acc[ci][ni][3] + bb.w + r.w;
      *(float4*)(smem + row * 1568 + col * 4) = v;
    }
  }
  __syncthreads();

  // ---- LN2 on the tile: 16 thr/row; emit x2 fp32 + h2 bf16 (coalesced) ----
  {
    int row = tid >> 4, t16 = tid & 15;
    const char* rbase = smem + row * 1568;
    float4 vv[6];
    float s = 0.f, ss = 0.f;
    #pragma unroll
    for (int i = 0; i < 6; ++i) {
      vv[i] = *(const float4*)(rbase + (t16 + i * 16) * 16);
      s  += vv[i].x + vv[i].y + vv[i].z + vv[i].w;
      ss += vv[i].x*vv[i].x + vv[i].y*vv[i].y + vv[i].z*vv[i].z + vv[i].w*vv[i].w;
    }
    s += __shfl_xor(s, 1); ss += __shfl_xor(ss, 1);
    s += __shfl_xor(s, 2); ss += __shfl_xor(ss, 2);
    s += __shfl_xor(s, 4); ss += __shfl_xor(ss, 4);
    s += __shfl_xor(s, 8); ss += __shfl_xor(ss, 8);
    float mu = s * (1.f / 384.f);
    float rs = rsqrtf(ss * (1.f / 384.f) - mu * mu + 1e-5f);
    float* xrow = x2out + (R0 + row) * 384;
    unsigned short* hrow = h2out + (R0 + row) * 384;
    #pragma unroll
    for (int i = 0; i < 6; ++i) {
      int c4 = t16 + i * 16;                   // float4 index in row
      float4 ga = *(const float4*)(g  + c4 * 4);
      float4 ba = *(const float4*)(be + c4 * 4);
      *(float4*)(xrow + c4 * 4) = vv[i];
      ushort4 pk;
      pk.x = f2bf((vv[i].x - mu) * rs * ga.x + ba.x);
      pk.y = f2bf((vv[i].y - mu) * rs * ga.y + ba.y);
      pk.z = f2bf((vv[i].z - mu) * rs * ga.z + ba.z);
      pk.w = f2bf((vv[i].w - mu) * rs * ga.w + ba.w);
      *(ushort4*)(hrow + c4 * 4) = pk;
    }
  }
}

// ======== 8-wave ffn building blocks (frag-order LDS + packed W) ========
#define LDA3(dst, pA, k0)                                                    \
  { _Pragma("unroll") for (int kq = 0; kq < 3; ++kq)                         \
      dst[kq] = *(const bf16x8*)((pA) + ((k0) + kq) * 512); }

#define CMP3(buf, k0, acc)                                                   \
  { _Pragma("unroll") for (int kq = 0; kq < 3; ++kq) {                       \
      bf16x8 bfr[4];                                                         \
      _Pragma("unroll") for (int ni = 0; ni < 4; ++ni)                       \
        bfr[ni] = *(const bf16x8*)(smem + (ni*12 + (k0)+kq)*1024 + l*16);    \
      _Pragma("unroll") for (int ni = 0; ni < 4; ++ni)                       \
        acc[ni] = __builtin_amdgcn_mfma_f32_16x16x32_bf16(                   \
            buf[kq], bfr[ni], acc[ni], 0, 0, 0);                             \
    } }

// ---------------- fused FFN (8-wave, setprio, dbuf Psf, 1 barrier/chunk; R18-proven) -
__global__ __launch_bounds__(512, 4) void ffn_fused(
    const unsigned short* __restrict__ h2,   // [NROW][384] bf16
    const unsigned short* __restrict__ w1P,  // packed (pack_w1)
    const unsigned short* __restrict__ w2P,  // packed (pack_w2)
    const float* __restrict__ b1,            // [1536]
    const float* __restrict__ b2,            // [384]
    float* __restrict__ out)                 // [NROW][384] fp32, in-place residual add
{
  extern __shared__ __align__(16) char smem[];
  int tid = threadIdx.x, w = tid >> 6, l = tid & 63;
  int l15 = l & 15, lq = l >> 4;
  size_t R0 = (size_t)blockIdx.x * 64;

  // ---- stage h2 strip -> frag-order LDS (512 thr x 48 elems) ----
  {
    int row = tid >> 3, gi = row >> 4, l15w = row & 15;
    int cbase = (tid & 7) * 48;
    const unsigned short* src = h2 + (R0 + row) * 384 + cbase;
    #pragma unroll
    for (int i = 0; i < 6; ++i) {
      int col = cbase + i * 8;
      int k = col >> 5, lqw = (col >> 3) & 3;
      *(int4*)(smem + (gi*12 + k)*1024 + (lqw*16 + l15w)*16) = *(const int4*)(src + i*8);
    }
  }
  __syncthreads();

  f32x4 oacc[3][4];
  #pragma unroll
  for (int i = 0; i < 3; ++i)
    #pragma unroll
    for (int j = 0; j < 4; ++j) oacc[i][j] = (f32x4){0.f, 0.f, 0.f, 0.f};

  const unsigned short* w1b = w1P + w * 6144  + l * 8;  // + c*49152 + k*512
  const unsigned short* w2b = w2P + w * 73728 + l * 8;  // + mi*24576 + c*2048 + kk*512

  #define LDV(dst, pV, kk)                                                   \
    { _Pragma("unroll") for (int mi = 0; mi < 3; ++mi)                       \
        dst[mi] = *(const bf16x8*)((pV) + mi * 24576 + (kk) * 512); }

  #define CMPV(buf, kk, pb)                                                  \
    { bf16x8 bv[4];                                                          \
      _Pragma("unroll") for (int ni = 0; ni < 4; ++ni)                       \
        bv[ni] = *(const bf16x8*)(smem + (pb) + (ni*4 + (kk))*1024 + l*16);  \
      _Pragma("unroll") for (int mi = 0; mi < 3; ++mi)                       \
        _Pragma("unroll") for (int ni = 0; ni < 4; ++ni)                     \
          oacc[mi][ni] = __builtin_amdgcn_mfma_f32_16x16x32_bf16(            \
              buf[mi], bv[ni], oacc[mi][ni], 0, 0, 0);                       \
    }

  bf16x8 afA[3], afB[3];
  bf16x8 avA[3], avB[3];

  LDA3(afA, w1b, 0)   // prologue: first P-group of chunk 0

  for (int c = 0; c < 12; ++c) {
    const unsigned short* pA = w1b + (size_t)c * 49152;
    const unsigned short* pV = w2b + c * 2048;
    unsigned pb = 49152u + (unsigned)(c & 1) * 16384u;

    f32x4 pacc[4];
    #pragma unroll
    for (int j = 0; j < 4; ++j) pacc[j] = (f32x4){0.f, 0.f, 0.f, 0.f};

    // P-phase: 4 groups of 3 k-steps, ping-pong prefetch; T5 around MFMA clusters
    LDA3(afB, pA, 3)
    __builtin_amdgcn_s_setprio(1); CMP3(afA, 0, pacc) __builtin_amdgcn_s_setprio(0);
    LDA3(afA, pA, 6)
    __builtin_amdgcn_s_setprio(1); CMP3(afB, 3, pacc) __builtin_amdgcn_s_setprio(0);
    LDA3(afB, pA, 9)
    __builtin_amdgcn_s_setprio(1); CMP3(afA, 6, pacc) __builtin_amdgcn_s_setprio(0);
    LDV(avA, pV, 0)
    __builtin_amdgcn_s_setprio(1); CMP3(afB, 9, pacc) __builtin_amdgcn_s_setprio(0);

    // P epilogue: bias1 + relu + bf16 pack -> Psf[c&1]
    {
      int fcb = c * 128 + w * 16 + lq * 4;
      float4 bb = *(const float4*)(b1 + fcb);
      unsigned pw = pb + (unsigned)((w >> 1) * 1024 +
                    (((w & 1) * 2 + (lq >> 1)) * 16 + l15) * 16 + (lq & 1) * 8);
      #pragma unroll
      for (int ni = 0; ni < 4; ++ni) {
        float p0 = pacc[ni][0] + bb.x;
        float p1 = pacc[ni][1] + bb.y;
        float p2 = pacc[ni][2] + bb.z;
        float p3 = pacc[ni][3] + bb.w;
        ushort4 pk;
        pk.x = f2bf(p0 > 0.f ? p0 : 0.f);
        pk.y = f2bf(p1 > 0.f ? p1 : 0.f);
        pk.z = f2bf(p2 > 0.f ? p2 : 0.f);
        pk.w = f2bf(p3 > 0.f ? p3 : 0.f);
        *(ushort4*)(smem + pw + ni * 4096) = pk;
      }
    }
    BAR_LGKM();   // single barrier per chunk: Psf[c&1] visible; prefetches in flight

    const unsigned short* pAn = w1b + (size_t)(c < 11 ? c + 1 : 11) * 49152;
    LDV(avB, pV, 1)
    __builtin_amdgcn_s_setprio(1); CMPV(avA, 0, pb) __builtin_amdgcn_s_setprio(0);
    LDV(avA, pV, 2)
    __builtin_amdgcn_s_setprio(1); CMPV(avB, 1, pb) __builtin_amdgcn_s_setprio(0);
    LDV(avB, pV, 3)
    __builtin_amdgcn_s_setprio(1); CMPV(avA, 2, pb) __builtin_amdgcn_s_setprio(0);
    LDA3(afA, pAn, 0)
    __builtin_amdgcn_s_setprio(1); CMPV(avB, 3, pb) __builtin_amdgcn_s_setprio(0);
    // no trailing barrier: next chunk writes Psf[(c+1)&1]
  }
  #undef LDV
  #undef CMPV

  // epilogue: out[row][ocol..+3] = oacc + b2 + res  (dwordx4)
  #pragma unroll
  for (int mi = 0; mi < 3; ++mi) {
    int ocb = w * 48 + mi * 16 + lq * 4;
    float4 b2v = *(const float4*)(b2 + ocb);
    #pragma unroll
    for (int ni = 0; ni < 4; ++ni) {
      size_t row = R0 + ni * 16 + l15;
      float* op = out + row * D_ + ocb;
      float4 r = *(const float4*)op;
      float4 o;
      o.x = oacc[mi][ni][0] + b2v.x + r.x;
      o.y = oacc[mi][ni][1] + b2v.y + r.y;
      o.z = oacc[mi][ni][2] + b2v.z + r.z;
      o.w = oacc[mi][ni][3] + b2v.w + r.w;
      *(float4*)op = o;
    }
  }
}

// ---------------- causal attention (+T5 setprio), one block per (b,h) ----------------
__global__ __launch_bounds__(256) void attn_kernel(const unsigned short* __restrict__ q,
                                                   const unsigned short* __restrict__ k,
                                                   const unsigned short* __restrict__ v,
                                                   unsigned short* __restrict__ o) {
  __shared__ __align__(16) char smem[52224];
  unsigned short (*Ks)[72]       = (unsigned short(*)[72])smem;
  unsigned short (*Ps)[32][136]  = (unsigned short(*)[32][136])smem;
  unsigned short (*Vt)[136]      = (unsigned short(*)[136])(smem + 34816);

  int bh = blockIdx.x;
  int b = bh / H_, h = bh % H_;
  int tid = threadIdx.x, w = tid >> 6, l = tid & 63;

  const unsigned short* kb = k + ((size_t)b * T_) * D_ + h * DH_;
  const unsigned short* vb = v + ((size_t)b * T_) * D_ + h * DH_;
  #pragma unroll
  for (int it = 0; it < 4; ++it) {
    int id = it * 256 + tid;
    int s = id >> 3, c8 = (id & 7) * 8;
    int4 kv = *(const int4*)(kb + (size_t)s * D_ + c8);
    *(int4*)(&Ks[s][c8]) = kv;
    int4 vv = *(const int4*)(vb + (size_t)s * D_ + c8);
    const unsigned short* pe = (const unsigned short*)&vv;
    #pragma unroll
    for (int j2 = 0; j2 < 8; ++j2) Vt[c8 + j2][s] = pe[j2];
  }
  __syncthreads();

  const unsigned short* qbp = q + ((size_t)b * T_) * D_ + h * DH_;
  int rowbase = w * 32;
  bf16x8 aq[2][2];
  #pragma unroll
  for (int mi = 0; mi < 2; ++mi)
    #pragma unroll
    for (int ks = 0; ks < 2; ++ks)
      aq[mi][ks] = *(const bf16x8*)(qbp + (size_t)(rowbase + mi*16 + (l & 15)) * D_
                                        + ks*32 + ((l >> 4) << 3));

  f32x4 accs[2][8];
  #pragma unroll
  for (int i = 0; i < 2; ++i)
    #pragma unroll
    for (int j = 0; j < 8; ++j) accs[i][j] = (f32x4){0.f, 0.f, 0.f, 0.f};
  #pragma unroll
  for (int ks = 0; ks < 2; ++ks) {
    bf16x8 bk[8];
    #pragma unroll
    for (int ni = 0; ni < 8; ++ni)
      bk[ni] = *(const bf16x8*)(&Ks[ni*16 + (l & 15)][ks*32 + ((l >> 4) << 3)]);
    __builtin_amdgcn_s_setprio(1);
    #pragma unroll
    for (int mi = 0; mi < 2; ++mi)
      #pragma unroll
      for (int ni = 0; ni < 8; ++ni)
        accs[mi][ni] = __builtin_amdgcn_mfma_f32_16x16x32_bf16(aq[mi][ks], bk[ni], accs[mi][ni], 0, 0, 0);
    __builtin_amdgcn_s_setprio(0);
  }
  __syncthreads();

  #pragma unroll
  for (int mi = 0; mi < 2; ++mi) {
    #pragma unroll
    for (int j = 0; j < 4; ++j) {
      int t = rowbase + mi*16 + ((l >> 4) << 2) + j;
      float mx = -1e30f;
      #pragma unroll
      for (int ni = 0; ni < 8; ++ni) {
        int scol = ni*16 + (l & 15);
        float sv = accs[mi][ni][j] * 0.125f;
        sv = (scol <= t) ? sv : -1e30f;
        accs[mi][ni][j] = sv;
        mx = fmaxf(mx, sv);
      }
      mx = fmaxf(mx, __shfl_xor(mx, 1));
      mx = fmaxf(mx, __shfl_xor(mx, 2));
      mx = fmaxf(mx, __shfl_xor(mx, 4));
      mx = fmaxf(mx, __shfl_xor(mx, 8));
      float sum = 0.f;
      #pragma unroll
      for (int ni = 0; ni < 8; ++ni) {
        float e = __expf(accs[mi][ni][j] - mx);
        accs[mi][ni][j] = e;
        sum += e;
      }
      sum += __shfl_xor(sum, 1);
      sum += __shfl_xor(sum, 2);
      sum += __shfl_xor(sum, 4);
      sum += __shfl_xor(sum, 8);
      float inv = 1.f / sum;
      #pragma unroll
      for (int ni = 0; ni < 8; ++ni)
        Ps[w][mi*16 + ((l >> 4) << 2) + j][ni*16 + (l & 15)] = f2bf(accs[mi][ni][j] * inv);
    }
  }
  __syncthreads();

  f32x4 acco[2][4];
  #pragma unroll
  for (int i = 0; i < 2; ++i)
    #pragma unroll
    for (int j = 0; j < 4; ++j) acco[i][j] = (f32x4){0.f, 0.f, 0.f, 0.f};
  #pragma unroll
  for (int ks = 0; ks < 4; ++ks) {
    bf16x8 ap[2], bv[4];
    #pragma unroll
    for (int mi = 0; mi < 2; ++mi)
      ap[mi] = *(const bf16x8*)(&Ps[w][mi*16 + (l & 15)][ks*32 + ((l >> 4) << 3)]);
    #pragma unroll
    for (int ni = 0; ni < 4; ++ni)
      bv[ni] = *(const bf16x8*)(&Vt[ni*16 + (l & 15)][ks*32 + ((l >> 4) << 3)]);
    __builtin_amdgcn_s_setprio(1);
    #pragma unroll
    for (int mi = 0; mi < 2; ++mi)
      #pragma unroll
      for (int ni = 0; ni < 4; ++ni)
        acco[mi][ni] = __builtin_amdgcn_mfma_f32_16x16x32_bf16(ap[mi], bv[ni], acco[mi][ni], 0, 0, 0);
    __builtin_amdgcn_s_setprio(0);
  }

  unsigned short* ob = o + ((size_t)b * T_) * D_ + h * DH_;
  #pragma unroll
  for (int mi = 0; mi < 2; ++mi)
    #pragma unroll
    for (int ni = 0; ni < 4; ++ni)
      #pragma unroll
      for (int j = 0; j < 4; ++j) {
        int t = rowbase + mi*16 + ((l >> 4) << 2) + j;
        int d = ni*16 + (l & 15);
        ob[(size_t)t * D_ + d] = f2bf(acco[mi][ni][j]);
      }
}

extern "C" void kernel_launch(void* const* d_in, const int* in_sizes, int n_in,
                              void* d_out, int out_size, void* d_ws, size_t ws_size,
                              hipStream_t stream) {
  const float* x   = (const float*)d_in[0];
  const float* Wq  = (const float*)d_in[1];
  const float* Wk  = (const float*)d_in[2];
  const float* Wv  = (const float*)d_in[3];
  const float* Wo  = (const float*)d_in[4];
  const float* bo  = (const float*)d_in[5];
  const float* W1  = (const float*)d_in[6];
  const float* b1  = (const float*)d_in[7];
  const float* W2  = (const float*)d_in[8];
  const float* b2  = (const float*)d_in[9];
  const float* g1  = (const float*)d_in[10];
  const float* be1 = (const float*)d_in[11];
  const float* g2  = (const float*)d_in[12];
  const float* be2 = (const float*)d_in[13];

  // workspace layout (bytes); total ~210 MiB
  char* ws = (char*)d_ws;
  unsigned short* hb    = (unsigned short*)(ws);               // h (LN1), later h2 (LN2)
  unsigned short* qb    = (unsigned short*)(ws +  50331648);   // q|k|v contiguous; o in-place
  unsigned short* kbuf  = (unsigned short*)(ws + 100663296);
  unsigned short* vbuf  = (unsigned short*)(ws + 150994944);
  unsigned short* wqT   = (unsigned short*)(ws + 201326592);   // [1152][384] (wq|wk|wv)
  unsigned short* woT   = wqT + 442368;                        // [384][384]
  unsigned short* w1T   = woT + 147456;                        // [1536][384]
  unsigned short* w2T   = w1T + 589824;                        // [384][1536]
  unsigned short* w1P   = w2T + 589824;                        // packed (pack_w1, NC=12)
  unsigned short* w2P   = w1P + 589824;                        // packed (pack_w2)
  unsigned short* wqkvP = w2P + 589824;                        // packed (pack_w1, NC=9)
  unsigned short* woP   = wqkvP + 442368;                      // packed (pack_w1, NC=3)
  float* x2 = (float*)d_out;
  (void)kbuf; (void)vbuf;

  // allow 80KB dynamic LDS for ffn_fused (host-side attribute; idempotent)
  hipFuncSetAttribute(reinterpret_cast<const void*>(ffn_fused),
                      hipFuncAttributeMaxDynamicSharedMemorySize, 81920);

  // 1) weight convert+transpose (tiny) + fragment-order packs
  wt_kernel<<<dim3(576),  256, 0, stream>>>(Wq, wqT,          384, 384);
  wt_kernel<<<dim3(576),  256, 0, stream>>>(Wk, wqT + 147456, 384, 384);
  wt_kernel<<<dim3(576),  256, 0, stream>>>(Wv, wqT + 294912, 384, 384);
  wt_kernel<<<dim3(576),  256, 0, stream>>>(Wo, woT,          384, 384);
  wt_kernel<<<dim3(2304), 256, 0, stream>>>(W1, w1T, 384, 1536);
  wt_kernel<<<dim3(2304), 256, 0, stream>>>(W2, w2T, 1536, 384);
  pack_w1<<<dim3(216), 256, 0, stream>>>(wqT, wqkvP);   // NC=9
  pack_w1<<<dim3(72),  256, 0, stream>>>(woT, woP);     // NC=3
  pack_w1<<<dim3(288), 256, 0, stream>>>(w1T, w1P);     // NC=12
  pack_w2<<<dim3(288), 256, 0, stream>>>(w2T, w2P);

  // 2) LN1: x -> h (bf16)
  ln_kernel<<<dim3(NROW / 4), 256, 0, stream>>>(x, g1, be1, hb);

  // 3) QKV GEMM v3 (32-row blocks, deferred epilogue): q|k|v = h @ [Wq|Wk|Wv]
  qkv_gemm<<<dim3(NROW / 32), 512, 0, stream>>>(hb, wqkvP, qb);

  // 4) attention: o overwrites q in place (per-block disjoint strips)
  attn_kernel<<<dim3(B_ * H_), 256, 0, stream>>>(qb, kbuf, vbuf, qb);

  // 5) fused Wo + residual + LN2: x2 -> d_out (fp32), h2 -> hb (bf16)
  wo_ln<<<dim3(NROW / 32), 512, 0, stream>>>(qb, woP, bo, x, g2, be2, x2, hb);

  // 6) fused FFN (dbuf-Psf, 1 barrier/chunk, 80KB dyn LDS)
  ffn_fused<<<dim3(NROW / 64), 512, 81920, stream>>>(hb, w1P, w2P, b1, b2, x2);
}

// Round 21
// 401.268 us; speedup vs baseline: 2.3280x; 1.0524x over previous
//
#include <hip/hip_runtime.h>

// Problem constants
#define B_   512
#define T_   128
#define D_   384
#define H_   6
#define DH_  64
#define DFF_ 1536
#define NROW (B_*T_)   // 65536 rows

typedef __attribute__((ext_vector_type(8))) short bf16x8;   // MFMA A/B frag (4 VGPRs)
typedef __attribute__((ext_vector_type(4))) float f32x4;    // MFMA C/D frag

__device__ __forceinline__ unsigned short f2bf(float f) {
  union { float f; unsigned u; } v; v.f = f;
  unsigned r = v.u + 0x7fffu + ((v.u >> 16) & 1u);   // RNE
  return (unsigned short)(r >> 16);
}

// lgkm-only barrier (keeps reg-destined global loads in flight)
#define BAR_LGKM() asm volatile("s_waitcnt lgkmcnt(0)\n\ts_barrier" ::: "memory")

// ======== direct fragment-order weight packing from fp32 (bit-identical to the
// ======== old wt_kernel+pack two-stage path: same f2bf at the same element) =====
// K=384 family mapping (frag=(c*8+w8)*12+k): chunk tid holds
//   WT[r = c*128+w*32+mi*16+l15][col = k*32+lq*8 + e] = f2bf(Wsrc[col+e][r%384])
__global__ void pack_wqkv(const float* __restrict__ Wq, const float* __restrict__ Wk,
                          const float* __restrict__ Wv, unsigned short* __restrict__ WP) {
  int tid = blockIdx.x * 256 + threadIdx.x;      // 55296 chunks (216 blocks)
  int lane = tid & 63, frag = tid >> 6;
  int k = frag % 12, t2 = frag / 12;
  int mi = t2 & 1, t3 = t2 >> 1;
  int w = t3 & 3, c = t3 >> 2;                   // c in 0..8
  int l15 = lane & 15, lq = lane >> 4;
  int r = c * 128 + w * 32 + mi * 16 + l15;      // 0..1151
  int col = k * 32 + lq * 8;
  const float* Wsrc = (c < 3) ? Wq : (c < 6) ? Wk : Wv;
  int rr = r - (c / 3) * 384;
  unsigned short tmp[8];
  #pragma unroll
  for (int e = 0; e < 8; ++e)
    tmp[e] = f2bf(Wsrc[(size_t)(col + e) * 384 + rr]);
  *(int4*)(WP + (size_t)tid * 8) = *(const int4*)tmp;
}
// generic K=384, single source W [384][ld]: r in [0, ld)
__global__ void pack_k384(const float* __restrict__ W, unsigned short* __restrict__ WP,
                          int ld) {
  int tid = blockIdx.x * 256 + threadIdx.x;
  int lane = tid & 63, frag = tid >> 6;
  int k = frag % 12, t2 = frag / 12;
  int mi = t2 & 1, t3 = t2 >> 1;
  int w = t3 & 3, c = t3 >> 2;
  int l15 = lane & 15, lq = lane >> 4;
  int r = c * 128 + w * 32 + mi * 16 + l15;
  int col = k * 32 + lq * 8;
  unsigned short tmp[8];
  #pragma unroll
  for (int e = 0; e < 8; ++e)
    tmp[e] = f2bf(W[(size_t)(col + e) * ld + r]);
  *(int4*)(WP + (size_t)tid * 8) = *(const int4*)tmp;
}
// W2 [1536][384]: frag=(((w4*6+mi6)*12+c)*4+kk); value = W2[col+e][r]
__global__ void pack_w2d(const float* __restrict__ W2, unsigned short* __restrict__ W2P) {
  int tid = blockIdx.x * 256 + threadIdx.x;      // 73728 chunks (288 blocks)
  int lane = tid & 63, frag = tid >> 6;
  int kk = frag & 3, t2 = frag >> 2;
  int c = t2 % 12, t3 = t2 / 12;
  int mi = t3 % 6, w = t3 / 6;
  int l15 = lane & 15, lq = lane >> 4;
  int r = w * 96 + mi * 16 + l15;                // 0..383
  int col = c * 128 + kk * 32 + lq * 8;          // 0..1535
  unsigned short tmp[8];
  #pragma unroll
  for (int e = 0; e < 8; ++e)
    tmp[e] = f2bf(W2[(size_t)(col + e) * 384 + r]);
  *(int4*)(W2P + (size_t)tid * 8) = *(const int4*)tmp;
}

// ---------------- layernorm (LN1): fp32 in -> bf16 out (one wave per row; R9) -------
__global__ __launch_bounds__(256) void ln_kernel(const float* __restrict__ x,
                                                 const float* __restrict__ g,
                                                 const float* __restrict__ be,
                                                 unsigned short* __restrict__ out) {
  int row = (blockIdx.x * 256 + threadIdx.x) >> 6;
  int l = threadIdx.x & 63;
  const float* xr = x + (size_t)row * D_;
  float v[6]; float s = 0.f, ss = 0.f;
  #pragma unroll
  for (int i = 0; i < 6; ++i) { v[i] = xr[l + i*64]; s += v[i]; ss += v[i]*v[i]; }
  #pragma unroll
  for (int m = 1; m < 64; m <<= 1) { s += __shfl_xor(s, m); ss += __shfl_xor(ss, m); }
  float mu  = s * (1.f / D_);
  float var = ss * (1.f / D_) - mu * mu;
  float rs  = rsqrtf(var + 1e-5f);
  unsigned short* orow = out + (size_t)row * D_;
  #pragma unroll
  for (int i = 0; i < 6; ++i) {
    int c = l + i*64;
    orow[c] = f2bf((v[i] - mu) * rs * g[c] + be[c]);
  }
}

// ---------------- QKV GEMM v3 (32-row block, k-outer, deferred epilogue; R17-19) ----
__global__ __launch_bounds__(512, 4) void qkv_gemm(
    const unsigned short* __restrict__ h, const unsigned short* __restrict__ wP,
    unsigned short* __restrict__ qkv)
{
  __shared__ __align__(16) char smem[25600];   // staging 24576 | transpose 32x784
  int tid = threadIdx.x, w = tid >> 6, l = tid & 63;
  int l15 = l & 15, lq = l >> 4;
  size_t R0 = (size_t)blockIdx.x * 32;

  // ---- stage h strip (32 rows) -> frag-order LDS: 512 thr x 3 int4 ----
  {
    int row = tid >> 4, gi = row >> 4, l15w = row & 15;
    const unsigned short* src = h + (R0 + row) * 384 + (tid & 15) * 24;
    #pragma unroll
    for (int i = 0; i < 3; ++i) {
      int col = (tid & 15) * 24 + i * 8;
      int k = col >> 5, lqw = (col >> 3) & 3;
      *(int4*)(smem + (gi*12 + k)*1024 + (lqw*16 + l15w)*16) = *(const int4*)(src + i*8);
    }
  }
  __syncthreads();

  f32x4 acc[9][2];
  #pragma unroll
  for (int c = 0; c < 9; ++c)
    #pragma unroll
    for (int ni = 0; ni < 2; ++ni) acc[c][ni] = (f32x4){0.f, 0.f, 0.f, 0.f};

  const unsigned short* wb = wP + l * 8;       // + ((c*8+w)*12 + k)*512

  #define LDG(dst, cb, k)                                                    \
    { _Pragma("unroll") for (int ci = 0; ci < 3; ++ci)                       \
        dst[ci] = *(const bf16x8*)(wb + (((cb)+ci)*8 + w) * 6144 + (k) * 512); }

  #define CMPG(buf, cb)                                                      \
    { _Pragma("unroll") for (int ci = 0; ci < 3; ++ci)                       \
        _Pragma("unroll") for (int ni = 0; ni < 2; ++ni)                     \
          acc[(cb)+ci][ni] = __builtin_amdgcn_mfma_f32_16x16x32_bf16(        \
              buf[ci], bfr[ni], acc[(cb)+ci][ni], 0, 0, 0); }

  bf16x8 a0[3], a1[3], a2[3];
  LDG(a0, 0, 0)                                // preload k=0 group 0

  for (int k = 0; k < 12; ++k) {
    bf16x8 bfr[2];
    #pragma unroll
    for (int ni = 0; ni < 2; ++ni)
      bfr[ni] = *(const bf16x8*)(smem + (ni*12 + k)*1024 + l*16);
    int kn = (k < 11) ? k + 1 : 11;
    LDG(a1, 3, k)
    __builtin_amdgcn_s_setprio(1); CMPG(a0, 0) __builtin_amdgcn_s_setprio(0);
    LDG(a2, 6, k)
    __builtin_amdgcn_s_setprio(1); CMPG(a1, 3) __builtin_amdgcn_s_setprio(0);
    LDG(a0, 0, kn)
    __builtin_amdgcn_s_setprio(1); CMPG(a2, 6) __builtin_amdgcn_s_setprio(0);
  }
  #undef LDG
  #undef CMPG

  // ---- deferred epilogue: per buffer (q,k,v): acc -> LDS (784B rows) -> int4 stores
  __syncthreads();                              // staging region dead; reads drained
  #pragma unroll
  for (int buf = 0; buf < 3; ++buf) {
    #pragma unroll
    for (int ci = 0; ci < 3; ++ci) {
      int c = buf * 3 + ci;
      #pragma unroll
      for (int ni = 0; ni < 2; ++ni) {
        int row = ni * 16 + l15;
        ushort4 pk;
        pk.x = f2bf(acc[c][ni][0]);
        pk.y = f2bf(acc[c][ni][1]);
        pk.z = f2bf(acc[c][ni][2]);
        pk.w = f2bf(acc[c][ni][3]);
        *(ushort4*)(smem + row * 784 + ci * 256 + w * 32 + lq * 8) = pk;
      }
    }
    __syncthreads();
    {
      int row = tid >> 4;
      unsigned short* obase = qkv + (size_t)buf * NROW * 384 + (R0 + row) * 384;
      #pragma unroll
      for (int i = 0; i < 3; ++i) {
        int ob = (tid & 15) * 16 + i * 256;     // byte offset in 768-B row
        *(int4*)(obase + (ob >> 1)) = *(const int4*)(smem + row * 784 + ob);
      }
    }
    __syncthreads();
  }
}

// ---------------- fused Wo + residual + LN2 (32-row block; R19-proven) --------------
__global__ __launch_bounds__(512, 4) void wo_ln(
    const unsigned short* __restrict__ o,    // [NROW][384] bf16 (attention out)
    const unsigned short* __restrict__ wP,   // woP packed (NC=3)
    const float* __restrict__ bo, const float* __restrict__ xres,
    const float* __restrict__ g, const float* __restrict__ be,
    float* __restrict__ x2out,               // d_out
    unsigned short* __restrict__ h2out)      // hb
{
  __shared__ __align__(16) char smem[50176]; // staging 24576 (reused) | x2 tile 32x392 f32
  int tid = threadIdx.x, w = tid >> 6, l = tid & 63;
  int l15 = l & 15, lq = l >> 4;
  size_t R0 = (size_t)blockIdx.x * 32;

  // ---- stage o strip (32 rows) -> frag-order LDS (qkv-v3 pattern) ----
  {
    int row = tid >> 4, gi = row >> 4, l15w = row & 15;
    const unsigned short* src = o + (R0 + row) * 384 + (tid & 15) * 24;
    #pragma unroll
    for (int i = 0; i < 3; ++i) {
      int col = (tid & 15) * 24 + i * 8;
      int k = col >> 5, lqw = (col >> 3) & 3;
      *(int4*)(smem + (gi*12 + k)*1024 + (lqw*16 + l15w)*16) = *(const int4*)(src + i*8);
    }
  }
  __syncthreads();

  f32x4 acc[3][2];
  #pragma unroll
  for (int c = 0; c < 3; ++c)
    #pragma unroll
    for (int ni = 0; ni < 2; ++ni) acc[c][ni] = (f32x4){0.f, 0.f, 0.f, 0.f};

  const unsigned short* wb = wP + l * 8;       // + ((ci*8+w)*12 + k)*512

  #define LDGW(dst, k)                                                       \
    { _Pragma("unroll") for (int ci = 0; ci < 3; ++ci)                       \
        dst[ci] = *(const bf16x8*)(wb + (ci*8 + w) * 6144 + (k) * 512); }

  #define CMPW(buf)                                                          \
    { _Pragma("unroll") for (int ci = 0; ci < 3; ++ci)                       \
        _Pragma("unroll") for (int ni = 0; ni < 2; ++ni)                     \
          acc[ci][ni] = __builtin_amdgcn_mfma_f32_16x16x32_bf16(             \
              buf[ci], bfr[ni], acc[ci][ni], 0, 0, 0); }

  bf16x8 aA[3], aB[3];
  LDGW(aA, 0)
  for (int k = 0; k < 12; k += 2) {
    bf16x8 bfr[2];
    #pragma unroll
    for (int ni = 0; ni < 2; ++ni)
      bfr[ni] = *(const bf16x8*)(smem + (ni*12 + k)*1024 + l*16);
    LDGW(aB, k + 1)
    __builtin_amdgcn_s_setprio(1); CMPW(aA) __builtin_amdgcn_s_setprio(0);
    #pragma unroll
    for (int ni = 0; ni < 2; ++ni)
      bfr[ni] = *(const bf16x8*)(smem + (ni*12 + k + 1)*1024 + l*16);
    int kn = (k + 2 < 12) ? k + 2 : 11;
    LDGW(aA, kn)
    __builtin_amdgcn_s_setprio(1); CMPW(aB) __builtin_amdgcn_s_setprio(0);
  }
  #undef LDGW
  #undef CMPW

  // ---- epilogue: x2 = acc + bo + x -> LDS tile [32][392] f32 ----
  __syncthreads();                              // staging reads retired
  #pragma unroll
  for (int ci = 0; ci < 3; ++ci) {
    int col = ci * 128 + w * 16 + lq * 4;
    float4 bb = *(const float4*)(bo + col);
    #pragma unroll
    for (int ni = 0; ni < 2; ++ni) {
      int row = ni * 16 + l15;
      float4 r = *(const float4*)(xres + (R0 + row) * 384 + col);
      float4 v;
      v.x = acc[ci][ni][0] + bb.x + r.x;
      v.y = acc[ci][ni][1] + bb.y + r.y;
      v.z = acc[ci][ni][2] + bb.z + r.z;
      v.w = acc[ci][ni][3] + bb.w + r.w;
      *(float4*)(smem + row * 1568 + col * 4) = v;
    }
  }
  __syncthreads();

  // ---- LN2 on the tile: 16 thr/row; emit x2 fp32 + h2 bf16 (coalesced) ----
  {
    int row = tid >> 4, t16 = tid & 15;
    const char* rbase = smem + row * 1568;
    float4 vv[6];
    float s = 0.f, ss = 0.f;
    #pragma unroll
    for (int i = 0; i < 6; ++i) {
      vv[i] = *(const float4*)(rbase + (t16 + i * 16) * 16);
      s  += vv[i].x + vv[i].y + vv[i].z + vv[i].w;
      ss += vv[i].x*vv[i].x + vv[i].y*vv[i].y + vv[i].z*vv[i].z + vv[i].w*vv[i].w;
    }
    s += __shfl_xor(s, 1); ss += __shfl_xor(ss, 1);
    s += __shfl_xor(s, 2); ss += __shfl_xor(ss, 2);
    s += __shfl_xor(s, 4); ss += __shfl_xor(ss, 4);
    s += __shfl_xor(s, 8); ss += __shfl_xor(ss, 8);
    float mu = s * (1.f / 384.f);
    float rs = rsqrtf(ss * (1.f / 384.f) - mu * mu + 1e-5f);
    float* xrow = x2out + (R0 + row) * 384;
    unsigned short* hrow = h2out + (R0 + row) * 384;
    #pragma unroll
    for (int i = 0; i < 6; ++i) {
      int c4 = t16 + i * 16;                   // float4 index in row
      float4 ga = *(const float4*)(g  + c4 * 4);
      float4 ba = *(const float4*)(be + c4 * 4);
      *(float4*)(xrow + c4 * 4) = vv[i];
      ushort4 pk;
      pk.x = f2bf((vv[i].x - mu) * rs * ga.x + ba.x);
      pk.y = f2bf((vv[i].y - mu) * rs * ga.y + ba.y);
      pk.z = f2bf((vv[i].z - mu) * rs * ga.z + ba.z);
      pk.w = f2bf((vv[i].w - mu) * rs * ga.w + ba.w);
      *(ushort4*)(hrow + c4 * 4) = pk;
    }
  }
}

// ======== 8-wave ffn building blocks (frag-order LDS + packed W) ========
#define LDA3(dst, pA, k0)                                                    \
  { _Pragma("unroll") for (int kq = 0; kq < 3; ++kq)                         \
      dst[kq] = *(const bf16x8*)((pA) + ((k0) + kq) * 512); }

#define CMP3(buf, k0, acc)                                                   \
  { _Pragma("unroll") for (int kq = 0; kq < 3; ++kq) {                       \
      bf16x8 bfr[4];                                                         \
      _Pragma("unroll") for (int ni = 0; ni < 4; ++ni)                       \
        bfr[ni] = *(const bf16x8*)(smem + (ni*12 + (k0)+kq)*1024 + l*16);    \
      _Pragma("unroll") for (int ni = 0; ni < 4; ++ni)                       \
        acc[ni] = __builtin_amdgcn_mfma_f32_16x16x32_bf16(                   \
            buf[kq], bfr[ni], acc[ni], 0, 0, 0);                             \
    } }

// ---------------- fused FFN (8-wave, setprio, dbuf Psf, 1 barrier/chunk; R18-19) ----
__global__ __launch_bounds__(512, 4) void ffn_fused(
    const unsigned short* __restrict__ h2,   // [NROW][384] bf16
    const unsigned short* __restrict__ w1P,  // packed (NC=12)
    const unsigned short* __restrict__ w2P,  // packed (pack_w2d)
    const float* __restrict__ b1,            // [1536]
    const float* __restrict__ b2,            // [384]
    float* __restrict__ out)                 // [NROW][384] fp32, in-place residual add
{
  extern __shared__ __align__(16) char smem[];
  int tid = threadIdx.x, w = tid >> 6, l = tid & 63;
  int l15 = l & 15, lq = l >> 4;
  size_t R0 = (size_t)blockIdx.x * 64;

  // ---- stage h2 strip -> frag-order LDS (512 thr x 48 elems) ----
  {
    int row = tid >> 3, gi = row >> 4, l15w = row & 15;
    int cbase = (tid & 7) * 48;
    const unsigned short* src = h2 + (R0 + row) * 384 + cbase;
    #pragma unroll
    for (int i = 0; i < 6; ++i) {
      int col = cbase + i * 8;
      int k = col >> 5, lqw = (col >> 3) & 3;
      *(int4*)(smem + (gi*12 + k)*1024 + (lqw*16 + l15w)*16) = *(const int4*)(src + i*8);
    }
  }
  __syncthreads();

  f32x4 oacc[3][4];
  #pragma unroll
  for (int i = 0; i < 3; ++i)
    #pragma unroll
    for (int j = 0; j < 4; ++j) oacc[i][j] = (f32x4){0.f, 0.f, 0.f, 0.f};

  const unsigned short* w1b = w1P + w * 6144  + l * 8;  // + c*49152 + k*512
  const unsigned short* w2b = w2P + w * 73728 + l * 8;  // + mi*24576 + c*2048 + kk*512

  #define LDV(dst, pV, kk)                                                   \
    { _Pragma("unroll") for (int mi = 0; mi < 3; ++mi)                       \
        dst[mi] = *(const bf16x8*)((pV) + mi * 24576 + (kk) * 512); }

  #define CMPV(buf, kk, pb)                                                  \
    { bf16x8 bv[4];                                                          \
      _Pragma("unroll") for (int ni = 0; ni < 4; ++ni)                       \
        bv[ni] = *(const bf16x8*)(smem + (pb) + (ni*4 + (kk))*1024 + l*16);  \
      _Pragma("unroll") for (int mi = 0; mi < 3; ++mi)                       \
        _Pragma("unroll") for (int ni = 0; ni < 4; ++ni)                     \
          oacc[mi][ni] = __builtin_amdgcn_mfma_f32_16x16x32_bf16(            \
              buf[mi], bv[ni], oacc[mi][ni], 0, 0, 0);                       \
    }

  bf16x8 afA[3], afB[3];
  bf16x8 avA[3], avB[3];

  LDA3(afA, w1b, 0)   // prologue: first P-group of chunk 0

  for (int c = 0; c < 12; ++c) {
    const unsigned short* pA = w1b + (size_t)c * 49152;
    const unsigned short* pV = w2b + c * 2048;
    unsigned pb = 49152u + (unsigned)(c & 1) * 16384u;

    f32x4 pacc[4];
    #pragma unroll
    for (int j = 0; j < 4; ++j) pacc[j] = (f32x4){0.f, 0.f, 0.f, 0.f};

    // P-phase: 4 groups of 3 k-steps, ping-pong prefetch; T5 around MFMA clusters
    LDA3(afB, pA, 3)
    __builtin_amdgcn_s_setprio(1); CMP3(afA, 0, pacc) __builtin_amdgcn_s_setprio(0);
    LDA3(afA, pA, 6)
    __builtin_amdgcn_s_setprio(1); CMP3(afB, 3, pacc) __builtin_amdgcn_s_setprio(0);
    LDA3(afB, pA, 9)
    __builtin_amdgcn_s_setprio(1); CMP3(afA, 6, pacc) __builtin_amdgcn_s_setprio(0);
    LDV(avA, pV, 0)
    __builtin_amdgcn_s_setprio(1); CMP3(afB, 9, pacc) __builtin_amdgcn_s_setprio(0);

    // P epilogue: bias1 + relu + bf16 pack -> Psf[c&1]
    {
      int fcb = c * 128 + w * 16 + lq * 4;
      float4 bb = *(const float4*)(b1 + fcb);
      unsigned pw = pb + (unsigned)((w >> 1) * 1024 +
                    (((w & 1) * 2 + (lq >> 1)) * 16 + l15) * 16 + (lq & 1) * 8);
      #pragma unroll
      for (int ni = 0; ni < 4; ++ni) {
        float p0 = pacc[ni][0] + bb.x;
        float p1 = pacc[ni][1] + bb.y;
        float p2 = pacc[ni][2] + bb.z;
        float p3 = pacc[ni][3] + bb.w;
        ushort4 pk;
        pk.x = f2bf(p0 > 0.f ? p0 : 0.f);
        pk.y = f2bf(p1 > 0.f ? p1 : 0.f);
        pk.z = f2bf(p2 > 0.f ? p2 : 0.f);
        pk.w = f2bf(p3 > 0.f ? p3 : 0.f);
        *(ushort4*)(smem + pw + ni * 4096) = pk;
      }
    }
    BAR_LGKM();   // single barrier per chunk: Psf[c&1] visible; prefetches in flight

    const unsigned short* pAn = w1b + (size_t)(c < 11 ? c + 1 : 11) * 49152;
    LDV(avB, pV, 1)
    __builtin_amdgcn_s_setprio(1); CMPV(avA, 0, pb) __builtin_amdgcn_s_setprio(0);
    LDV(avA, pV, 2)
    __builtin_amdgcn_s_setprio(1); CMPV(avB, 1, pb) __builtin_amdgcn_s_setprio(0);
    LDV(avB, pV, 3)
    __builtin_amdgcn_s_setprio(1); CMPV(avA, 2, pb) __builtin_amdgcn_s_setprio(0);
    LDA3(afA, pAn, 0)
    __builtin_amdgcn_s_setprio(1); CMPV(avB, 3, pb) __builtin_amdgcn_s_setprio(0);
    // no trailing barrier: next chunk writes Psf[(c+1)&1]
  }
  #undef LDV
  #undef CMPV

  // epilogue: out[row][ocol..+3] = oacc + b2 + res  (dwordx4)
  #pragma unroll
  for (int mi = 0; mi < 3; ++mi) {
    int ocb = w * 48 + mi * 16 + lq * 4;
    float4 b2v = *(const float4*)(b2 + ocb);
    #pragma unroll
    for (int ni = 0; ni < 4; ++ni) {
      size_t row = R0 + ni * 16 + l15;
      float* op = out + row * D_ + ocb;
      float4 r = *(const float4*)op;
      float4 o;
      o.x = oacc[mi][ni][0] + b2v.x + r.x;
      o.y = oacc[mi][ni][1] + b2v.y + r.y;
      o.z = oacc[mi][ni][2] + b2v.z + r.z;
      o.w = oacc[mi][ni][3] + b2v.w + r.w;
      *(float4*)op = o;
    }
  }
}

// ---------------- causal attention (+T5 setprio), one block per (b,h) ----------------
__global__ __launch_bounds__(256) void attn_kernel(const unsigned short* __restrict__ q,
                                                   const unsigned short* __restrict__ k,
                                                   const unsigned short* __restrict__ v,
                                                   unsigned short* __restrict__ o) {
  __shared__ __align__(16) char smem[52224];
  unsigned short (*Ks)[72]       = (unsigned short(*)[72])smem;
  unsigned short (*Ps)[32][136]  = (unsigned short(*)[32][136])smem;
  unsigned short (*Vt)[136]      = (unsigned short(*)[136])(smem + 34816);

  int bh = blockIdx.x;
  int b = bh / H_, h = bh % H_;
  int tid = threadIdx.x, w = tid >> 6, l = tid & 63;

  const unsigned short* kb = k + ((size_t)b * T_) * D_ + h * DH_;
  const unsigned short* vb = v + ((size_t)b * T_) * D_ + h * DH_;
  #pragma unroll
  for (int it = 0; it < 4; ++it) {
    int id = it * 256 + tid;
    int s = id >> 3, c8 = (id & 7) * 8;
    int4 kv = *(const int4*)(kb + (size_t)s * D_ + c8);
    *(int4*)(&Ks[s][c8]) = kv;
    int4 vv = *(const int4*)(vb + (size_t)s * D_ + c8);
    const unsigned short* pe = (const unsigned short*)&vv;
    #pragma unroll
    for (int j2 = 0; j2 < 8; ++j2) Vt[c8 + j2][s] = pe[j2];
  }
  __syncthreads();

  const unsigned short* qbp = q + ((size_t)b * T_) * D_ + h * DH_;
  int rowbase = w * 32;
  bf16x8 aq[2][2];
  #pragma unroll
  for (int mi = 0; mi < 2; ++mi)
    #pragma unroll
    for (int ks = 0; ks < 2; ++ks)
      aq[mi][ks] = *(const bf16x8*)(qbp + (size_t)(rowbase + mi*16 + (l & 15)) * D_
                                        + ks*32 + ((l >> 4) << 3));

  f32x4 accs[2][8];
  #pragma unroll
  for (int i = 0; i < 2; ++i)
    #pragma unroll
    for (int j = 0; j < 8; ++j) accs[i][j] = (f32x4){0.f, 0.f, 0.f, 0.f};
  #pragma unroll
  for (int ks = 0; ks < 2; ++ks) {
    bf16x8 bk[8];
    #pragma unroll
    for (int ni = 0; ni < 8; ++ni)
      bk[ni] = *(const bf16x8*)(&Ks[ni*16 + (l & 15)][ks*32 + ((l >> 4) << 3)]);
    __builtin_amdgcn_s_setprio(1);
    #pragma unroll
    for (int mi = 0; mi < 2; ++mi)
      #pragma unroll
      for (int ni = 0; ni < 8; ++ni)
        accs[mi][ni] = __builtin_amdgcn_mfma_f32_16x16x32_bf16(aq[mi][ks], bk[ni], accs[mi][ni], 0, 0, 0);
    __builtin_amdgcn_s_setprio(0);
  }
  __syncthreads();

  #pragma unroll
  for (int mi = 0; mi < 2; ++mi) {
    #pragma unroll
    for (int j = 0; j < 4; ++j) {
      int t = rowbase + mi*16 + ((l >> 4) << 2) + j;
      float mx = -1e30f;
      #pragma unroll
      for (int ni = 0; ni < 8; ++ni) {
        int scol = ni*16 + (l & 15);
        float sv = accs[mi][ni][j] * 0.125f;
        sv = (scol <= t) ? sv : -1e30f;
        accs[mi][ni][j] = sv;
        mx = fmaxf(mx, sv);
      }
      mx = fmaxf(mx, __shfl_xor(mx, 1));
      mx = fmaxf(mx, __shfl_xor(mx, 2));
      mx = fmaxf(mx, __shfl_xor(mx, 4));
      mx = fmaxf(mx, __shfl_xor(mx, 8));
      float sum = 0.f;
      #pragma unroll
      for (int ni = 0; ni < 8; ++ni) {
        float e = __expf(accs[mi][ni][j] - mx);
        accs[mi][ni][j] = e;
        sum += e;
      }
      sum += __shfl_xor(sum, 1);
      sum += __shfl_xor(sum, 2);
      sum += __shfl_xor(sum, 4);
      sum += __shfl_xor(sum, 8);
      float inv = 1.f / sum;
      #pragma unroll
      for (int ni = 0; ni < 8; ++ni)
        Ps[w][mi*16 + ((l >> 4) << 2) + j][ni*16 + (l & 15)] = f2bf(accs[mi][ni][j] * inv);
    }
  }
  __syncthreads();

  f32x4 acco[2][4];
  #pragma unroll
  for (int i = 0; i < 2; ++i)
    #pragma unroll
    for (int j = 0; j < 4; ++j) acco[i][j] = (f32x4){0.f, 0.f, 0.f, 0.f};
  #pragma unroll
  for (int ks = 0; ks < 4; ++ks) {
    bf16x8 ap[2], bv[4];
    #pragma unroll
    for (int mi = 0; mi < 2; ++mi)
      ap[mi] = *(const bf16x8*)(&Ps[w][mi*16 + (l & 15)][ks*32 + ((l >> 4) << 3)]);
    #pragma unroll
    for (int ni = 0; ni < 4; ++ni)
      bv[ni] = *(const bf16x8*)(&Vt[ni*16 + (l & 15)][ks*32 + ((l >> 4) << 3)]);
    __builtin_amdgcn_s_setprio(1);
    #pragma unroll
    for (int mi = 0; mi < 2; ++mi)
      #pragma unroll
      for (int ni = 0; ni < 4; ++ni)
        acco[mi][ni] = __builtin_amdgcn_mfma_f32_16x16x32_bf16(ap[mi], bv[ni], acco[mi][ni], 0, 0, 0);
    __builtin_amdgcn_s_setprio(0);
  }

  unsigned short* ob = o + ((size_t)b * T_) * D_ + h * DH_;
  #pragma unroll
  for (int mi = 0; mi < 2; ++mi)
    #pragma unroll
    for (int ni = 0; ni < 4; ++ni)
      #pragma unroll
      for (int j = 0; j < 4; ++j) {
        int t = rowbase + mi*16 + ((l >> 4) << 2) + j;
        int d = ni*16 + (l & 15);
        ob[(size_t)t * D_ + d] = f2bf(acco[mi][ni][j]);
      }
}

extern "C" void kernel_launch(void* const* d_in, const int* in_sizes, int n_in,
                              void* d_out, int out_size, void* d_ws, size_t ws_size,
                              hipStream_t stream) {
  const float* x   = (const float*)d_in[0];
  const float* Wq  = (const float*)d_in[1];
  const float* Wk  = (const float*)d_in[2];
  const float* Wv  = (const float*)d_in[3];
  const float* Wo  = (const float*)d_in[4];
  const float* bo  = (const float*)d_in[5];
  const float* W1  = (const float*)d_in[6];
  const float* b1  = (const float*)d_in[7];
  const float* W2  = (const float*)d_in[8];
  const float* b2  = (const float*)d_in[9];
  const float* g1  = (const float*)d_in[10];
  const float* be1 = (const float*)d_in[11];
  const float* g2  = (const float*)d_in[12];
  const float* be2 = (const float*)d_in[13];

  // workspace layout (bytes); total ~204 MiB
  char* ws = (char*)d_ws;
  unsigned short* hb    = (unsigned short*)(ws);               // h (LN1), later h2 (LN2)
  unsigned short* qb    = (unsigned short*)(ws +  50331648);   // q|k|v contiguous; o in-place
  unsigned short* kbuf  = (unsigned short*)(ws + 100663296);
  unsigned short* vbuf  = (unsigned short*)(ws + 150994944);
  unsigned short* wqkvP = (unsigned short*)(ws + 201326592);   // packed (pack_wqkv, NC=9)
  unsigned short* woP   = wqkvP + 442368;                      // packed (pack_k384, NC=3)
  unsigned short* w1P   = woP + 147456;                        // packed (pack_k384, NC=12)
  unsigned short* w2P   = w1P + 589824;                        // packed (pack_w2d)
  float* x2 = (float*)d_out;
  (void)kbuf; (void)vbuf;

  // allow 80KB dynamic LDS for ffn_fused (host-side attribute; idempotent)
  hipFuncSetAttribute(reinterpret_cast<const void*>(ffn_fused),
                      hipFuncAttributeMaxDynamicSharedMemorySize, 81920);

  // 1) direct fragment-order packs from fp32 weights (bit-identical values)
  pack_wqkv<<<dim3(216), 256, 0, stream>>>(Wq, Wk, Wv, wqkvP);
  pack_k384<<<dim3(72),  256, 0, stream>>>(Wo, woP, 384);
  pack_k384<<<dim3(288), 256, 0, stream>>>(W1, w1P, 1536);
  pack_w2d <<<dim3(288), 256, 0, stream>>>(W2, w2P);

  // 2) LN1 (R9-exact): x -> h (bf16)
  ln_kernel<<<dim3(NROW / 4), 256, 0, stream>>>(x, g1, be1, hb);

  // 3) QKV GEMM v3 (32-row blocks, deferred epilogue): q|k|v = h @ [Wq|Wk|Wv]
  qkv_gemm<<<dim3(NROW / 32), 512, 0, stream>>>(hb, wqkvP, qb);

  // 4) attention: o overwrites q in place (per-block disjoint strips)
  attn_kernel<<<dim3(B_ * H_), 256, 0, stream>>>(qb, kbuf, vbuf, qb);

  // 5) fused Wo + residual + LN2: x2 -> d_out (fp32), h2 -> hb (bf16)
  wo_ln<<<dim3(NROW / 32), 512, 0, stream>>>(qb, woP, bo, x, g2, be2, x2, hb);

  // 6) fused FFN (dbuf-Psf, 1 barrier/chunk, 80KB dyn LDS)
  ffn_fused<<<dim3(NROW / 64), 512, 81920, stream>>>(hb, w1P, w2P, b1, b2, x2);
}

// Round 22
// 380.757 us; speedup vs baseline: 2.4534x; 1.0539x over previous
//
#include <hip/hip_runtime.h>

// Problem constants
#define B_   512
#define T_   128
#define D_   384
#define H_   6
#define DH_  64
#define DFF_ 1536
#define NROW (B_*T_)   // 65536 rows

typedef __attribute__((ext_vector_type(8))) short bf16x8;   // MFMA A/B frag (4 VGPRs)
typedef __attribute__((ext_vector_type(4))) float f32x4;    // MFMA C/D frag

__device__ __forceinline__ unsigned short f2bf(float f) {
  union { float f; unsigned u; } v; v.f = f;
  unsigned r = v.u + 0x7fffu + ((v.u >> 16) & 1u);   // RNE
  return (unsigned short)(r >> 16);
}

// lgkm-only barrier (keeps reg-destined global loads in flight)
#define BAR_LGKM() asm volatile("s_waitcnt lgkmcnt(0)\n\ts_barrier" ::: "memory")

// ======== direct fragment-order weight packing from fp32 (R21-proven) ==========
__global__ void pack_wqkv(const float* __restrict__ Wq, const float* __restrict__ Wk,
                          const float* __restrict__ Wv, unsigned short* __restrict__ WP) {
  int tid = blockIdx.x * 256 + threadIdx.x;      // 55296 chunks (216 blocks)
  int lane = tid & 63, frag = tid >> 6;
  int k = frag % 12, t2 = frag / 12;
  int mi = t2 & 1, t3 = t2 >> 1;
  int w = t3 & 3, c = t3 >> 2;                   // c in 0..8
  int l15 = lane & 15, lq = lane >> 4;
  int r = c * 128 + w * 32 + mi * 16 + l15;      // 0..1151
  int col = k * 32 + lq * 8;
  const float* Wsrc = (c < 3) ? Wq : (c < 6) ? Wk : Wv;
  int rr = r - (c / 3) * 384;
  unsigned short tmp[8];
  #pragma unroll
  for (int e = 0; e < 8; ++e)
    tmp[e] = f2bf(Wsrc[(size_t)(col + e) * 384 + rr]);
  *(int4*)(WP + (size_t)tid * 8) = *(const int4*)tmp;
}
__global__ void pack_k384(const float* __restrict__ W, unsigned short* __restrict__ WP,
                          int ld) {
  int tid = blockIdx.x * 256 + threadIdx.x;
  int lane = tid & 63, frag = tid >> 6;
  int k = frag % 12, t2 = frag / 12;
  int mi = t2 & 1, t3 = t2 >> 1;
  int w = t3 & 3, c = t3 >> 2;
  int l15 = lane & 15, lq = lane >> 4;
  int r = c * 128 + w * 32 + mi * 16 + l15;
  int col = k * 32 + lq * 8;
  unsigned short tmp[8];
  #pragma unroll
  for (int e = 0; e < 8; ++e)
    tmp[e] = f2bf(W[(size_t)(col + e) * ld + r]);
  *(int4*)(WP + (size_t)tid * 8) = *(const int4*)tmp;
}
__global__ void pack_w2d(const float* __restrict__ W2, unsigned short* __restrict__ W2P) {
  int tid = blockIdx.x * 256 + threadIdx.x;      // 73728 chunks (288 blocks)
  int lane = tid & 63, frag = tid >> 6;
  int kk = frag & 3, t2 = frag >> 2;
  int c = t2 % 12, t3 = t2 / 12;
  int mi = t3 % 6, w = t3 / 6;
  int l15 = lane & 15, lq = lane >> 4;
  int r = w * 96 + mi * 16 + l15;                // 0..383
  int col = c * 128 + kk * 32 + lq * 8;          // 0..1535
  unsigned short tmp[8];
  #pragma unroll
  for (int e = 0; e < 8; ++e)
    tmp[e] = f2bf(W2[(size_t)(col + e) * 384 + r]);
  *(int4*)(W2P + (size_t)tid * 8) = *(const int4*)tmp;
}

// ---------------- layernorm (LN1): fp32 in -> bf16 out (one wave per row; R9) -------
__global__ __launch_bounds__(256) void ln_kernel(const float* __restrict__ x,
                                                 const float* __restrict__ g,
                                                 const float* __restrict__ be,
                                                 unsigned short* __restrict__ out) {
  int row = (blockIdx.x * 256 + threadIdx.x) >> 6;
  int l = threadIdx.x & 63;
  const float* xr = x + (size_t)row * D_;
  float v[6]; float s = 0.f, ss = 0.f;
  #pragma unroll
  for (int i = 0; i < 6; ++i) { v[i] = xr[l + i*64]; s += v[i]; ss += v[i]*v[i]; }
  #pragma unroll
  for (int m = 1; m < 64; m <<= 1) { s += __shfl_xor(s, m); ss += __shfl_xor(ss, m); }
  float mu  = s * (1.f / D_);
  float var = ss * (1.f / D_) - mu * mu;
  float rs  = rsqrtf(var + 1e-5f);
  unsigned short* orow = out + (size_t)row * D_;
  #pragma unroll
  for (int i = 0; i < 6; ++i) {
    int c = l + i*64;
    orow[c] = f2bf((v[i] - mu) * rs * g[c] + be[c]);
  }
}

// ---------------- QKV GEMM v4 (64-row block, k-outer, deferred epilogue) ------------
// Scale-up of R17-proven v3: 64 rows per block halves the per-block weight-panel
// L2 stream (1.8 GB -> 0.9 GB). acc[9][4] under (512,2) cap; staging = ffn's
// verbatim 64-row pattern; epilogue = v3 transpose-store per (buf, 32-row half).
__global__ __launch_bounds__(512, 2) void qkv_gemm(
    const unsigned short* __restrict__ h, const unsigned short* __restrict__ wP,
    unsigned short* __restrict__ qkv)
{
  __shared__ __align__(16) char smem[49152];   // staging 48KB | epilogue 32x784 reuse
  int tid = threadIdx.x, w = tid >> 6, l = tid & 63;
  int l15 = l & 15, lq = l >> 4;
  size_t R0 = (size_t)blockIdx.x * 64;

  // ---- stage h strip (64 rows) -> frag-order LDS (ffn-proven 512thr x 6 int4) ----
  {
    int row = tid >> 3, gi = row >> 4, l15w = row & 15;
    int cbase = (tid & 7) * 48;
    const unsigned short* src = h + (R0 + row) * 384 + cbase;
    #pragma unroll
    for (int i = 0; i < 6; ++i) {
      int col = cbase + i * 8;
      int k = col >> 5, lqw = (col >> 3) & 3;
      *(int4*)(smem + (gi*12 + k)*1024 + (lqw*16 + l15w)*16) = *(const int4*)(src + i*8);
    }
  }
  __syncthreads();

  f32x4 acc[9][4];
  #pragma unroll
  for (int c = 0; c < 9; ++c)
    #pragma unroll
    for (int ni = 0; ni < 4; ++ni) acc[c][ni] = (f32x4){0.f, 0.f, 0.f, 0.f};

  const unsigned short* wb = wP + l * 8;       // + ((c*8+w)*12 + k)*512

  #define LDG(dst, cb, k)                                                    \
    { _Pragma("unroll") for (int ci = 0; ci < 3; ++ci)                       \
        dst[ci] = *(const bf16x8*)(wb + (((cb)+ci)*8 + w) * 6144 + (k) * 512); }

  #define CMPG(buf, cb)                                                      \
    { _Pragma("unroll") for (int ci = 0; ci < 3; ++ci)                       \
        _Pragma("unroll") for (int ni = 0; ni < 4; ++ni)                     \
          acc[(cb)+ci][ni] = __builtin_amdgcn_mfma_f32_16x16x32_bf16(        \
              buf[ci], bfr[ni], acc[(cb)+ci][ni], 0, 0, 0); }

  bf16x8 a0[3], a1[3], a2[3];
  LDG(a0, 0, 0)                                // preload k=0 group 0

  for (int k = 0; k < 12; ++k) {
    bf16x8 bfr[4];
    #pragma unroll
    for (int ni = 0; ni < 4; ++ni)
      bfr[ni] = *(const bf16x8*)(smem + (ni*12 + k)*1024 + l*16);
    int kn = (k < 11) ? k + 1 : 11;
    LDG(a1, 3, k)
    __builtin_amdgcn_s_setprio(1); CMPG(a0, 0) __builtin_amdgcn_s_setprio(0);
    LDG(a2, 6, k)
    __builtin_amdgcn_s_setprio(1); CMPG(a1, 3) __builtin_amdgcn_s_setprio(0);
    LDG(a0, 0, kn)
    __builtin_amdgcn_s_setprio(1); CMPG(a2, 6) __builtin_amdgcn_s_setprio(0);
  }
  #undef LDG
  #undef CMPG

  // ---- deferred epilogue: per buffer x per 32-row half: acc -> LDS -> int4 stores
  __syncthreads();                              // staging region dead; reads drained
  #pragma unroll
  for (int buf = 0; buf < 3; ++buf) {
    #pragma unroll
    for (int half = 0; half < 2; ++half) {
      #pragma unroll
      for (int ci = 0; ci < 3; ++ci) {
        int c = buf * 3 + ci;
        #pragma unroll
        for (int n2 = 0; n2 < 2; ++n2) {
          int ni = half * 2 + n2;
          int lrow = n2 * 16 + l15;
          ushort4 pk;
          pk.x = f2bf(acc[c][ni][0]);
          pk.y = f2bf(acc[c][ni][1]);
          pk.z = f2bf(acc[c][ni][2]);
          pk.w = f2bf(acc[c][ni][3]);
          *(ushort4*)(smem + lrow * 784 + ci * 256 + w * 32 + lq * 8) = pk;
        }
      }
      __syncthreads();
      {
        int row = tid >> 4;
        unsigned short* obase = qkv + (size_t)buf * NROW * 384
                              + (R0 + half * 32 + row) * 384;
        #pragma unroll
        for (int i = 0; i < 3; ++i) {
          int ob = (tid & 15) * 16 + i * 256;   // byte offset in 768-B row
          *(int4*)(obase + (ob >> 1)) = *(const int4*)(smem + row * 784 + ob);
        }
      }
      __syncthreads();
    }
  }
}

// ---------------- fused Wo + residual + LN2 (32-row block; R19-proven) --------------
__global__ __launch_bounds__(512, 4) void wo_ln(
    const unsigned short* __restrict__ o,    // [NROW][384] bf16 (attention out)
    const unsigned short* __restrict__ wP,   // woP packed (NC=3)
    const float* __restrict__ bo, const float* __restrict__ xres,
    const float* __restrict__ g, const float* __restrict__ be,
    float* __restrict__ x2out,               // d_out
    unsigned short* __restrict__ h2out)      // hb
{
  __shared__ __align__(16) char smem[50176]; // staging 24576 (reused) | x2 tile 32x392 f32
  int tid = threadIdx.x, w = tid >> 6, l = tid & 63;
  int l15 = l & 15, lq = l >> 4;
  size_t R0 = (size_t)blockIdx.x * 32;

  // ---- stage o strip (32 rows) -> frag-order LDS (qkv-v3 pattern) ----
  {
    int row = tid >> 4, gi = row >> 4, l15w = row & 15;
    const unsigned short* src = o + (R0 + row) * 384 + (tid & 15) * 24;
    #pragma unroll
    for (int i = 0; i < 3; ++i) {
      int col = (tid & 15) * 24 + i * 8;
      int k = col >> 5, lqw = (col >> 3) & 3;
      *(int4*)(smem + (gi*12 + k)*1024 + (lqw*16 + l15w)*16) = *(const int4*)(src + i*8);
    }
  }
  __syncthreads();

  f32x4 acc[3][2];
  #pragma unroll
  for (int c = 0; c < 3; ++c)
    #pragma unroll
    for (int ni = 0; ni < 2; ++ni) acc[c][ni] = (f32x4){0.f, 0.f, 0.f, 0.f};

  const unsigned short* wb = wP + l * 8;       // + ((ci*8+w)*12 + k)*512

  #define LDGW(dst, k)                                                       \
    { _Pragma("unroll") for (int ci = 0; ci < 3; ++ci)                       \
        dst[ci] = *(const bf16x8*)(wb + (ci*8 + w) * 6144 + (k) * 512); }

  #define CMPW(buf)                                                          \
    { _Pragma("unroll") for (int ci = 0; ci < 3; ++ci)                       \
        _Pragma("unroll") for (int ni = 0; ni < 2; ++ni)                     \
          acc[ci][ni] = __builtin_amdgcn_mfma_f32_16x16x32_bf16(             \
              buf[ci], bfr[ni], acc[ci][ni], 0, 0, 0); }

  bf16x8 aA[3], aB[3];
  LDGW(aA, 0)
  for (int k = 0; k < 12; k += 2) {
    bf16x8 bfr[2];
    #pragma unroll
    for (int ni = 0; ni < 2; ++ni)
      bfr[ni] = *(const bf16x8*)(smem + (ni*12 + k)*1024 + l*16);
    LDGW(aB, k + 1)
    __builtin_amdgcn_s_setprio(1); CMPW(aA) __builtin_amdgcn_s_setprio(0);
    #pragma unroll
    for (int ni = 0; ni < 2; ++ni)
      bfr[ni] = *(const bf16x8*)(smem + (ni*12 + k + 1)*1024 + l*16);
    int kn = (k + 2 < 12) ? k + 2 : 11;
    LDGW(aA, kn)
    __builtin_amdgcn_s_setprio(1); CMPW(aB) __builtin_amdgcn_s_setprio(0);
  }
  #undef LDGW
  #undef CMPW

  // ---- epilogue: x2 = acc + bo + x -> LDS tile [32][392] f32 ----
  __syncthreads();                              // staging reads retired
  #pragma unroll
  for (int ci = 0; ci < 3; ++ci) {
    int col = ci * 128 + w * 16 + lq * 4;
    float4 bb = *(const float4*)(bo + col);
    #pragma unroll
    for (int ni = 0; ni < 2; ++ni) {
      int row = ni * 16 + l15;
      float4 r = *(const float4*)(xres + (R0 + row) * 384 + col);
      float4 v;
      v.x = acc[ci][ni][0] + bb.x + r.x;
      v.y = acc[ci][ni][1] + bb.y + r.y;
      v.z = acc[ci][ni][2] + bb.z + r.z;
      v.w = acc[ci][ni][3] + bb.w + r.w;
      *(float4*)(smem + row * 1568 + col * 4) = v;
    }
  }
  __syncthreads();

  // ---- LN2 on the tile: 16 thr/row; emit x2 fp32 + h2 bf16 (coalesced) ----
  {
    int row = tid >> 4, t16 = tid & 15;
    const char* rbase = smem + row * 1568;
    float4 vv[6];
    float s = 0.f, ss = 0.f;
    #pragma unroll
    for (int i = 0; i < 6; ++i) {
      vv[i] = *(const float4*)(rbase + (t16 + i * 16) * 16);
      s  += vv[i].x + vv[i].y + vv[i].z + vv[i].w;
      ss += vv[i].x*vv[i].x + vv[i].y*vv[i].y + vv[i].z*vv[i].z + vv[i].w*vv[i].w;
    }
    s += __shfl_xor(s, 1); ss += __shfl_xor(ss, 1);
    s += __shfl_xor(s, 2); ss += __shfl_xor(ss, 2);
    s += __shfl_xor(s, 4); ss += __shfl_xor(ss, 4);
    s += __shfl_xor(s, 8); ss += __shfl_xor(ss, 8);
    float mu = s * (1.f / 384.f);
    float rs = rsqrtf(ss * (1.f / 384.f) - mu * mu + 1e-5f);
    float* xrow = x2out + (R0 + row) * 384;
    unsigned short* hrow = h2out + (R0 + row) * 384;
    #pragma unroll
    for (int i = 0; i < 6; ++i) {
      int c4 = t16 + i * 16;                   // float4 index in row
      float4 ga = *(const float4*)(g  + c4 * 4);
      float4 ba = *(const float4*)(be + c4 * 4);
      *(float4*)(xrow + c4 * 4) = vv[i];
      ushort4 pk;
      pk.x = f2bf((vv[i].x - mu) * rs * ga.x + ba.x);
      pk.y = f2bf((vv[i].y - mu) * rs * ga.y + ba.y);
      pk.z = f2bf((vv[i].z - mu) * rs * ga.z + ba.z);
      pk.w = f2bf((vv[i].w - mu) * rs * ga.w + ba.w);
      *(ushort4*)(hrow + c4 * 4) = pk;
    }
  }
}

// ======== 8-wave ffn building blocks (frag-order LDS + packed W) ========
#define LDA3(dst, pA, k0)                                                    \
  { _Pragma("unroll") for (int kq = 0; kq < 3; ++kq)                         \
      dst[kq] = *(const bf16x8*)((pA) + ((k0) + kq) * 512); }

#define CMP3(buf, k0, acc)                                                   \
  { _Pragma("unroll") for (int kq = 0; kq < 3; ++kq) {                       \
      bf16x8 bfr[4];                                                         \
      _Pragma("unroll") for (int ni = 0; ni < 4; ++ni)                       \
        bfr[ni] = *(const bf16x8*)(smem + (ni*12 + (k0)+kq)*1024 + l*16);    \
      _Pragma("unroll") for (int ni = 0; ni < 4; ++ni)                       \
        acc[ni] = __builtin_amdgcn_mfma_f32_16x16x32_bf16(                   \
            buf[kq], bfr[ni], acc[ni], 0, 0, 0);                             \
    } }

// ---------------- fused FFN (8-wave, setprio, dbuf Psf, 1 barrier/chunk; R18-19) ----
__global__ __launch_bounds__(512, 4) void ffn_fused(
    const unsigned short* __restrict__ h2,   // [NROW][384] bf16
    const unsigned short* __restrict__ w1P,  // packed (NC=12)
    const unsigned short* __restrict__ w2P,  // packed (pack_w2d)
    const float* __restrict__ b1,            // [1536]
    const float* __restrict__ b2,            // [384]
    float* __restrict__ out)                 // [NROW][384] fp32, in-place residual add
{
  extern __shared__ __align__(16) char smem[];
  int tid = threadIdx.x, w = tid >> 6, l = tid & 63;
  int l15 = l & 15, lq = l >> 4;
  size_t R0 = (size_t)blockIdx.x * 64;

  // ---- stage h2 strip -> frag-order LDS (512 thr x 48 elems) ----
  {
    int row = tid >> 3, gi = row >> 4, l15w = row & 15;
    int cbase = (tid & 7) * 48;
    const unsigned short* src = h2 + (R0 + row) * 384 + cbase;
    #pragma unroll
    for (int i = 0; i < 6; ++i) {
      int col = cbase + i * 8;
      int k = col >> 5, lqw = (col >> 3) & 3;
      *(int4*)(smem + (gi*12 + k)*1024 + (lqw*16 + l15w)*16) = *(const int4*)(src + i*8);
    }
  }
  __syncthreads();

  f32x4 oacc[3][4];
  #pragma unroll
  for (int i = 0; i < 3; ++i)
    #pragma unroll
    for (int j = 0; j < 4; ++j) oacc[i][j] = (f32x4){0.f, 0.f, 0.f, 0.f};

  const unsigned short* w1b = w1P + w * 6144  + l * 8;  // + c*49152 + k*512
  const unsigned short* w2b = w2P + w * 73728 + l * 8;  // + mi*24576 + c*2048 + kk*512

  #define LDV(dst, pV, kk)                                                   \
    { _Pragma("unroll") for (int mi = 0; mi < 3; ++mi)                       \
        dst[mi] = *(const bf16x8*)((pV) + mi * 24576 + (kk) * 512); }

  #define CMPV(buf, kk, pb)                                                  \
    { bf16x8 bv[4];                                                          \
      _Pragma("unroll") for (int ni = 0; ni < 4; ++ni)                       \
        bv[ni] = *(const bf16x8*)(smem + (pb) + (ni*4 + (kk))*1024 + l*16);  \
      _Pragma("unroll") for (int mi = 0; mi < 3; ++mi)                       \
        _Pragma("unroll") for (int ni = 0; ni < 4; ++ni)                     \
          oacc[mi][ni] = __builtin_amdgcn_mfma_f32_16x16x32_bf16(            \
              buf[mi], bv[ni], oacc[mi][ni], 0, 0, 0);                       \
    }

  bf16x8 afA[3], afB[3];
  bf16x8 avA[3], avB[3];

  LDA3(afA, w1b, 0)   // prologue: first P-group of chunk 0

  for (int c = 0; c < 12; ++c) {
    const unsigned short* pA = w1b + (size_t)c * 49152;
    const unsigned short* pV = w2b + c * 2048;
    unsigned pb = 49152u + (unsigned)(c & 1) * 16384u;

    f32x4 pacc[4];
    #pragma unroll
    for (int j = 0; j < 4; ++j) pacc[j] = (f32x4){0.f, 0.f, 0.f, 0.f};

    // P-phase: 4 groups of 3 k-steps, ping-pong prefetch; T5 around MFMA clusters
    LDA3(afB, pA, 3)
    __builtin_amdgcn_s_setprio(1); CMP3(afA, 0, pacc) __builtin_amdgcn_s_setprio(0);
    LDA3(afA, pA, 6)
    __builtin_amdgcn_s_setprio(1); CMP3(afB, 3, pacc) __builtin_amdgcn_s_setprio(0);
    LDA3(afB, pA, 9)
    __builtin_amdgcn_s_setprio(1); CMP3(afA, 6, pacc) __builtin_amdgcn_s_setprio(0);
    LDV(avA, pV, 0)
    __builtin_amdgcn_s_setprio(1); CMP3(afB, 9, pacc) __builtin_amdgcn_s_setprio(0);

    // P epilogue: bias1 + relu + bf16 pack -> Psf[c&1]
    {
      int fcb = c * 128 + w * 16 + lq * 4;
      float4 bb = *(const float4*)(b1 + fcb);
      unsigned pw = pb + (unsigned)((w >> 1) * 1024 +
                    (((w & 1) * 2 + (lq >> 1)) * 16 + l15) * 16 + (lq & 1) * 8);
      #pragma unroll
      for (int ni = 0; ni < 4; ++ni) {
        float p0 = pacc[ni][0] + bb.x;
        float p1 = pacc[ni][1] + bb.y;
        float p2 = pacc[ni][2] + bb.z;
        float p3 = pacc[ni][3] + bb.w;
        ushort4 pk;
        pk.x = f2bf(p0 > 0.f ? p0 : 0.f);
        pk.y = f2bf(p1 > 0.f ? p1 : 0.f);
        pk.z = f2bf(p2 > 0.f ? p2 : 0.f);
        pk.w = f2bf(p3 > 0.f ? p3 : 0.f);
        *(ushort4*)(smem + pw + ni * 4096) = pk;
      }
    }
    BAR_LGKM();   // single barrier per chunk: Psf[c&1] visible; prefetches in flight

    const unsigned short* pAn = w1b + (size_t)(c < 11 ? c + 1 : 11) * 49152;
    LDV(avB, pV, 1)
    __builtin_amdgcn_s_setprio(1); CMPV(avA, 0, pb) __builtin_amdgcn_s_setprio(0);
    LDV(avA, pV, 2)
    __builtin_amdgcn_s_setprio(1); CMPV(avB, 1, pb) __builtin_amdgcn_s_setprio(0);
    LDV(avB, pV, 3)
    __builtin_amdgcn_s_setprio(1); CMPV(avA, 2, pb) __builtin_amdgcn_s_setprio(0);
    LDA3(afA, pAn, 0)
    __builtin_amdgcn_s_setprio(1); CMPV(avB, 3, pb) __builtin_amdgcn_s_setprio(0);
    // no trailing barrier: next chunk writes Psf[(c+1)&1]
  }
  #undef LDV
  #undef CMPV

  // epilogue: out[row][ocol..+3] = oacc + b2 + res  (dwordx4)
  #pragma unroll
  for (int mi = 0; mi < 3; ++mi) {
    int ocb = w * 48 + mi * 16 + lq * 4;
    float4 b2v = *(const float4*)(b2 + ocb);
    #pragma unroll
    for (int ni = 0; ni < 4; ++ni) {
      size_t row = R0 + ni * 16 + l15;
      float* op = out + row * D_ + ocb;
      float4 r = *(const float4*)op;
      float4 o;
      o.x = oacc[mi][ni][0] + b2v.x + r.x;
      o.y = oacc[mi][ni][1] + b2v.y + r.y;
      o.z = oacc[mi][ni][2] + b2v.z + r.z;
      o.w = oacc[mi][ni][3] + b2v.w + r.w;
      *(float4*)op = o;
    }
  }
}

// ---------------- causal attention (+T5 setprio), one block per (b,h) ----------------
__global__ __launch_bounds__(256) void attn_kernel(const unsigned short* __restrict__ q,
                                                   const unsigned short* __restrict__ k,
                                                   const unsigned short* __restrict__ v,
                                                   unsigned short* __restrict__ o) {
  __shared__ __align__(16) char smem[52224];
  unsigned short (*Ks)[72]       = (unsigned short(*)[72])smem;
  unsigned short (*Ps)[32][136]  = (unsigned short(*)[32][136])smem;
  unsigned short (*Vt)[136]      = (unsigned short(*)[136])(smem + 34816);

  int bh = blockIdx.x;
  int b = bh / H_, h = bh % H_;
  int tid = threadIdx.x, w = tid >> 6, l = tid & 63;

  const unsigned short* kb = k + ((size_t)b * T_) * D_ + h * DH_;
  const unsigned short* vb = v + ((size_t)b * T_) * D_ + h * DH_;
  #pragma unroll
  for (int it = 0; it < 4; ++it) {
    int id = it * 256 + tid;
    int s = id >> 3, c8 = (id & 7) * 8;
    int4 kv = *(const int4*)(kb + (size_t)s * D_ + c8);
    *(int4*)(&Ks[s][c8]) = kv;
    int4 vv = *(const int4*)(vb + (size_t)s * D_ + c8);
    const unsigned short* pe = (const unsigned short*)&vv;
    #pragma unroll
    for (int j2 = 0; j2 < 8; ++j2) Vt[c8 + j2][s] = pe[j2];
  }
  __syncthreads();

  const unsigned short* qbp = q + ((size_t)b * T_) * D_ + h * DH_;
  int rowbase = w * 32;
  bf16x8 aq[2][2];
  #pragma unroll
  for (int mi = 0; mi < 2; ++mi)
    #pragma unroll
    for (int ks = 0; ks < 2; ++ks)
      aq[mi][ks] = *(const bf16x8*)(qbp + (size_t)(rowbase + mi*16 + (l & 15)) * D_
                                        + ks*32 + ((l >> 4) << 3));

  f32x4 accs[2][8];
  #pragma unroll
  for (int i = 0; i < 2; ++i)
    #pragma unroll
    for (int j = 0; j < 8; ++j) accs[i][j] = (f32x4){0.f, 0.f, 0.f, 0.f};
  #pragma unroll
  for (int ks = 0; ks < 2; ++ks) {
    bf16x8 bk[8];
    #pragma unroll
    for (int ni = 0; ni < 8; ++ni)
      bk[ni] = *(const bf16x8*)(&Ks[ni*16 + (l & 15)][ks*32 + ((l >> 4) << 3)]);
    __builtin_amdgcn_s_setprio(1);
    #pragma unroll
    for (int mi = 0; mi < 2; ++mi)
      #pragma unroll
      for (int ni = 0; ni < 8; ++ni)
        accs[mi][ni] = __builtin_amdgcn_mfma_f32_16x16x32_bf16(aq[mi][ks], bk[ni], accs[mi][ni], 0, 0, 0);
    __builtin_amdgcn_s_setprio(0);
  }
  __syncthreads();

  #pragma unroll
  for (int mi = 0; mi < 2; ++mi) {
    #pragma unroll
    for (int j = 0; j < 4; ++j) {
      int t = rowbase + mi*16 + ((l >> 4) << 2) + j;
      float mx = -1e30f;
      #pragma unroll
      for (int ni = 0; ni < 8; ++ni) {
        int scol = ni*16 + (l & 15);
        float sv = accs[mi][ni][j] * 0.125f;
        sv = (scol <= t) ? sv : -1e30f;
        accs[mi][ni][j] = sv;
        mx = fmaxf(mx, sv);
      }
      mx = fmaxf(mx, __shfl_xor(mx, 1));
      mx = fmaxf(mx, __shfl_xor(mx, 2));
      mx = fmaxf(mx, __shfl_xor(mx, 4));
      mx = fmaxf(mx, __shfl_xor(mx, 8));
      float sum = 0.f;
      #pragma unroll
      for (int ni = 0; ni < 8; ++ni) {
        float e = __expf(accs[mi][ni][j] - mx);
        accs[mi][ni][j] = e;
        sum += e;
      }
      sum += __shfl_xor(sum, 1);
      sum += __shfl_xor(sum, 2);
      sum += __shfl_xor(sum, 4);
      sum += __shfl_xor(sum, 8);
      float inv = 1.f / sum;
      #pragma unroll
      for (int ni = 0; ni < 8; ++ni)
        Ps[w][mi*16 + ((l >> 4) << 2) + j][ni*16 + (l & 15)] = f2bf(accs[mi][ni][j] * inv);
    }
  }
  __syncthreads();

  f32x4 acco[2][4];
  #pragma unroll
  for (int i = 0; i < 2; ++i)
    #pragma unroll
    for (int j = 0; j < 4; ++j) acco[i][j] = (f32x4){0.f, 0.f, 0.f, 0.f};
  #pragma unroll
  for (int ks = 0; ks < 4; ++ks) {
    bf16x8 ap[2], bv[4];
    #pragma unroll
    for (int mi = 0; mi < 2; ++mi)
      ap[mi] = *(const bf16x8*)(&Ps[w][mi*16 + (l & 15)][ks*32 + ((l >> 4) << 3)]);
    #pragma unroll
    for (int ni = 0; ni < 4; ++ni)
      bv[ni] = *(const bf16x8*)(&Vt[ni*16 + (l & 15)][ks*32 + ((l >> 4) << 3)]);
    __builtin_amdgcn_s_setprio(1);
    #pragma unroll
    for (int mi = 0; mi < 2; ++mi)
      #pragma unroll
      for (int ni = 0; ni < 4; ++ni)
        acco[mi][ni] = __builtin_amdgcn_mfma_f32_16x16x32_bf16(ap[mi], bv[ni], acco[mi][ni], 0, 0, 0);
    __builtin_amdgcn_s_setprio(0);
  }

  unsigned short* ob = o + ((size_t)b * T_) * D_ + h * DH_;
  #pragma unroll
  for (int mi = 0; mi < 2; ++mi)
    #pragma unroll
    for (int ni = 0; ni < 4; ++ni)
      #pragma unroll
      for (int j = 0; j < 4; ++j) {
        int t = rowbase + mi*16 + ((l >> 4) << 2) + j;
        int d = ni*16 + (l & 15);
        ob[(size_t)t * D_ + d] = f2bf(acco[mi][ni][j]);
      }
}

extern "C" void kernel_launch(void* const* d_in, const int* in_sizes, int n_in,
                              void* d_out, int out_size, void* d_ws, size_t ws_size,
                              hipStream_t stream) {
  const float* x   = (const float*)d_in[0];
  const float* Wq  = (const float*)d_in[1];
  const float* Wk  = (const float*)d_in[2];
  const float* Wv  = (const float*)d_in[3];
  const float* Wo  = (const float*)d_in[4];
  const float* bo  = (const float*)d_in[5];
  const float* W1  = (const float*)d_in[6];
  const float* b1  = (const float*)d_in[7];
  const float* W2  = (const float*)d_in[8];
  const float* b2  = (const float*)d_in[9];
  const float* g1  = (const float*)d_in[10];
  const float* be1 = (const float*)d_in[11];
  const float* g2  = (const float*)d_in[12];
  const float* be2 = (const float*)d_in[13];

  // workspace layout (bytes); total ~204 MiB
  char* ws = (char*)d_ws;
  unsigned short* hb    = (unsigned short*)(ws);               // h (LN1), later h2 (LN2)
  unsigned short* qb    = (unsigned short*)(ws +  50331648);   // q|k|v contiguous; o in-place
  unsigned short* kbuf  = (unsigned short*)(ws + 100663296);
  unsigned short* vbuf  = (unsigned short*)(ws + 150994944);
  unsigned short* wqkvP = (unsigned short*)(ws + 201326592);   // packed (pack_wqkv, NC=9)
  unsigned short* woP   = wqkvP + 442368;                      // packed (pack_k384, NC=3)
  unsigned short* w1P   = woP + 147456;                        // packed (pack_k384, NC=12)
  unsigned short* w2P   = w1P + 589824;                        // packed (pack_w2d)
  float* x2 = (float*)d_out;
  (void)kbuf; (void)vbuf;

  // allow 80KB dynamic LDS for ffn_fused (host-side attribute; idempotent)
  hipFuncSetAttribute(reinterpret_cast<const void*>(ffn_fused),
                      hipFuncAttributeMaxDynamicSharedMemorySize, 81920);

  // 1) direct fragment-order packs from fp32 weights (bit-identical values)
  pack_wqkv<<<dim3(216), 256, 0, stream>>>(Wq, Wk, Wv, wqkvP);
  pack_k384<<<dim3(72),  256, 0, stream>>>(Wo, woP, 384);
  pack_k384<<<dim3(288), 256, 0, stream>>>(W1, w1P, 1536);
  pack_w2d <<<dim3(288), 256, 0, stream>>>(W2, w2P);

  // 2) LN1 (R9-exact): x -> h (bf16)
  ln_kernel<<<dim3(NROW / 4), 256, 0, stream>>>(x, g1, be1, hb);

  // 3) QKV GEMM v4 (64-row blocks, halved L2 weight stream): q|k|v = h @ [Wq|Wk|Wv]
  qkv_gemm<<<dim3(NROW / 64), 512, 0, stream>>>(hb, wqkvP, qb);

  // 4) attention: o overwrites q in place (per-block disjoint strips)
  attn_kernel<<<dim3(B_ * H_), 256, 0, stream>>>(qb, kbuf, vbuf, qb);

  // 5) fused Wo + residual + LN2: x2 -> d_out (fp32), h2 -> hb (bf16)
  wo_ln<<<dim3(NROW / 32), 512, 0, stream>>>(qb, woP, bo, x, g2, be2, x2, hb);

  // 6) fused FFN (dbuf-Psf, 1 barrier/chunk, 80KB dyn LDS)
  ffn_fused<<<dim3(NROW / 64), 512, 81920, stream>>>(hb, w1P, w2P, b1, b2, x2);
}